// Round 1
// baseline (8940.579 us; speedup 1.0000x reference)
//
#include <hip/hip_runtime.h>
#include <cstdint>
#include <cstddef>

// Problem constants
#define B_   8
#define NM_  10
#define T_   16376
#define RED_ 8
#define D_   512
#define H_   8
#define DH_  64
#define L_   4
#define S_   2048
#define NB_  32
#define BS_  64
#define FF_  2048
#define MTOK (B_*S_)   // 16384 token rows

// ---------------------------------------------------------------------------
// Embed: h[b, t, :] for t==0 -> pos_emb[0]; else
//   h[b,t,d] = sum_m x[b, m/8, (m%8)*2047 + (t-1)] * w_embed[m,d] + b_embed[d] + pos_emb[t,d]
// ---------------------------------------------------------------------------
__global__ __launch_bounds__(128) void embed_kernel(
    const float* __restrict__ x, const float* __restrict__ we,
    const float* __restrict__ be, const float* __restrict__ pe,
    float* __restrict__ h)
{
    int row = blockIdx.x;            // 0..MTOK-1
    int b = row >> 11;               // /S_
    int t = row & (S_ - 1);
    int tid = threadIdx.x;
    float* hp = h + (size_t)row * D_;
    const float* pep = pe + (size_t)t * D_;
    if (t == 0) {
        for (int d = tid; d < D_; d += 128) hp[d] = pep[d];
        return;
    }
    __shared__ float xv[80];
    int tp = t - 1;
    if (tid < 80) {
        int mm = tid;
        xv[mm] = x[(size_t)b * NM_ * T_ + (size_t)(mm >> 3) * T_ + (mm & 7) * 2047 + tp];
    }
    __syncthreads();
    for (int d = tid; d < D_; d += 128) {
        float acc = be[d] + pep[d];
        #pragma unroll
        for (int mm = 0; mm < 80; mm++) acc += xv[mm] * we[mm * D_ + d];
        hp[d] = acc;
    }
}

// ---------------------------------------------------------------------------
// Generic fp32 GEMM: C = A(MxK) @ W(KxN) + bias [+res] [relu]
// 64x64 tile, BK=16, 256 threads, 4x4 microtile.
// qkv_scatter: write C into (B,H,S,DH) layout instead of (M,N).
// NOTE: res and C may alias (in-place residual) -> no __restrict__ on them.
// ---------------------------------------------------------------------------
#define ASTR 20   // padded LDS stride for A tile
__global__ __launch_bounds__(256) void gemm_kernel(
    const float* __restrict__ A, const float* __restrict__ W,
    const float* __restrict__ bias, const float* res,
    float* C, int M, int N, int K, int relu, int qkv_scatter)
{
    __shared__ float As[64 * ASTR];
    __shared__ float Bs[16 * 64];
    int tid = threadIdx.x;
    int bn = blockIdx.x * 64;
    int bm = blockIdx.y * 64;
    int tx = tid & 15, ty = tid >> 4;
    int arow = tid >> 2, ac4 = (tid & 3) * 4;
    int brow = tid >> 4, bc4 = (tid & 15) * 4;

    float acc[4][4];
    #pragma unroll
    for (int i = 0; i < 4; i++)
        #pragma unroll
        for (int j = 0; j < 4; j++) acc[i][j] = 0.f;

    const float* Ap = A + (size_t)(bm + arow) * K + ac4;
    const float* Wp = W + (size_t)brow * N + bn + bc4;

    for (int kk = 0; kk < K; kk += 16) {
        float4 av = *(const float4*)(Ap + kk);
        float4 bv = *(const float4*)(Wp + (size_t)kk * N);
        __syncthreads();
        As[arow * ASTR + ac4 + 0] = av.x;
        As[arow * ASTR + ac4 + 1] = av.y;
        As[arow * ASTR + ac4 + 2] = av.z;
        As[arow * ASTR + ac4 + 3] = av.w;
        *(float4*)&Bs[brow * 64 + bc4] = bv;
        __syncthreads();
        #pragma unroll
        for (int k = 0; k < 16; k++) {
            float a[4];
            #pragma unroll
            for (int i = 0; i < 4; i++) a[i] = As[(ty * 4 + i) * ASTR + k];
            float4 b4 = *(const float4*)&Bs[k * 64 + tx * 4];
            float bb[4] = {b4.x, b4.y, b4.z, b4.w};
            #pragma unroll
            for (int i = 0; i < 4; i++)
                #pragma unroll
                for (int j = 0; j < 4; j++)
                    acc[i][j] = fmaf(a[i], bb[j], acc[i][j]);
        }
    }

    int cbase = bn + tx * 4;
    float4 bi = *(const float4*)(bias + cbase);
    #pragma unroll
    for (int i = 0; i < 4; i++) {
        int r = bm + ty * 4 + i;
        float4 o4;
        o4.x = acc[i][0] + bi.x;
        o4.y = acc[i][1] + bi.y;
        o4.z = acc[i][2] + bi.z;
        o4.w = acc[i][3] + bi.w;
        if (relu) {
            o4.x = fmaxf(o4.x, 0.f); o4.y = fmaxf(o4.y, 0.f);
            o4.z = fmaxf(o4.z, 0.f); o4.w = fmaxf(o4.w, 0.f);
        }
        if (res) {
            float4 rv = *(const float4*)(res + (size_t)r * N + cbase);
            o4.x += rv.x; o4.y += rv.y; o4.z += rv.z; o4.w += rv.w;
        }
        if (qkv_scatter) {
            int bb_ = r >> 11;          // batch
            int s = r & (S_ - 1);
            int hh = bn >> 6;           // head (tile is 64-col aligned)
            int dh = cbase & 63;
            *(float4*)(C + ((((size_t)bb_ * H_ + hh) * S_ + s) * DH_) + dh) = o4;
        } else {
            *(float4*)(C + (size_t)r * N + cbase) = o4;
        }
    }
}

// ---------------------------------------------------------------------------
// Block-sparse attention. One wave (64 threads) per (b, h, n) query block.
// q,k,v layout: (B,H,S,DH). out layout: (B,S,D) with col h*64+dh.
// idx = {0, clip(n-1), n, clip(n+1), rand0, rand1}; duplicate columns skipped
// (exact: reference sets them to -1e9 -> exp underflows to 0 in fp32).
// ---------------------------------------------------------------------------
__global__ __launch_bounds__(64) void attn_kernel(
    const float* __restrict__ q, const float* __restrict__ k,
    const float* __restrict__ v, const int* __restrict__ rb,
    float* __restrict__ out)
{
    __shared__ float kv[64 * 64];
    __shared__ float sl[64 * 65];
    int bid = blockIdx.x;
    int n = bid & (NB_ - 1);
    int hh = (bid >> 5) & (H_ - 1);
    int b = bid >> 8;
    int lane = threadIdx.x;

    int idx[6];
    idx[0] = 0;
    idx[1] = (n - 1 < 0) ? 0 : n - 1;
    idx[2] = n;
    idx[3] = (n + 1 > NB_ - 1) ? NB_ - 1 : n + 1;
    idx[4] = rb[n * 2 + 0];
    idx[5] = rb[n * 2 + 1];

    const size_t plane = ((size_t)b * H_ + hh) * S_;
    const float4* qp4 = (const float4*)(q + (plane + n * BS_ + lane) * DH_);
    float qr[64];
    #pragma unroll
    for (int i = 0; i < 16; i++) {
        float4 tq = qp4[i];
        qr[4*i+0] = tq.x; qr[4*i+1] = tq.y; qr[4*i+2] = tq.z; qr[4*i+3] = tq.w;
    }
    float orow[64];
    #pragma unroll
    for (int d = 0; d < 64; d++) orow[d] = 0.f;
    float m = -1e30f, lsum = 0.f;

    for (int c = 0; c < 6; c++) {
        bool dup = false;
        #pragma unroll
        for (int j = 0; j < 5; j++) if (j < c) dup = dup || (idx[j] == idx[c]);
        if (dup) continue;   // uniform across the wave

        // stage K block
        const float4* kp4 = (const float4*)(k + (plane + (size_t)idx[c] * BS_) * DH_);
        __syncthreads();
        #pragma unroll
        for (int i = 0; i < 16; i++) ((float4*)kv)[lane + i * 64] = kp4[lane + i * 64];
        __syncthreads();

        float rowmax = -1e30f;
        for (int jj = 0; jj < 64; jj++) {
            float acc = 0.f;
            #pragma unroll
            for (int d = 0; d < 64; d++) acc += qr[d] * kv[jj * 64 + d];
            acc *= 0.125f;                 // 1/sqrt(64)
            sl[lane * 65 + jj] = acc;
            rowmax = fmaxf(rowmax, acc);
        }
        float newm = fmaxf(m, rowmax);
        float corr = __expf(m - newm);
        lsum *= corr;
        #pragma unroll
        for (int d = 0; d < 64; d++) orow[d] *= corr;
        float ps = 0.f;
        for (int jj = 0; jj < 64; jj++) {
            float p = __expf(sl[lane * 65 + jj] - newm);
            sl[lane * 65 + jj] = p;
            ps += p;
        }
        lsum += ps;
        m = newm;

        // stage V block (reuse kv)
        const float4* vp4 = (const float4*)(v + (plane + (size_t)idx[c] * BS_) * DH_);
        __syncthreads();
        #pragma unroll
        for (int i = 0; i < 16; i++) ((float4*)kv)[lane + i * 64] = vp4[lane + i * 64];
        __syncthreads();

        for (int jj = 0; jj < 64; jj++) {
            float p = sl[lane * 65 + jj];
            #pragma unroll
            for (int d = 0; d < 64; d++) orow[d] += p * kv[jj * 64 + d];
        }
    }

    float inv = 1.f / lsum;
    float4* op4 = (float4*)(out + ((size_t)b * S_ + n * BS_ + lane) * D_ + hh * DH_);
    #pragma unroll
    for (int i = 0; i < 16; i++) {
        float4 t4;
        t4.x = orow[4*i+0] * inv; t4.y = orow[4*i+1] * inv;
        t4.z = orow[4*i+2] * inv; t4.w = orow[4*i+3] * inv;
        op4[i] = t4;
    }
}

// ---------------------------------------------------------------------------
// Row LayerNorm (two-pass, in-place capable). 64 threads per row of 512.
// ---------------------------------------------------------------------------
__global__ __launch_bounds__(64) void ln_kernel(
    const float* in, float* outp,
    const float* __restrict__ g, const float* __restrict__ bb)
{
    size_t r = blockIdx.x;
    int t = threadIdx.x;
    const float4* ip = (const float4*)(in + r * D_);
    float4 x0 = ip[2 * t], x1 = ip[2 * t + 1];
    float s = x0.x + x0.y + x0.z + x0.w + x1.x + x1.y + x1.z + x1.w;
    #pragma unroll
    for (int off = 32; off; off >>= 1) s += __shfl_xor(s, off, 64);
    float mean = s * (1.0f / D_);
    float d0 = x0.x - mean, d1 = x0.y - mean, d2 = x0.z - mean, d3 = x0.w - mean;
    float d4 = x1.x - mean, d5 = x1.y - mean, d6 = x1.z - mean, d7 = x1.w - mean;
    float ss = d0*d0 + d1*d1 + d2*d2 + d3*d3 + d4*d4 + d5*d5 + d6*d6 + d7*d7;
    #pragma unroll
    for (int off = 32; off; off >>= 1) ss += __shfl_xor(ss, off, 64);
    float rs = rsqrtf(ss * (1.0f / D_) + 1e-5f);
    float4 g0 = ((const float4*)g)[2 * t], g1 = ((const float4*)g)[2 * t + 1];
    float4 b0 = ((const float4*)bb)[2 * t], b1 = ((const float4*)bb)[2 * t + 1];
    float4 y0, y1;
    y0.x = d0 * rs * g0.x + b0.x; y0.y = d1 * rs * g0.y + b0.y;
    y0.z = d2 * rs * g0.z + b0.z; y0.w = d3 * rs * g0.w + b0.w;
    y1.x = d4 * rs * g1.x + b1.x; y1.y = d5 * rs * g1.y + b1.y;
    y1.z = d6 * rs * g1.z + b1.z; y1.w = d7 * rs * g1.w + b1.w;
    float4* op = (float4*)(outp + r * D_);
    op[2 * t] = y0; op[2 * t + 1] = y1;
}

// ---------------------------------------------------------------------------
// Head: out[b,:] = tanh(relu(h[b,0,:] @ w_dense + b_dense) @ w_out + b_out)
// ---------------------------------------------------------------------------
__global__ __launch_bounds__(256) void head_kernel(
    const float* __restrict__ h, const float* __restrict__ wd,
    const float* __restrict__ bd, const float* __restrict__ wo,
    const float* __restrict__ bo, float* __restrict__ out)
{
    __shared__ float hrow[D_];
    __shared__ float red[8];
    int b = blockIdx.x;
    int tid = threadIdx.x;
    if (tid < 128) ((float4*)hrow)[tid] = ((const float4*)(h + (size_t)b * S_ * D_))[tid];
    __syncthreads();
    float p0 = 0.f, p1 = 0.f;
    #pragma unroll
    for (int jj = 0; jj < 4; jj++) {
        int j = tid + jj * 256;   // 0..1023, lanes consecutive -> coalesced
        float acc = bd[j];
        for (int i = 0; i < D_; i++) acc += hrow[i] * wd[(size_t)i * 1024 + j];
        float dns = fmaxf(acc, 0.f);
        p0 += dns * wo[j * 2 + 0];
        p1 += dns * wo[j * 2 + 1];
    }
    #pragma unroll
    for (int off = 32; off; off >>= 1) { p0 += __shfl_xor(p0, off, 64); p1 += __shfl_xor(p1, off, 64); }
    int wid = tid >> 6;
    if ((tid & 63) == 0) { red[wid * 2] = p0; red[wid * 2 + 1] = p1; }
    __syncthreads();
    if (tid == 0) {
        float t0 = red[0] + red[2] + red[4] + red[6] + bo[0];
        float t1 = red[1] + red[3] + red[5] + red[7] + bo[1];
        out[b * 2 + 0] = tanhf(t0);
        out[b * 2 + 1] = tanhf(t1);
    }
}

// ---------------------------------------------------------------------------
extern "C" void kernel_launch(void* const* d_in, const int* in_sizes, int n_in,
                              void* d_out, int out_size, void* d_ws, size_t ws_size,
                              hipStream_t stream) {
    (void)in_sizes; (void)n_in; (void)out_size; (void)ws_size;
    const float* x       = (const float*)d_in[0];
    const float* w_embed = (const float*)d_in[1];
    const float* b_embed = (const float*)d_in[2];
    const float* pos_emb = (const float*)d_in[3];
    const float* Wq      = (const float*)d_in[4];
    const float* bq      = (const float*)d_in[5];
    const float* Wk      = (const float*)d_in[6];
    const float* bk      = (const float*)d_in[7];
    const float* Wv      = (const float*)d_in[8];
    const float* bv      = (const float*)d_in[9];
    const float* Wo      = (const float*)d_in[10];
    const float* bo      = (const float*)d_in[11];
    const float* ln1_g   = (const float*)d_in[12];
    const float* ln1_b   = (const float*)d_in[13];
    const float* W1      = (const float*)d_in[14];
    const float* b1      = (const float*)d_in[15];
    const float* W2      = (const float*)d_in[16];
    const float* b2      = (const float*)d_in[17];
    const float* ln2_g   = (const float*)d_in[18];
    const float* ln2_b   = (const float*)d_in[19];
    const float* w_dense = (const float*)d_in[20];
    const float* b_dense = (const float*)d_in[21];
    const float* w_out   = (const float*)d_in[22];
    const float* b_out   = (const float*)d_in[23];
    const int*   rb      = (const int*)d_in[24];
    float* out = (float*)d_out;

    // Workspace layout: h (32 MiB) + buf (128 MiB, used as q|k|v|o then ff1)
    float* h   = (float*)d_ws;
    float* buf = h + (size_t)MTOK * D_;
    float* q   = buf;
    float* k   = buf + (size_t)MTOK * D_;
    float* v   = buf + 2 * (size_t)MTOK * D_;
    float* o   = buf + 3 * (size_t)MTOK * D_;
    float* ff1 = buf;

    embed_kernel<<<MTOK, 128, 0, stream>>>(x, w_embed, b_embed, pos_emb, h);

    for (int l = 0; l < L_; l++) {
        const float* Wq_l = Wq + (size_t)l * D_ * D_;
        const float* Wk_l = Wk + (size_t)l * D_ * D_;
        const float* Wv_l = Wv + (size_t)l * D_ * D_;
        const float* Wo_l = Wo + (size_t)l * D_ * D_;
        const float* W1_l = W1 + (size_t)l * D_ * FF_;
        const float* W2_l = W2 + (size_t)l * FF_ * D_;

        dim3 gD(D_ / 64, MTOK / 64);
        dim3 gF(FF_ / 64, MTOK / 64);

        gemm_kernel<<<gD, 256, 0, stream>>>(h, Wq_l, bq + l * D_, nullptr, q, MTOK, D_, D_, 0, 1);
        gemm_kernel<<<gD, 256, 0, stream>>>(h, Wk_l, bk + l * D_, nullptr, k, MTOK, D_, D_, 0, 1);
        gemm_kernel<<<gD, 256, 0, stream>>>(h, Wv_l, bv + l * D_, nullptr, v, MTOK, D_, D_, 0, 1);

        attn_kernel<<<B_ * H_ * NB_, 64, 0, stream>>>(q, k, v, rb, o);

        // h = h + o @ Wo + bo   (in-place residual write into h)
        gemm_kernel<<<gD, 256, 0, stream>>>(o, Wo_l, bo + l * D_, h, h, MTOK, D_, D_, 0, 0);
        ln_kernel<<<MTOK, 64, 0, stream>>>(h, h, ln1_g + l * D_, ln1_b + l * D_);

        // ff1 = relu(h @ W1 + b1)
        gemm_kernel<<<gF, 256, 0, stream>>>(h, W1_l, b1 + l * FF_, nullptr, ff1, MTOK, FF_, D_, 1, 0);
        // h = h + ff1 @ W2 + b2
        gemm_kernel<<<gD, 256, 0, stream>>>(ff1, W2_l, b2 + l * D_, h, h, MTOK, D_, FF_, 0, 0);
        ln_kernel<<<MTOK, 64, 0, stream>>>(h, h, ln2_g + l * D_, ln2_b + l * D_);
    }

    head_kernel<<<B_, 256, 0, stream>>>(h, w_dense, b_dense, w_out, b_out, out);
}

// Round 3
// 3028.090 us; speedup vs baseline: 2.9525x; 2.9525x over previous
//
#include <hip/hip_runtime.h>
#include <cstdint>
#include <cstddef>

// Problem constants
#define B_   8
#define NM_  10
#define T_   16376
#define D_   512
#define H_   8
#define DH_  64
#define L_   4
#define S_   2048
#define NB_  32
#define BS_  64
#define FF_  2048
#define MTOK (B_*S_)   // 16384 token rows
#define DD_  (D_*D_)

typedef __attribute__((ext_vector_type(8))) __bf16 bf16x8;
typedef __attribute__((ext_vector_type(4))) float f32x4;

__device__ __forceinline__ void async16(void* lds, const void* g) {
    __builtin_amdgcn_global_load_lds(
        (const __attribute__((address_space(1))) void*)g,
        (__attribute__((address_space(3))) void*)lds, 16, 0, 0);
}

// ---------------------------------------------------------------------------
// Weight transpose+convert: in (K x N fp32, z-strided) -> out (N x K bf16)
// ---------------------------------------------------------------------------
__global__ __launch_bounds__(256) void wconv_kernel(
    const float* __restrict__ in, __bf16* __restrict__ outp, int K, int N)
{
    __shared__ float t[32][33];
    size_t zo = (size_t)blockIdx.z * K * N;
    const float* ip = in + zo;
    __bf16* op = outp + zo;
    int n0 = blockIdx.x * 32, k0 = blockIdx.y * 32;
    int tx = threadIdx.x, ty = threadIdx.y;   // 32 x 8
    #pragma unroll
    for (int j = 0; j < 4; j++)
        t[ty + 8 * j][tx] = ip[(size_t)(k0 + ty + 8 * j) * N + n0 + tx];
    __syncthreads();
    #pragma unroll
    for (int j = 0; j < 4; j++)
        op[(size_t)(n0 + ty + 8 * j) * K + k0 + tx] = (__bf16)t[tx][ty + 8 * j];
}

// ---------------------------------------------------------------------------
// Embed: writes h (fp32) and h_bf (bf16)
// ---------------------------------------------------------------------------
__global__ __launch_bounds__(128) void embed_kernel(
    const float* __restrict__ x, const float* __restrict__ we,
    const float* __restrict__ be, const float* __restrict__ pe,
    float* __restrict__ h, __bf16* __restrict__ hb)
{
    int row = blockIdx.x;
    int b = row >> 11;
    int t = row & (S_ - 1);
    int tid = threadIdx.x;
    float* hp = h + (size_t)row * D_;
    __bf16* hbp = hb + (size_t)row * D_;
    const float* pep = pe + (size_t)t * D_;
    if (t == 0) {
        for (int d = tid; d < D_; d += 128) { float vv = pep[d]; hp[d] = vv; hbp[d] = (__bf16)vv; }
        return;
    }
    __shared__ float xv[80];
    int tp = t - 1;
    if (tid < 80)
        xv[tid] = x[(size_t)b * NM_ * T_ + (size_t)(tid >> 3) * T_ + (tid & 7) * 2047 + tp];
    __syncthreads();
    for (int d = tid; d < D_; d += 128) {
        float acc = be[d] + pep[d];
        #pragma unroll
        for (int mm = 0; mm < 80; mm++) acc += xv[mm] * we[mm * D_ + d];
        hp[d] = acc;
        hbp[d] = (__bf16)acc;
    }
}

// ---------------------------------------------------------------------------
// MFMA bf16 GEMM: C = A(MxK bf16) @ Wt^T + bias [+res] [relu]
// Wt is N x K bf16 (pre-transposed). 128x128 tile, BK=32, 256 thr (4 waves).
// Outputs: Cf (fp32 MxN, optional), Cb (bf16, optional; scatter -> (B,H,S,DH)).
// blockIdx.z selects Wt plane (wtz), bias pointer, Cb plane (cbz) for QKV.
// ---------------------------------------------------------------------------
__global__ __launch_bounds__(256, 2) void mfma_gemm(
    const __bf16* __restrict__ A, const __bf16* __restrict__ Wt,
    const float* __restrict__ bias0, const float* __restrict__ bias1,
    const float* __restrict__ bias2,
    const float* res, float* Cf, __bf16* Cb,
    int N, int K, long wtz, long cbz, int relu, int scatter)
{
    __shared__ __align__(16) __bf16 As[128 * 32];
    __shared__ __align__(16) __bf16 Bs[128 * 32];
    int tid = threadIdx.x;
    int wave = tid >> 6;
    int lane = tid & 63;
    int bn = blockIdx.x * 128;
    int bm = blockIdx.y * 128;
    int z = blockIdx.z;
    const __bf16* Wz = Wt + (size_t)z * wtz;
    const float* bias = (z == 0) ? bias0 : (z == 1 ? bias1 : bias2);

    f32x4 acc[4][4];
    #pragma unroll
    for (int r = 0; r < 4; r++)
        #pragma unroll
        for (int c = 0; c < 4; c++) acc[r][c] = (f32x4){0.f, 0.f, 0.f, 0.f};

    const int wr = (wave >> 1) * 64;
    const int wc = (wave & 1) * 64;
    const int fr = lane & 15;
    const int fk = (lane >> 4) * 8;

    // staging: chunk id c covers 16B (8 bf16); row = c>>2, kpart = (c&3)*8
    const int c0 = tid, c1 = tid + 256;
    const __bf16* Ag0 = A  + (size_t)(bm + (c0 >> 2)) * K + (c0 & 3) * 8;
    const __bf16* Ag1 = A  + (size_t)(bm + (c1 >> 2)) * K + (c1 & 3) * 8;
    const __bf16* Bg0 = Wz + (size_t)(bn + (c0 >> 2)) * K + (c0 & 3) * 8;
    const __bf16* Bg1 = Wz + (size_t)(bn + (c1 >> 2)) * K + (c1 & 3) * 8;
    __bf16* AsW0 = As + (size_t)(wave * 64) * 8;
    __bf16* AsW1 = As + (size_t)(256 + wave * 64) * 8;
    __bf16* BsW0 = Bs + (size_t)(wave * 64) * 8;
    __bf16* BsW1 = Bs + (size_t)(256 + wave * 64) * 8;

    for (int kk = 0; kk < K; kk += 32) {
        __syncthreads();
        async16(AsW0, Ag0 + kk);
        async16(AsW1, Ag1 + kk);
        async16(BsW0, Bg0 + kk);
        async16(BsW1, Bg1 + kk);
        __syncthreads();
        bf16x8 af[4], bfr[4];
        #pragma unroll
        for (int r = 0; r < 4; r++)
            af[r] = *(const bf16x8*)&As[(size_t)(wr + r * 16 + fr) * 32 + fk];
        #pragma unroll
        for (int c = 0; c < 4; c++)
            bfr[c] = *(const bf16x8*)&Bs[(size_t)(wc + c * 16 + fr) * 32 + fk];
        #pragma unroll
        for (int r = 0; r < 4; r++)
            #pragma unroll
            for (int c = 0; c < 4; c++)
                acc[r][c] = __builtin_amdgcn_mfma_f32_16x16x32_bf16(af[r], bfr[c], acc[r][c], 0, 0, 0);
    }

    // epilogue: C/D layout col = lane&15, row = (lane>>4)*4 + reg
    int rbase = bm + wr + (lane >> 4) * 4;
    #pragma unroll
    for (int c = 0; c < 4; c++) {
        int cg = bn + wc + c * 16 + fr;
        float bv = bias[cg];
        #pragma unroll
        for (int r = 0; r < 4; r++) {
            #pragma unroll
            for (int i = 0; i < 4; i++) {
                int rg = rbase + r * 16 + i;
                float val = acc[r][c][i] + bv;
                if (relu) val = fmaxf(val, 0.f);
                if (res) val += res[(size_t)rg * N + cg];
                if (Cf) Cf[(size_t)rg * N + cg] = val;
                if (Cb) {
                    if (scatter) {
                        int bb = rg >> 11, s = rg & (S_ - 1);
                        int hh = cg >> 6, dh = cg & 63;
                        (Cb + (size_t)z * cbz)[((((size_t)bb * H_ + hh) * S_ + s) * DH_) + dh] = (__bf16)val;
                    } else {
                        Cb[(size_t)rg * N + cg] = (__bf16)val;
                    }
                }
            }
        }
    }
}

// ---------------------------------------------------------------------------
// Block-sparse attention v2. One wave per (b,h,n). bf16 q/k/v in (B,H,S,DH).
// K/V staged fp32 in LDS (stride 68); fp16 score scratch; online softmax.
// Output o_bf (B,S,D) bf16.
// ---------------------------------------------------------------------------
#define KVS 68
__global__ __launch_bounds__(64, 2) void attn_kernel(
    const __bf16* __restrict__ q, const __bf16* __restrict__ k,
    const __bf16* __restrict__ v, const int* __restrict__ rb,
    __bf16* __restrict__ o)
{
    __shared__ __align__(16) float kvf[64 * KVS];
    __shared__ _Float16 sl[64 * 66];
    int bid = blockIdx.x;
    int n = bid & (NB_ - 1);
    int hh = (bid >> 5) & (H_ - 1);
    int b = bid >> 8;
    int lane = threadIdx.x;

    int idx[6];
    idx[0] = 0;
    idx[1] = n > 0 ? n - 1 : 0;
    idx[2] = n;
    idx[3] = n < NB_ - 1 ? n + 1 : NB_ - 1;
    idx[4] = rb[n * 2 + 0];
    idx[5] = rb[n * 2 + 1];

    size_t plane = ((size_t)b * H_ + hh) * S_;

    float qr[64];
    {
        const __bf16* qp = q + (plane + (size_t)n * BS_ + lane) * DH_;
        #pragma unroll
        for (int i = 0; i < 8; i++) {
            bf16x8 t = *(const bf16x8*)(qp + i * 8);
            #pragma unroll
            for (int j = 0; j < 8; j++) qr[i * 8 + j] = (float)t[j];
        }
    }
    float orow[64];
    #pragma unroll
    for (int d = 0; d < 64; d++) orow[d] = 0.f;
    float m = -1e30f, lsum = 0.f;

    for (int c = 0; c < 6; c++) {
        bool dup = false;
        #pragma unroll
        for (int j = 0; j < 6; j++) if (j < c && idx[j] == idx[c]) dup = true;
        if (dup) continue;   // wave-uniform

        // ---- stage K block (8 KiB contiguous, coalesced) ----
        {
            const __bf16* kp = k + (plane + (size_t)idx[c] * BS_) * DH_;
            __syncthreads();
            #pragma unroll
            for (int i = 0; i < 8; i++) {
                int ch = i * 64 + lane;
                bf16x8 t = *(const bf16x8*)(kp + ch * 8);
                int jj = ch >> 3, d0 = (ch & 7) * 8;
                #pragma unroll
                for (int j = 0; j < 8; j++) kvf[jj * KVS + d0 + j] = (float)t[j];
            }
            __syncthreads();
        }
        // ---- scores (per lane = query row) ----
        float rowmax = -1e30f;
        for (int jj = 0; jj < 64; jj++) {
            const float4* r4 = (const float4*)&kvf[jj * KVS];
            float a0 = 0.f, a1 = 0.f, a2 = 0.f, a3 = 0.f;
            #pragma unroll
            for (int t4 = 0; t4 < 16; t4++) {
                float4 kv4 = r4[t4];
                a0 = fmaf(qr[4 * t4 + 0], kv4.x, a0);
                a1 = fmaf(qr[4 * t4 + 1], kv4.y, a1);
                a2 = fmaf(qr[4 * t4 + 2], kv4.z, a2);
                a3 = fmaf(qr[4 * t4 + 3], kv4.w, a3);
            }
            float s = ((a0 + a1) + (a2 + a3)) * 0.125f;
            sl[lane * 66 + jj] = (_Float16)s;
            rowmax = fmaxf(rowmax, s);
        }
        float newm = fmaxf(m, rowmax);
        float corr = __expf(m - newm);
        lsum *= corr;
        #pragma unroll
        for (int d = 0; d < 64; d++) orow[d] *= corr;

        // ---- stage V block ----
        {
            const __bf16* vp = v + (plane + (size_t)idx[c] * BS_) * DH_;
            __syncthreads();
            #pragma unroll
            for (int i = 0; i < 8; i++) {
                int ch = i * 64 + lane;
                bf16x8 t = *(const bf16x8*)(vp + ch * 8);
                int jj = ch >> 3, d0 = (ch & 7) * 8;
                #pragma unroll
                for (int j = 0; j < 8; j++) kvf[jj * KVS + d0 + j] = (float)t[j];
            }
            __syncthreads();
        }
        // ---- PV with online rescale ----
        for (int jj = 0; jj < 64; jj++) {
            float p = __expf((float)sl[lane * 66 + jj] - newm);
            lsum += p;
            const float4* r4 = (const float4*)&kvf[jj * KVS];
            #pragma unroll
            for (int t4 = 0; t4 < 16; t4++) {
                float4 v4 = r4[t4];
                orow[4 * t4 + 0] = fmaf(p, v4.x, orow[4 * t4 + 0]);
                orow[4 * t4 + 1] = fmaf(p, v4.y, orow[4 * t4 + 1]);
                orow[4 * t4 + 2] = fmaf(p, v4.z, orow[4 * t4 + 2]);
                orow[4 * t4 + 3] = fmaf(p, v4.w, orow[4 * t4 + 3]);
            }
        }
        m = newm;
    }

    float inv = 1.f / lsum;
    __bf16* op = o + ((size_t)b * S_ + (size_t)n * BS_ + lane) * D_ + hh * DH_;
    #pragma unroll
    for (int i = 0; i < 8; i++) {
        bf16x8 t;
        #pragma unroll
        for (int j = 0; j < 8; j++) t[j] = (__bf16)(orow[i * 8 + j] * inv);
        *(bf16x8*)(op + i * 8) = t;
    }
}

// ---------------------------------------------------------------------------
// Row LayerNorm: fp32 in -> fp32 out + bf16 out. 64 thr/row.
// ---------------------------------------------------------------------------
__global__ __launch_bounds__(64) void ln_kernel(
    const float* in, float* outp, __bf16* outb,
    const float* __restrict__ g, const float* __restrict__ bb)
{
    size_t r = blockIdx.x;
    int t = threadIdx.x;
    const float4* ip = (const float4*)(in + r * D_);
    float4 x0 = ip[2 * t], x1 = ip[2 * t + 1];
    float s = x0.x + x0.y + x0.z + x0.w + x1.x + x1.y + x1.z + x1.w;
    #pragma unroll
    for (int off = 32; off; off >>= 1) s += __shfl_xor(s, off, 64);
    float mean = s * (1.0f / D_);
    float d0 = x0.x - mean, d1 = x0.y - mean, d2 = x0.z - mean, d3 = x0.w - mean;
    float d4 = x1.x - mean, d5 = x1.y - mean, d6 = x1.z - mean, d7 = x1.w - mean;
    float ss = d0*d0 + d1*d1 + d2*d2 + d3*d3 + d4*d4 + d5*d5 + d6*d6 + d7*d7;
    #pragma unroll
    for (int off = 32; off; off >>= 1) ss += __shfl_xor(ss, off, 64);
    float rs = rsqrtf(ss * (1.0f / D_) + 1e-5f);
    float4 g0 = ((const float4*)g)[2 * t], g1 = ((const float4*)g)[2 * t + 1];
    float4 b0 = ((const float4*)bb)[2 * t], b1 = ((const float4*)bb)[2 * t + 1];
    float y[8];
    y[0] = d0 * rs * g0.x + b0.x; y[1] = d1 * rs * g0.y + b0.y;
    y[2] = d2 * rs * g0.z + b0.z; y[3] = d3 * rs * g0.w + b0.w;
    y[4] = d4 * rs * g1.x + b1.x; y[5] = d5 * rs * g1.y + b1.y;
    y[6] = d6 * rs * g1.z + b1.z; y[7] = d7 * rs * g1.w + b1.w;
    float4* op = (float4*)(outp + r * D_);
    op[2 * t]     = (float4){y[0], y[1], y[2], y[3]};
    op[2 * t + 1] = (float4){y[4], y[5], y[6], y[7]};
    bf16x8 hb;
    #pragma unroll
    for (int j = 0; j < 8; j++) hb[j] = (__bf16)y[j];
    *(bf16x8*)(outb + r * D_ + t * 8) = hb;
}

// ---------------------------------------------------------------------------
// Head (fp32): out[b,:] = tanh(relu(h[b,0,:] @ w_dense + b_dense) @ w_out + b_out)
// ---------------------------------------------------------------------------
__global__ __launch_bounds__(256) void head_kernel(
    const float* __restrict__ h, const float* __restrict__ wd,
    const float* __restrict__ bd, const float* __restrict__ wo,
    const float* __restrict__ bo, float* __restrict__ out)
{
    __shared__ float hrow[D_];
    __shared__ float red[8];
    int b = blockIdx.x;
    int tid = threadIdx.x;
    if (tid < 128) ((float4*)hrow)[tid] = ((const float4*)(h + (size_t)b * S_ * D_))[tid];
    __syncthreads();
    float p0 = 0.f, p1 = 0.f;
    #pragma unroll
    for (int jj = 0; jj < 4; jj++) {
        int j = tid + jj * 256;
        float acc = bd[j];
        for (int i = 0; i < D_; i++) acc += hrow[i] * wd[(size_t)i * 1024 + j];
        float dns = fmaxf(acc, 0.f);
        p0 += dns * wo[j * 2 + 0];
        p1 += dns * wo[j * 2 + 1];
    }
    #pragma unroll
    for (int off = 32; off; off >>= 1) { p0 += __shfl_xor(p0, off, 64); p1 += __shfl_xor(p1, off, 64); }
    int wid = tid >> 6;
    if ((tid & 63) == 0) { red[wid * 2] = p0; red[wid * 2 + 1] = p1; }
    __syncthreads();
    if (tid == 0) {
        float t0 = red[0] + red[2] + red[4] + red[6] + bo[0];
        float t1 = red[1] + red[3] + red[5] + red[7] + bo[1];
        out[b * 2 + 0] = tanhf(t0);
        out[b * 2 + 1] = tanhf(t1);
    }
}

// ---------------------------------------------------------------------------
extern "C" void kernel_launch(void* const* d_in, const int* in_sizes, int n_in,
                              void* d_out, int out_size, void* d_ws, size_t ws_size,
                              hipStream_t stream) {
    (void)in_sizes; (void)n_in; (void)out_size; (void)ws_size;
    const float* x       = (const float*)d_in[0];
    const float* w_embed = (const float*)d_in[1];
    const float* b_embed = (const float*)d_in[2];
    const float* pos_emb = (const float*)d_in[3];
    const float* Wq      = (const float*)d_in[4];
    const float* bq      = (const float*)d_in[5];
    const float* Wk      = (const float*)d_in[6];
    const float* bk      = (const float*)d_in[7];
    const float* Wv      = (const float*)d_in[8];
    const float* bv      = (const float*)d_in[9];
    const float* Wo      = (const float*)d_in[10];
    const float* bo      = (const float*)d_in[11];
    const float* ln1_g   = (const float*)d_in[12];
    const float* ln1_b   = (const float*)d_in[13];
    const float* W1      = (const float*)d_in[14];
    const float* b1      = (const float*)d_in[15];
    const float* W2      = (const float*)d_in[16];
    const float* b2      = (const float*)d_in[17];
    const float* ln2_g   = (const float*)d_in[18];
    const float* ln2_b   = (const float*)d_in[19];
    const float* w_dense = (const float*)d_in[20];
    const float* b_dense = (const float*)d_in[21];
    const float* w_out   = (const float*)d_in[22];
    const float* b_out   = (const float*)d_in[23];
    const int*   rb      = (const int*)d_in[24];
    float* out = (float*)d_out;

    // Workspace layout (total 136 MiB):
    //  h fp32 (32M) | h_bf (16M) | big bf16 region 64M: qkv(48M)+o(16M) == ff1 | wt 24M
    const size_t PLANE = (size_t)B_ * H_ * S_ * DH_;  // 8,388,608
    float*  h    = (float*)d_ws;
    __bf16* h_bf = (__bf16*)(h + (size_t)MTOK * D_);
    __bf16* big  = (__bf16*)((char*)d_ws + (size_t)48 * 1024 * 1024);
    __bf16* qkv  = big;
    __bf16* o_bf = big + 3 * PLANE;
    __bf16* ff1  = big;                                // alias, lifetime-disjoint
    __bf16* wt   = (__bf16*)((char*)d_ws + (size_t)112 * 1024 * 1024);
    __bf16* wt_qkv = wt;                               // 3*L*D*D
    __bf16* wt_o   = wt_qkv + (size_t)3 * L_ * DD_;    // L*D*D
    __bf16* wt_1   = wt_o + (size_t)L_ * DD_;          // L*D*FF
    __bf16* wt_2   = wt_1 + (size_t)L_ * D_ * FF_;     // L*FF*D

    dim3 tb(32, 8);
    wconv_kernel<<<dim3(16, 16, L_), tb, 0, stream>>>(Wq, wt_qkv,                      D_, D_);
    wconv_kernel<<<dim3(16, 16, L_), tb, 0, stream>>>(Wk, wt_qkv + (size_t)L_ * DD_,   D_, D_);
    wconv_kernel<<<dim3(16, 16, L_), tb, 0, stream>>>(Wv, wt_qkv + (size_t)2 * L_ * DD_, D_, D_);
    wconv_kernel<<<dim3(16, 16, L_), tb, 0, stream>>>(Wo, wt_o,                        D_, D_);
    wconv_kernel<<<dim3(64, 16, L_), tb, 0, stream>>>(W1, wt_1,                        D_, FF_);
    wconv_kernel<<<dim3(16, 64, L_), tb, 0, stream>>>(W2, wt_2,                        FF_, D_);

    embed_kernel<<<MTOK, 128, 0, stream>>>(x, w_embed, b_embed, pos_emb, h, h_bf);

    for (int l = 0; l < L_; l++) {
        // QKV (fused, z selects q/k/v)
        mfma_gemm<<<dim3(D_ / 128, MTOK / 128, 3), 256, 0, stream>>>(
            h_bf, wt_qkv + (size_t)l * DD_, bq + l * D_, bk + l * D_, bv + l * D_,
            nullptr, nullptr, qkv, D_, D_, (long)L_ * DD_, (long)PLANE, 0, 1);

        attn_kernel<<<B_ * H_ * NB_, 64, 0, stream>>>(qkv, qkv + PLANE, qkv + 2 * PLANE, rb, o_bf);

        // h = h + o @ Wo + bo
        mfma_gemm<<<dim3(D_ / 128, MTOK / 128, 1), 256, 0, stream>>>(
            o_bf, wt_o + (size_t)l * DD_, bo + l * D_, bo + l * D_, bo + l * D_,
            h, h, nullptr, D_, D_, 0, 0, 0, 0);
        ln_kernel<<<MTOK, 64, 0, stream>>>(h, h, h_bf, ln1_g + l * D_, ln1_b + l * D_);

        // ff1 = relu(h @ W1 + b1), bf16 out
        mfma_gemm<<<dim3(FF_ / 128, MTOK / 128, 1), 256, 0, stream>>>(
            h_bf, wt_1 + (size_t)l * D_ * FF_, b1 + l * FF_, b1 + l * FF_, b1 + l * FF_,
            nullptr, nullptr, ff1, FF_, D_, 0, 0, 1, 0);

        // h = h + ff1 @ W2 + b2
        mfma_gemm<<<dim3(D_ / 128, MTOK / 128, 1), 256, 0, stream>>>(
            ff1, wt_2 + (size_t)l * FF_ * D_, b2 + l * D_, b2 + l * D_, b2 + l * D_,
            h, h, nullptr, D_, FF_, 0, 0, 0, 0);
        ln_kernel<<<MTOK, 64, 0, stream>>>(h, h, h_bf, ln2_g + l * D_, ln2_b + l * D_);
    }

    head_kernel<<<B_, 256, 0, stream>>>(h, w_dense, b_dense, w_out, b_out, out);
}

// Round 5
// 1550.279 us; speedup vs baseline: 5.7671x; 1.9533x over previous
//
#include <hip/hip_runtime.h>
#include <cstdint>
#include <cstddef>

// Problem constants
#define B_   8
#define NM_  10
#define T_   16376
#define D_   512
#define H_   8
#define DH_  64
#define L_   4
#define S_   2048
#define NB_  32
#define BS_  64
#define FF_  2048
#define MTOK (B_*S_)   // 16384 token rows
#define DD_  (D_*D_)

typedef __attribute__((ext_vector_type(8))) __bf16 bf16x8;
typedef __attribute__((ext_vector_type(4))) __bf16 bf16x4;
typedef __attribute__((ext_vector_type(4))) float f32x4;

__device__ __forceinline__ void async16(void* lds, const void* g) {
    __builtin_amdgcn_global_load_lds(
        (const __attribute__((address_space(1))) void*)g,
        (__attribute__((address_space(3))) void*)lds, 16, 0, 0);
}

// ---------------------------------------------------------------------------
// Weight transpose+convert: in (K x N fp32, z-strided) -> out (N x K bf16)
// ---------------------------------------------------------------------------
__global__ __launch_bounds__(256) void wconv_kernel(
    const float* __restrict__ in, __bf16* __restrict__ outp, int K, int N)
{
    __shared__ float t[32][33];
    size_t zo = (size_t)blockIdx.z * K * N;
    const float* ip = in + zo;
    __bf16* op = outp + zo;
    int n0 = blockIdx.x * 32, k0 = blockIdx.y * 32;
    int tx = threadIdx.x, ty = threadIdx.y;   // 32 x 8
    #pragma unroll
    for (int j = 0; j < 4; j++)
        t[ty + 8 * j][tx] = ip[(size_t)(k0 + ty + 8 * j) * N + n0 + tx];
    __syncthreads();
    #pragma unroll
    for (int j = 0; j < 4; j++)
        op[(size_t)(n0 + ty + 8 * j) * K + k0 + tx] = (__bf16)t[tx][ty + 8 * j];
}

// ---------------------------------------------------------------------------
// Embed: writes h (fp32) and h_bf (bf16)
// ---------------------------------------------------------------------------
__global__ __launch_bounds__(128) void embed_kernel(
    const float* __restrict__ x, const float* __restrict__ we,
    const float* __restrict__ be, const float* __restrict__ pe,
    float* __restrict__ h, __bf16* __restrict__ hb)
{
    int row = blockIdx.x;
    int b = row >> 11;
    int t = row & (S_ - 1);
    int tid = threadIdx.x;
    float* hp = h + (size_t)row * D_;
    __bf16* hbp = hb + (size_t)row * D_;
    const float* pep = pe + (size_t)t * D_;
    if (t == 0) {
        for (int d = tid; d < D_; d += 128) { float vv = pep[d]; hp[d] = vv; hbp[d] = (__bf16)vv; }
        return;
    }
    __shared__ float xv[80];
    int tp = t - 1;
    if (tid < 80)
        xv[tid] = x[(size_t)b * NM_ * T_ + (size_t)(tid >> 3) * T_ + (tid & 7) * 2047 + tp];
    __syncthreads();
    for (int d = tid; d < D_; d += 128) {
        float acc = be[d] + pep[d];
        #pragma unroll
        for (int mm = 0; mm < 80; mm++) acc += xv[mm] * we[mm * D_ + d];
        hp[d] = acc;
        hbp[d] = (__bf16)acc;
    }
}

// ---------------------------------------------------------------------------
// MFMA bf16 GEMM: C = A(MxK bf16) @ Wt^T + bias [+res] [relu]
// Wt is N x K bf16 (pre-transposed). 128x128 tile, BK=32, 256 thr (4 waves).
// Outputs: Cf (fp32 MxN, optional), Cb (bf16, optional).
// scatter==1: z in {0,1} -> (B,H,S,DH); z==2 -> V transposed (B,H,DH,S).
// ---------------------------------------------------------------------------
__global__ __launch_bounds__(256, 2) void mfma_gemm(
    const __bf16* __restrict__ A, const __bf16* __restrict__ Wt,
    const float* __restrict__ bias0, const float* __restrict__ bias1,
    const float* __restrict__ bias2,
    const float* res, float* Cf, __bf16* Cb,
    int N, int K, long wtz, long cbz, int relu, int scatter)
{
    __shared__ __align__(16) __bf16 As[128 * 32];
    __shared__ __align__(16) __bf16 Bs[128 * 32];
    int tid = threadIdx.x;
    int wave = tid >> 6;
    int lane = tid & 63;
    int bn = blockIdx.x * 128;
    int bm = blockIdx.y * 128;
    int z = blockIdx.z;
    const __bf16* Wz = Wt + (size_t)z * wtz;
    const float* bias = (z == 0) ? bias0 : (z == 1 ? bias1 : bias2);

    f32x4 acc[4][4];
    #pragma unroll
    for (int r = 0; r < 4; r++)
        #pragma unroll
        for (int c = 0; c < 4; c++) acc[r][c] = (f32x4){0.f, 0.f, 0.f, 0.f};

    const int wr = (wave >> 1) * 64;
    const int wc = (wave & 1) * 64;
    const int fr = lane & 15;
    const int fk = (lane >> 4) * 8;

    const int c0 = tid, c1 = tid + 256;
    const __bf16* Ag0 = A  + (size_t)(bm + (c0 >> 2)) * K + (c0 & 3) * 8;
    const __bf16* Ag1 = A  + (size_t)(bm + (c1 >> 2)) * K + (c1 & 3) * 8;
    const __bf16* Bg0 = Wz + (size_t)(bn + (c0 >> 2)) * K + (c0 & 3) * 8;
    const __bf16* Bg1 = Wz + (size_t)(bn + (c1 >> 2)) * K + (c1 & 3) * 8;
    __bf16* AsW0 = As + (size_t)(wave * 64) * 8;
    __bf16* AsW1 = As + (size_t)(256 + wave * 64) * 8;
    __bf16* BsW0 = Bs + (size_t)(wave * 64) * 8;
    __bf16* BsW1 = Bs + (size_t)(256 + wave * 64) * 8;

    for (int kk = 0; kk < K; kk += 32) {
        __syncthreads();
        async16(AsW0, Ag0 + kk);
        async16(AsW1, Ag1 + kk);
        async16(BsW0, Bg0 + kk);
        async16(BsW1, Bg1 + kk);
        __syncthreads();
        bf16x8 af[4], bfr[4];
        #pragma unroll
        for (int r = 0; r < 4; r++)
            af[r] = *(const bf16x8*)&As[(size_t)(wr + r * 16 + fr) * 32 + fk];
        #pragma unroll
        for (int c = 0; c < 4; c++)
            bfr[c] = *(const bf16x8*)&Bs[(size_t)(wc + c * 16 + fr) * 32 + fk];
        #pragma unroll
        for (int r = 0; r < 4; r++)
            #pragma unroll
            for (int c = 0; c < 4; c++)
                acc[r][c] = __builtin_amdgcn_mfma_f32_16x16x32_bf16(af[r], bfr[c], acc[r][c], 0, 0, 0);
    }

    // epilogue: C/D layout col = lane&15, row = (lane>>4)*4 + reg
    int rbase = bm + wr + (lane >> 4) * 4;
    #pragma unroll
    for (int c = 0; c < 4; c++) {
        int cg = bn + wc + c * 16 + fr;
        float bv = bias[cg];
        #pragma unroll
        for (int r = 0; r < 4; r++) {
            int rg0 = rbase + r * 16;   // 4-aligned
            float vals[4];
            #pragma unroll
            for (int i = 0; i < 4; i++) {
                float val = acc[r][c][i] + bv;
                if (relu) val = fmaxf(val, 0.f);
                if (res) val += res[(size_t)(rg0 + i) * N + cg];
                vals[i] = val;
            }
            if (Cf) {
                #pragma unroll
                for (int i = 0; i < 4; i++) Cf[(size_t)(rg0 + i) * N + cg] = vals[i];
            }
            if (Cb) {
                if (scatter) {
                    int bb = rg0 >> 11;
                    int s0 = rg0 & (S_ - 1);
                    int hh = cg >> 6, dh = cg & 63;
                    if (z == 2) {
                        // V transposed: (B,H,DH,S), pack 4 consecutive s
                        bf16x4 pk;
                        #pragma unroll
                        for (int i = 0; i < 4; i++) pk[i] = (__bf16)vals[i];
                        *(bf16x4*)(Cb + (size_t)z * cbz +
                                   ((((size_t)bb * H_ + hh) * DH_ + dh) * S_) + s0) = pk;
                    } else {
                        #pragma unroll
                        for (int i = 0; i < 4; i++)
                            (Cb + (size_t)z * cbz)[((((size_t)bb * H_ + hh) * S_ + s0 + i) * DH_) + dh] = (__bf16)vals[i];
                    }
                } else {
                    #pragma unroll
                    for (int i = 0; i < 4; i++) Cb[(size_t)(rg0 + i) * N + cg] = (__bf16)vals[i];
                }
            }
        }
    }
}

// ---------------------------------------------------------------------------
// MFMA block-sparse attention. One workgroup (4 waves) per (b,h,n); each wave
// owns 16 q-rows. K staged n-major, V^T staged d-major (from (B,H,DH,S)
// global layout). S^T = K·Q^T via MFMA (row stats at lane&15 -> 2 shuffles);
// P round-trips LDS m-major; PV via MFMA (A=P, B=V^T). Online softmax.
// ---------------------------------------------------------------------------
#define KSTR 72
__global__ __launch_bounds__(256, 4) void attn_kernel(
    const __bf16* __restrict__ q, const __bf16* __restrict__ k,
    const __bf16* __restrict__ vt, const int* __restrict__ rb,
    __bf16* __restrict__ o)
{
    __shared__ __align__(16) __bf16 Ks[64 * KSTR];
    __shared__ __align__(16) __bf16 Vs[64 * KSTR];
    __shared__ __align__(16) __bf16 Ps[64 * KSTR];
    int bid = blockIdx.x;
    int n = bid & (NB_ - 1);
    int hh = (bid >> 5) & (H_ - 1);
    int b = bid >> 8;
    int tid = threadIdx.x;
    int wave = tid >> 6;
    int lane = tid & 63;
    const int fr = lane & 15;
    const int fq = lane >> 4;

    int idx[6];
    idx[0] = 0;
    idx[1] = n > 0 ? n - 1 : 0;
    idx[2] = n;
    idx[3] = n < NB_ - 1 ? n + 1 : NB_ - 1;
    idx[4] = rb[n * 2 + 0];
    idx[5] = rb[n * 2 + 1];

    const size_t plane = ((size_t)b * H_ + hh) * S_;           // q,k row base
    const __bf16* vtb = vt + plane * DH_;                      // (B,H,DH,S) plane

    // Q fragments (B-operand): row m = wave*16 + fr, k = fq*8 (+32)
    const __bf16* qrow = q + (plane + (size_t)n * BS_ + wave * 16 + fr) * DH_ + fq * 8;
    bf16x8 qf0 = *(const bf16x8*)qrow;
    bf16x8 qf1 = *(const bf16x8*)(qrow + 32);

    f32x4 oacc[4];
    #pragma unroll
    for (int dt = 0; dt < 4; dt++) oacc[dt] = (f32x4){0.f, 0.f, 0.f, 0.f};
    float mrow = -1e30f, lrow = 0.f;

    for (int c = 0; c < 6; c++) {
        bool dup = false;
        #pragma unroll
        for (int j = 0; j < 6; j++) if (j < c && idx[j] == idx[c]) dup = true;
        if (dup) continue;   // uniform across workgroup

        __syncthreads();     // prior iteration's reads of Ks/Vs complete
        // ---- stage K (n-major) and V^T (d-major), 512 16B chunks each ----
        {
            const __bf16* kb = k + (plane + (size_t)idx[c] * BS_) * DH_;
            const __bf16* vb = vtb + (size_t)idx[c] * BS_;
            #pragma unroll
            for (int u = 0; u < 2; u++) {
                int ch = tid + u * 256;
                int row = ch >> 3, d0 = (ch & 7) * 8;
                *(bf16x8*)&Ks[row * KSTR + d0] = *(const bf16x8*)(kb + row * DH_ + d0);
                *(bf16x8*)&Vs[row * KSTR + d0] = *(const bf16x8*)(vb + (size_t)row * S_ + d0);
            }
        }
        __syncthreads();

        // ---- S^T = K·Q^T : rows = keys, cols = q ----
        f32x4 st[4];
        #pragma unroll
        for (int t = 0; t < 4; t++) {
            bf16x8 ka0 = *(const bf16x8*)&Ks[(t * 16 + fr) * KSTR + fq * 8];
            bf16x8 ka1 = *(const bf16x8*)&Ks[(t * 16 + fr) * KSTR + 32 + fq * 8];
            st[t] = __builtin_amdgcn_mfma_f32_16x16x32_bf16(ka0, qf0, (f32x4){0.f,0.f,0.f,0.f}, 0, 0, 0);
            st[t] = __builtin_amdgcn_mfma_f32_16x16x32_bf16(ka1, qf1, st[t], 0, 0, 0);
        }
        // element (n_loc = t*16 + fq*4 + i, m = fr); scale then row stats over n
        float rmax = -1e30f;
        #pragma unroll
        for (int t = 0; t < 4; t++)
            #pragma unroll
            for (int i = 0; i < 4; i++) {
                st[t][i] *= 0.125f;
                rmax = fmaxf(rmax, st[t][i]);
            }
        rmax = fmaxf(rmax, __shfl_xor(rmax, 16));
        rmax = fmaxf(rmax, __shfl_xor(rmax, 32));
        float newm = fmaxf(mrow, rmax);
        float corr = __expf(mrow - newm);
        mrow = newm;
        float psum = 0.f;
        #pragma unroll
        for (int t = 0; t < 4; t++) {
            bf16x4 pk;
            #pragma unroll
            for (int i = 0; i < 4; i++) {
                float p = __expf(st[t][i] - newm);
                psum += p;
                pk[i] = (__bf16)p;
            }
            // P m-major: row m = wave*16 + fr, cols n = t*16 + fq*4 .. +3
            *(bf16x4*)&Ps[(wave * 16 + fr) * KSTR + t * 16 + fq * 4] = pk;
        }
        psum += __shfl_xor(psum, 16);
        psum += __shfl_xor(psum, 32);
        lrow = lrow * corr + psum;

        // ---- rescale O (rows in C layout: m_loc = fq*4 + i) ----
        #pragma unroll
        for (int i = 0; i < 4; i++) {
            float ci = __shfl(corr, fq * 4 + i);
            #pragma unroll
            for (int dt = 0; dt < 4; dt++) oacc[dt][i] *= ci;
        }

        // ---- O += P·V : A = P (m-major), B = V^T (d-major) ----
        bf16x8 pa0 = *(const bf16x8*)&Ps[(wave * 16 + fr) * KSTR + fq * 8];
        bf16x8 pa1 = *(const bf16x8*)&Ps[(wave * 16 + fr) * KSTR + 32 + fq * 8];
        #pragma unroll
        for (int dt = 0; dt < 4; dt++) {
            bf16x8 vb0 = *(const bf16x8*)&Vs[(dt * 16 + fr) * KSTR + fq * 8];
            bf16x8 vb1 = *(const bf16x8*)&Vs[(dt * 16 + fr) * KSTR + 32 + fq * 8];
            oacc[dt] = __builtin_amdgcn_mfma_f32_16x16x32_bf16(pa0, vb0, oacc[dt], 0, 0, 0);
            oacc[dt] = __builtin_amdgcn_mfma_f32_16x16x32_bf16(pa1, vb1, oacc[dt], 0, 0, 0);
        }
    }

    // ---- epilogue: normalize rows, write (B,S,D) bf16 ----
    float linv = 1.f / lrow;
    #pragma unroll
    for (int i = 0; i < 4; i++) {
        float li = __shfl(linv, fq * 4 + i);
        int s = n * BS_ + wave * 16 + fq * 4 + i;
        __bf16* op = o + ((size_t)b * S_ + s) * D_ + hh * DH_ + fr;
        #pragma unroll
        for (int dt = 0; dt < 4; dt++)
            op[dt * 16] = (__bf16)(oacc[dt][i] * li);
    }
}

// ---------------------------------------------------------------------------
// Row LayerNorm: fp32 in -> fp32 out + bf16 out. 64 thr/row.
// ---------------------------------------------------------------------------
__global__ __launch_bounds__(64) void ln_kernel(
    const float* in, float* outp, __bf16* outb,
    const float* __restrict__ g, const float* __restrict__ bb)
{
    size_t r = blockIdx.x;
    int t = threadIdx.x;
    const float4* ip = (const float4*)(in + r * D_);
    float4 x0 = ip[2 * t], x1 = ip[2 * t + 1];
    float s = x0.x + x0.y + x0.z + x0.w + x1.x + x1.y + x1.z + x1.w;
    #pragma unroll
    for (int off = 32; off; off >>= 1) s += __shfl_xor(s, off, 64);
    float mean = s * (1.0f / D_);
    float d0 = x0.x - mean, d1 = x0.y - mean, d2 = x0.z - mean, d3 = x0.w - mean;
    float d4 = x1.x - mean, d5 = x1.y - mean, d6 = x1.z - mean, d7 = x1.w - mean;
    float ss = d0*d0 + d1*d1 + d2*d2 + d3*d3 + d4*d4 + d5*d5 + d6*d6 + d7*d7;
    #pragma unroll
    for (int off = 32; off; off >>= 1) ss += __shfl_xor(ss, off, 64);
    float rs = rsqrtf(ss * (1.0f / D_) + 1e-5f);
    float4 g0 = ((const float4*)g)[2 * t], g1 = ((const float4*)g)[2 * t + 1];
    float4 b0 = ((const float4*)bb)[2 * t], b1 = ((const float4*)bb)[2 * t + 1];
    float y[8];
    y[0] = d0 * rs * g0.x + b0.x; y[1] = d1 * rs * g0.y + b0.y;
    y[2] = d2 * rs * g0.z + b0.z; y[3] = d3 * rs * g0.w + b0.w;
    y[4] = d4 * rs * g1.x + b1.x; y[5] = d5 * rs * g1.y + b1.y;
    y[6] = d6 * rs * g1.z + b1.z; y[7] = d7 * rs * g1.w + b1.w;
    float4* op = (float4*)(outp + r * D_);
    op[2 * t]     = (float4){y[0], y[1], y[2], y[3]};
    op[2 * t + 1] = (float4){y[4], y[5], y[6], y[7]};
    bf16x8 hb;
    #pragma unroll
    for (int j = 0; j < 8; j++) hb[j] = (__bf16)y[j];
    *(bf16x8*)(outb + r * D_ + t * 8) = hb;
}

// ---------------------------------------------------------------------------
// Head (fp32): out[b,:] = tanh(relu(h[b,0,:] @ w_dense + b_dense) @ w_out + b_out)
// ---------------------------------------------------------------------------
__global__ __launch_bounds__(256) void head_kernel(
    const float* __restrict__ h, const float* __restrict__ wd,
    const float* __restrict__ bd, const float* __restrict__ wo,
    const float* __restrict__ bo, float* __restrict__ out)
{
    __shared__ float hrow[D_];
    __shared__ float red[8];
    int b = blockIdx.x;
    int tid = threadIdx.x;
    if (tid < 128) ((float4*)hrow)[tid] = ((const float4*)(h + (size_t)b * S_ * D_))[tid];
    __syncthreads();
    float p0 = 0.f, p1 = 0.f;
    #pragma unroll
    for (int jj = 0; jj < 4; jj++) {
        int j = tid + jj * 256;
        float acc = bd[j];
        for (int i = 0; i < D_; i++) acc += hrow[i] * wd[(size_t)i * 1024 + j];
        float dns = fmaxf(acc, 0.f);
        p0 += dns * wo[j * 2 + 0];
        p1 += dns * wo[j * 2 + 1];
    }
    #pragma unroll
    for (int off = 32; off; off >>= 1) { p0 += __shfl_xor(p0, off, 64); p1 += __shfl_xor(p1, off, 64); }
    int wid = tid >> 6;
    if ((tid & 63) == 0) { red[wid * 2] = p0; red[wid * 2 + 1] = p1; }
    __syncthreads();
    if (tid == 0) {
        float t0 = red[0] + red[2] + red[4] + red[6] + bo[0];
        float t1 = red[1] + red[3] + red[5] + red[7] + bo[1];
        out[b * 2 + 0] = tanhf(t0);
        out[b * 2 + 1] = tanhf(t1);
    }
}

// ---------------------------------------------------------------------------
extern "C" void kernel_launch(void* const* d_in, const int* in_sizes, int n_in,
                              void* d_out, int out_size, void* d_ws, size_t ws_size,
                              hipStream_t stream) {
    (void)in_sizes; (void)n_in; (void)out_size; (void)ws_size;
    const float* x       = (const float*)d_in[0];
    const float* w_embed = (const float*)d_in[1];
    const float* b_embed = (const float*)d_in[2];
    const float* pos_emb = (const float*)d_in[3];
    const float* Wq      = (const float*)d_in[4];
    const float* bq      = (const float*)d_in[5];
    const float* Wk      = (const float*)d_in[6];
    const float* bk      = (const float*)d_in[7];
    const float* Wv      = (const float*)d_in[8];
    const float* bv      = (const float*)d_in[9];
    const float* Wo      = (const float*)d_in[10];
    const float* bo      = (const float*)d_in[11];
    const float* ln1_g   = (const float*)d_in[12];
    const float* ln1_b   = (const float*)d_in[13];
    const float* W1      = (const float*)d_in[14];
    const float* b1      = (const float*)d_in[15];
    const float* W2      = (const float*)d_in[16];
    const float* b2      = (const float*)d_in[17];
    const float* ln2_g   = (const float*)d_in[18];
    const float* ln2_b   = (const float*)d_in[19];
    const float* w_dense = (const float*)d_in[20];
    const float* b_dense = (const float*)d_in[21];
    const float* w_out   = (const float*)d_in[22];
    const float* b_out   = (const float*)d_in[23];
    const int*   rb      = (const int*)d_in[24];
    float* out = (float*)d_out;

    // Workspace layout (total 136 MiB):
    //  h fp32 (32M) | h_bf (16M) | big bf16 region 64M: qkv(48M)+o(16M) == ff1 | wt 24M
    const size_t PLANE = (size_t)B_ * H_ * S_ * DH_;  // 8,388,608
    float*  h    = (float*)d_ws;
    __bf16* h_bf = (__bf16*)(h + (size_t)MTOK * D_);
    __bf16* big  = (__bf16*)((char*)d_ws + (size_t)48 * 1024 * 1024);
    __bf16* qkv  = big;
    __bf16* o_bf = big + 3 * PLANE;
    __bf16* ff1  = big;                                // alias, lifetime-disjoint
    __bf16* wt   = (__bf16*)((char*)d_ws + (size_t)112 * 1024 * 1024);
    __bf16* wt_qkv = wt;                               // 3*L*D*D
    __bf16* wt_o   = wt_qkv + (size_t)3 * L_ * DD_;    // L*D*D
    __bf16* wt_1   = wt_o + (size_t)L_ * DD_;          // L*D*FF
    __bf16* wt_2   = wt_1 + (size_t)L_ * D_ * FF_;     // L*FF*D

    dim3 tb(32, 8);
    wconv_kernel<<<dim3(16, 16, L_), tb, 0, stream>>>(Wq, wt_qkv,                      D_, D_);
    wconv_kernel<<<dim3(16, 16, L_), tb, 0, stream>>>(Wk, wt_qkv + (size_t)L_ * DD_,   D_, D_);
    wconv_kernel<<<dim3(16, 16, L_), tb, 0, stream>>>(Wv, wt_qkv + (size_t)2 * L_ * DD_, D_, D_);
    wconv_kernel<<<dim3(16, 16, L_), tb, 0, stream>>>(Wo, wt_o,                        D_, D_);
    wconv_kernel<<<dim3(64, 16, L_), tb, 0, stream>>>(W1, wt_1,                        D_, FF_);
    wconv_kernel<<<dim3(16, 64, L_), tb, 0, stream>>>(W2, wt_2,                        FF_, D_);

    embed_kernel<<<MTOK, 128, 0, stream>>>(x, w_embed, b_embed, pos_emb, h, h_bf);

    for (int l = 0; l < L_; l++) {
        // QKV (fused, z selects q/k/v; v scattered transposed)
        mfma_gemm<<<dim3(D_ / 128, MTOK / 128, 3), 256, 0, stream>>>(
            h_bf, wt_qkv + (size_t)l * DD_, bq + l * D_, bk + l * D_, bv + l * D_,
            nullptr, nullptr, qkv, D_, D_, (long)L_ * DD_, (long)PLANE, 0, 1);

        attn_kernel<<<B_ * H_ * NB_, 256, 0, stream>>>(qkv, qkv + PLANE, qkv + 2 * PLANE, rb, o_bf);

        // h = h + o @ Wo + bo
        mfma_gemm<<<dim3(D_ / 128, MTOK / 128, 1), 256, 0, stream>>>(
            o_bf, wt_o + (size_t)l * DD_, bo + l * D_, bo + l * D_, bo + l * D_,
            h, h, nullptr, D_, D_, 0, 0, 0, 0);
        ln_kernel<<<MTOK, 64, 0, stream>>>(h, h, h_bf, ln1_g + l * D_, ln1_b + l * D_);

        // ff1 = relu(h @ W1 + b1), bf16 out
        mfma_gemm<<<dim3(FF_ / 128, MTOK / 128, 1), 256, 0, stream>>>(
            h_bf, wt_1 + (size_t)l * D_ * FF_, b1 + l * FF_, b1 + l * FF_, b1 + l * FF_,
            nullptr, nullptr, ff1, FF_, D_, 0, 0, 1, 0);

        // h = h + ff1 @ W2 + b2
        mfma_gemm<<<dim3(D_ / 128, MTOK / 128, 1), 256, 0, stream>>>(
            ff1, wt_2 + (size_t)l * FF_ * D_, b2 + l * D_, b2 + l * D_, b2 + l * D_,
            h, h, nullptr, D_, FF_, 0, 0, 0, 0);
        ln_kernel<<<MTOK, 64, 0, stream>>>(h, h, h_bf, ln2_g + l * D_, ln2_b + l * D_);
    }

    head_kernel<<<B_, 256, 0, stream>>>(h, w_dense, b_dense, w_out, b_out, out);
}

// Round 6
// 1413.459 us; speedup vs baseline: 6.3253x; 1.0968x over previous
//
#include <hip/hip_runtime.h>
#include <cstdint>
#include <cstddef>

// Problem constants
#define B_   8
#define NM_  10
#define T_   16376
#define D_   512
#define H_   8
#define DH_  64
#define L_   4
#define S_   2048
#define NB_  32
#define BS_  64
#define FF_  2048
#define MTOK (B_*S_)   // 16384 token rows
#define DD_  (D_*D_)
#define KE_  96        // embed K padded (80 -> 96)

typedef __attribute__((ext_vector_type(8))) __bf16 bf16x8;
typedef __attribute__((ext_vector_type(4))) __bf16 bf16x4;
typedef __attribute__((ext_vector_type(4))) float f32x4;

__device__ __forceinline__ void async16(void* lds, const void* g) {
    __builtin_amdgcn_global_load_lds(
        (const __attribute__((address_space(1))) void*)g,
        (__attribute__((address_space(3))) void*)lds, 16, 0, 0);
}

// ---------------------------------------------------------------------------
// Weight transpose+convert: in (K x N fp32, z-strided) -> out (N x Kp bf16),
// zero-padding k in [K, Kp). Grid: (N/32, Kp/32, Z).
// ---------------------------------------------------------------------------
__global__ __launch_bounds__(256) void wconv_kernel(
    const float* __restrict__ in, __bf16* __restrict__ outp, int K, int N, int Kp)
{
    __shared__ float t[32][33];
    const float* ip = in + (size_t)blockIdx.z * K * N;
    __bf16* op = outp + (size_t)blockIdx.z * N * Kp;
    int n0 = blockIdx.x * 32, k0 = blockIdx.y * 32;
    int tx = threadIdx.x, ty = threadIdx.y;   // 32 x 8
    #pragma unroll
    for (int j = 0; j < 4; j++) {
        int k = k0 + ty + 8 * j;
        t[ty + 8 * j][tx] = (k < K) ? ip[(size_t)k * N + n0 + tx] : 0.f;
    }
    __syncthreads();
    #pragma unroll
    for (int j = 0; j < 4; j++)
        op[(size_t)(n0 + ty + 8 * j) * Kp + k0 + tx] = (__bf16)t[tx][ty + 8 * j];
}

// ---------------------------------------------------------------------------
// Build xr (MTOK x KE_ bf16): xr[b*2048+t][m] = x[b, m/8, (m%8)*2047 + t-1]
// for t>=1, m<80; else 0. One block per 64 rows (same b).
// ---------------------------------------------------------------------------
__global__ __launch_bounds__(256) void xbuild_kernel(
    const float* __restrict__ x, __bf16* __restrict__ xr)
{
    __shared__ float xs[64][97];
    int row0 = blockIdx.x * 64;
    int b = row0 >> 11;
    int t0 = row0 & (S_ - 1);
    int tid = threadIdx.x;
    int lane = tid & 63;
    int mq = tid >> 6;          // 0..3
    // phase 1: coalesced loads over t for each m
    for (int mb = 0; mb < 24; mb++) {
        int m = mb * 4 + mq;    // 0..95
        int t = t0 + lane;
        float v = 0.f;
        if (m < 80 && t > 0)
            v = x[(size_t)b * NM_ * T_ + (size_t)(m >> 3) * T_ + (m & 7) * 2047 + (t - 1)];
        xs[lane][m] = v;
    }
    __syncthreads();
    // phase 2: row-major bf16 write, 8B chunks
    #pragma unroll
    for (int u = 0; u < 6; u++) {
        int ch = tid + u * 256;          // 0..1535
        int row = ch / 24, c4 = (ch % 24) * 4;
        bf16x4 pk;
        #pragma unroll
        for (int i = 0; i < 4; i++) pk[i] = (__bf16)xs[row][c4 + i];
        *(bf16x4*)&xr[(size_t)(row0 + row) * KE_ + c4] = pk;
    }
}

// ---------------------------------------------------------------------------
// MFMA bf16 GEMM: C = A(MxK bf16) @ Wt^T + bias [+res] [+posemb] [relu]
// Wt is N x K bf16 (pre-transposed). 128x128 tile, BK=32, 256 thr (4 waves).
// Outputs: Cf (fp32 MxN, optional), Cb (bf16, optional).
// scatter==1: z in {0,1} -> (B,H,S,DH); z==2 -> V transposed (B,H,DH,S).
// pe != null: val += pe[(row&2047)*N + col]; row with t==0 -> val = pe[col].
// ---------------------------------------------------------------------------
__global__ __launch_bounds__(256, 2) void mfma_gemm(
    const __bf16* __restrict__ A, const __bf16* __restrict__ Wt,
    const float* __restrict__ bias0, const float* __restrict__ bias1,
    const float* __restrict__ bias2,
    const float* res, const float* __restrict__ pe, float* Cf, __bf16* Cb,
    int N, int K, long wtz, long cbz, int relu, int scatter)
{
    __shared__ __align__(16) __bf16 As[128 * 32];
    __shared__ __align__(16) __bf16 Bs[128 * 32];
    int tid = threadIdx.x;
    int wave = tid >> 6;
    int lane = tid & 63;
    int bn = blockIdx.x * 128;
    int bm = blockIdx.y * 128;
    int z = blockIdx.z;
    const __bf16* Wz = Wt + (size_t)z * wtz;
    const float* bias = (z == 0) ? bias0 : (z == 1 ? bias1 : bias2);

    f32x4 acc[4][4];
    #pragma unroll
    for (int r = 0; r < 4; r++)
        #pragma unroll
        for (int c = 0; c < 4; c++) acc[r][c] = (f32x4){0.f, 0.f, 0.f, 0.f};

    const int wr = (wave >> 1) * 64;
    const int wc = (wave & 1) * 64;
    const int fr = lane & 15;
    const int fk = (lane >> 4) * 8;

    const int c0 = tid, c1 = tid + 256;
    const __bf16* Ag0 = A  + (size_t)(bm + (c0 >> 2)) * K + (c0 & 3) * 8;
    const __bf16* Ag1 = A  + (size_t)(bm + (c1 >> 2)) * K + (c1 & 3) * 8;
    const __bf16* Bg0 = Wz + (size_t)(bn + (c0 >> 2)) * K + (c0 & 3) * 8;
    const __bf16* Bg1 = Wz + (size_t)(bn + (c1 >> 2)) * K + (c1 & 3) * 8;
    __bf16* AsW0 = As + (size_t)(wave * 64) * 8;
    __bf16* AsW1 = As + (size_t)(256 + wave * 64) * 8;
    __bf16* BsW0 = Bs + (size_t)(wave * 64) * 8;
    __bf16* BsW1 = Bs + (size_t)(256 + wave * 64) * 8;

    for (int kk = 0; kk < K; kk += 32) {
        __syncthreads();
        async16(AsW0, Ag0 + kk);
        async16(AsW1, Ag1 + kk);
        async16(BsW0, Bg0 + kk);
        async16(BsW1, Bg1 + kk);
        __syncthreads();
        bf16x8 af[4], bfr[4];
        #pragma unroll
        for (int r = 0; r < 4; r++)
            af[r] = *(const bf16x8*)&As[(size_t)(wr + r * 16 + fr) * 32 + fk];
        #pragma unroll
        for (int c = 0; c < 4; c++)
            bfr[c] = *(const bf16x8*)&Bs[(size_t)(wc + c * 16 + fr) * 32 + fk];
        #pragma unroll
        for (int r = 0; r < 4; r++)
            #pragma unroll
            for (int c = 0; c < 4; c++)
                acc[r][c] = __builtin_amdgcn_mfma_f32_16x16x32_bf16(af[r], bfr[c], acc[r][c], 0, 0, 0);
    }

    // epilogue: C/D layout col = lane&15, row = (lane>>4)*4 + reg
    int rbase = bm + wr + (lane >> 4) * 4;
    #pragma unroll
    for (int c = 0; c < 4; c++) {
        int cg = bn + wc + c * 16 + fr;
        float bv = bias[cg];
        #pragma unroll
        for (int r = 0; r < 4; r++) {
            int rg0 = rbase + r * 16;   // 4-aligned
            float vals[4];
            #pragma unroll
            for (int i = 0; i < 4; i++) {
                float val = acc[r][c][i] + bv;
                if (relu) val = fmaxf(val, 0.f);
                if (res) val += res[(size_t)(rg0 + i) * N + cg];
                if (pe) {
                    int t = (rg0 + i) & (S_ - 1);
                    val = (t == 0) ? pe[cg] : val + pe[(size_t)t * N + cg];
                }
                vals[i] = val;
            }
            if (Cf) {
                #pragma unroll
                for (int i = 0; i < 4; i++) Cf[(size_t)(rg0 + i) * N + cg] = vals[i];
            }
            if (Cb) {
                if (scatter) {
                    int bb = rg0 >> 11;
                    int s0 = rg0 & (S_ - 1);
                    int hh = cg >> 6, dh = cg & 63;
                    if (z == 2) {
                        // V transposed: (B,H,DH,S), pack 4 consecutive s
                        bf16x4 pk;
                        #pragma unroll
                        for (int i = 0; i < 4; i++) pk[i] = (__bf16)vals[i];
                        *(bf16x4*)(Cb + (size_t)z * cbz +
                                   ((((size_t)bb * H_ + hh) * DH_ + dh) * S_) + s0) = pk;
                    } else {
                        #pragma unroll
                        for (int i = 0; i < 4; i++)
                            (Cb + (size_t)z * cbz)[((((size_t)bb * H_ + hh) * S_ + s0 + i) * DH_) + dh] = (__bf16)vals[i];
                    }
                } else {
                    #pragma unroll
                    for (int i = 0; i < 4; i++) Cb[(size_t)(rg0 + i) * N + cg] = (__bf16)vals[i];
                }
            }
        }
    }
}

// ---------------------------------------------------------------------------
// MFMA block-sparse attention. One workgroup (4 waves) per (b,h,n); each wave
// owns 16 q-rows. K staged n-major, V^T staged d-major (from (B,H,DH,S)
// global layout). S^T = K·Q^T via MFMA (row stats at lane&15 -> 2 shuffles);
// P round-trips LDS m-major; PV via MFMA (A=P, B=V^T). Online softmax.
// ---------------------------------------------------------------------------
#define KSTR 72
__global__ __launch_bounds__(256, 4) void attn_kernel(
    const __bf16* __restrict__ q, const __bf16* __restrict__ k,
    const __bf16* __restrict__ vt, const int* __restrict__ rb,
    __bf16* __restrict__ o)
{
    __shared__ __align__(16) __bf16 Ks[64 * KSTR];
    __shared__ __align__(16) __bf16 Vs[64 * KSTR];
    __shared__ __align__(16) __bf16 Ps[64 * KSTR];
    int bid = blockIdx.x;
    int n = bid & (NB_ - 1);
    int hh = (bid >> 5) & (H_ - 1);
    int b = bid >> 8;
    int tid = threadIdx.x;
    int wave = tid >> 6;
    int lane = tid & 63;
    const int fr = lane & 15;
    const int fq = lane >> 4;

    int idx[6];
    idx[0] = 0;
    idx[1] = n > 0 ? n - 1 : 0;
    idx[2] = n;
    idx[3] = n < NB_ - 1 ? n + 1 : NB_ - 1;
    idx[4] = rb[n * 2 + 0];
    idx[5] = rb[n * 2 + 1];

    const size_t plane = ((size_t)b * H_ + hh) * S_;           // q,k row base
    const __bf16* vtb = vt + plane * DH_;                      // (B,H,DH,S) plane

    // Q fragments (B-operand): row m = wave*16 + fr, k = fq*8 (+32)
    const __bf16* qrow = q + (plane + (size_t)n * BS_ + wave * 16 + fr) * DH_ + fq * 8;
    bf16x8 qf0 = *(const bf16x8*)qrow;
    bf16x8 qf1 = *(const bf16x8*)(qrow + 32);

    f32x4 oacc[4];
    #pragma unroll
    for (int dt = 0; dt < 4; dt++) oacc[dt] = (f32x4){0.f, 0.f, 0.f, 0.f};
    float mrow = -1e30f, lrow = 0.f;

    for (int c = 0; c < 6; c++) {
        bool dup = false;
        #pragma unroll
        for (int j = 0; j < 6; j++) if (j < c && idx[j] == idx[c]) dup = true;
        if (dup) continue;   // uniform across workgroup

        __syncthreads();     // prior iteration's reads of Ks/Vs complete
        // ---- stage K (n-major) and V^T (d-major), 512 16B chunks each ----
        {
            const __bf16* kb = k + (plane + (size_t)idx[c] * BS_) * DH_;
            const __bf16* vb = vtb + (size_t)idx[c] * BS_;
            #pragma unroll
            for (int u = 0; u < 2; u++) {
                int ch = tid + u * 256;
                int row = ch >> 3, d0 = (ch & 7) * 8;
                *(bf16x8*)&Ks[row * KSTR + d0] = *(const bf16x8*)(kb + row * DH_ + d0);
                *(bf16x8*)&Vs[row * KSTR + d0] = *(const bf16x8*)(vb + (size_t)row * S_ + d0);
            }
        }
        __syncthreads();

        // ---- S^T = K·Q^T : rows = keys, cols = q ----
        f32x4 st[4];
        #pragma unroll
        for (int t = 0; t < 4; t++) {
            bf16x8 ka0 = *(const bf16x8*)&Ks[(t * 16 + fr) * KSTR + fq * 8];
            bf16x8 ka1 = *(const bf16x8*)&Ks[(t * 16 + fr) * KSTR + 32 + fq * 8];
            st[t] = __builtin_amdgcn_mfma_f32_16x16x32_bf16(ka0, qf0, (f32x4){0.f,0.f,0.f,0.f}, 0, 0, 0);
            st[t] = __builtin_amdgcn_mfma_f32_16x16x32_bf16(ka1, qf1, st[t], 0, 0, 0);
        }
        // element (n_loc = t*16 + fq*4 + i, m = fr); scale then row stats over n
        float rmax = -1e30f;
        #pragma unroll
        for (int t = 0; t < 4; t++)
            #pragma unroll
            for (int i = 0; i < 4; i++) {
                st[t][i] *= 0.125f;
                rmax = fmaxf(rmax, st[t][i]);
            }
        rmax = fmaxf(rmax, __shfl_xor(rmax, 16));
        rmax = fmaxf(rmax, __shfl_xor(rmax, 32));
        float newm = fmaxf(mrow, rmax);
        float corr = __expf(mrow - newm);
        mrow = newm;
        float psum = 0.f;
        #pragma unroll
        for (int t = 0; t < 4; t++) {
            bf16x4 pk;
            #pragma unroll
            for (int i = 0; i < 4; i++) {
                float p = __expf(st[t][i] - newm);
                psum += p;
                pk[i] = (__bf16)p;
            }
            // P m-major: row m = wave*16 + fr, cols n = t*16 + fq*4 .. +3
            *(bf16x4*)&Ps[(wave * 16 + fr) * KSTR + t * 16 + fq * 4] = pk;
        }
        psum += __shfl_xor(psum, 16);
        psum += __shfl_xor(psum, 32);
        lrow = lrow * corr + psum;

        // ---- rescale O (rows in C layout: m_loc = fq*4 + i) ----
        #pragma unroll
        for (int i = 0; i < 4; i++) {
            float ci = __shfl(corr, fq * 4 + i);
            #pragma unroll
            for (int dt = 0; dt < 4; dt++) oacc[dt][i] *= ci;
        }

        // ---- O += P·V : A = P (m-major), B = V^T (d-major) ----
        bf16x8 pa0 = *(const bf16x8*)&Ps[(wave * 16 + fr) * KSTR + fq * 8];
        bf16x8 pa1 = *(const bf16x8*)&Ps[(wave * 16 + fr) * KSTR + 32 + fq * 8];
        #pragma unroll
        for (int dt = 0; dt < 4; dt++) {
            bf16x8 vb0 = *(const bf16x8*)&Vs[(dt * 16 + fr) * KSTR + fq * 8];
            bf16x8 vb1 = *(const bf16x8*)&Vs[(dt * 16 + fr) * KSTR + 32 + fq * 8];
            oacc[dt] = __builtin_amdgcn_mfma_f32_16x16x32_bf16(pa0, vb0, oacc[dt], 0, 0, 0);
            oacc[dt] = __builtin_amdgcn_mfma_f32_16x16x32_bf16(pa1, vb1, oacc[dt], 0, 0, 0);
        }
    }

    // ---- epilogue: normalize rows, write (B,S,D) bf16 ----
    float linv = 1.f / lrow;
    #pragma unroll
    for (int i = 0; i < 4; i++) {
        float li = __shfl(linv, fq * 4 + i);
        int s = n * BS_ + wave * 16 + fq * 4 + i;
        __bf16* op = o + ((size_t)b * S_ + s) * D_ + hh * DH_ + fr;
        #pragma unroll
        for (int dt = 0; dt < 4; dt++)
            op[dt * 16] = (__bf16)(oacc[dt][i] * li);
    }
}

// ---------------------------------------------------------------------------
// Row LayerNorm: fp32 in -> fp32 out + bf16 out. 256 thr = 4 rows/block.
// ---------------------------------------------------------------------------
__global__ __launch_bounds__(256) void ln_kernel(
    const float* in, float* outp, __bf16* outb,
    const float* __restrict__ g, const float* __restrict__ bb)
{
    size_t r = (size_t)blockIdx.x * 4 + (threadIdx.x >> 6);
    int t = threadIdx.x & 63;
    const float4* ip = (const float4*)(in + r * D_);
    float4 x0 = ip[2 * t], x1 = ip[2 * t + 1];
    float s = x0.x + x0.y + x0.z + x0.w + x1.x + x1.y + x1.z + x1.w;
    #pragma unroll
    for (int off = 32; off; off >>= 1) s += __shfl_xor(s, off, 64);
    float mean = s * (1.0f / D_);
    float d0 = x0.x - mean, d1 = x0.y - mean, d2 = x0.z - mean, d3 = x0.w - mean;
    float d4 = x1.x - mean, d5 = x1.y - mean, d6 = x1.z - mean, d7 = x1.w - mean;
    float ss = d0*d0 + d1*d1 + d2*d2 + d3*d3 + d4*d4 + d5*d5 + d6*d6 + d7*d7;
    #pragma unroll
    for (int off = 32; off; off >>= 1) ss += __shfl_xor(ss, off, 64);
    float rs = rsqrtf(ss * (1.0f / D_) + 1e-5f);
    float4 g0 = ((const float4*)g)[2 * t], g1 = ((const float4*)g)[2 * t + 1];
    float4 b0 = ((const float4*)bb)[2 * t], b1 = ((const float4*)bb)[2 * t + 1];
    float y[8];
    y[0] = d0 * rs * g0.x + b0.x; y[1] = d1 * rs * g0.y + b0.y;
    y[2] = d2 * rs * g0.z + b0.z; y[3] = d3 * rs * g0.w + b0.w;
    y[4] = d4 * rs * g1.x + b1.x; y[5] = d5 * rs * g1.y + b1.y;
    y[6] = d6 * rs * g1.z + b1.z; y[7] = d7 * rs * g1.w + b1.w;
    float4* op = (float4*)(outp + r * D_);
    op[2 * t]     = (float4){y[0], y[1], y[2], y[3]};
    op[2 * t + 1] = (float4){y[4], y[5], y[6], y[7]};
    bf16x8 hb;
    #pragma unroll
    for (int j = 0; j < 8; j++) hb[j] = (__bf16)y[j];
    *(bf16x8*)(outb + r * D_ + t * 8) = hb;
}

// ---------------------------------------------------------------------------
// Head (fp32): out[b,:] = tanh(relu(h[b,0,:] @ w_dense + b_dense) @ w_out + b_out)
// ---------------------------------------------------------------------------
__global__ __launch_bounds__(256) void head_kernel(
    const float* __restrict__ h, const float* __restrict__ wd,
    const float* __restrict__ bd, const float* __restrict__ wo,
    const float* __restrict__ bo, float* __restrict__ out)
{
    __shared__ float hrow[D_];
    __shared__ float red[8];
    int b = blockIdx.x;
    int tid = threadIdx.x;
    if (tid < 128) ((float4*)hrow)[tid] = ((const float4*)(h + (size_t)b * S_ * D_))[tid];
    __syncthreads();
    float p0 = 0.f, p1 = 0.f;
    #pragma unroll
    for (int jj = 0; jj < 4; jj++) {
        int j = tid + jj * 256;
        float acc = bd[j];
        for (int i = 0; i < D_; i++) acc += hrow[i] * wd[(size_t)i * 1024 + j];
        float dns = fmaxf(acc, 0.f);
        p0 += dns * wo[j * 2 + 0];
        p1 += dns * wo[j * 2 + 1];
    }
    #pragma unroll
    for (int off = 32; off; off >>= 1) { p0 += __shfl_xor(p0, off, 64); p1 += __shfl_xor(p1, off, 64); }
    int wid = tid >> 6;
    if ((tid & 63) == 0) { red[wid * 2] = p0; red[wid * 2 + 1] = p1; }
    __syncthreads();
    if (tid == 0) {
        float t0 = red[0] + red[2] + red[4] + red[6] + bo[0];
        float t1 = red[1] + red[3] + red[5] + red[7] + bo[1];
        out[b * 2 + 0] = tanhf(t0);
        out[b * 2 + 1] = tanhf(t1);
    }
}

// ---------------------------------------------------------------------------
extern "C" void kernel_launch(void* const* d_in, const int* in_sizes, int n_in,
                              void* d_out, int out_size, void* d_ws, size_t ws_size,
                              hipStream_t stream) {
    (void)in_sizes; (void)n_in; (void)out_size; (void)ws_size;
    const float* x       = (const float*)d_in[0];
    const float* w_embed = (const float*)d_in[1];
    const float* b_embed = (const float*)d_in[2];
    const float* pos_emb = (const float*)d_in[3];
    const float* Wq      = (const float*)d_in[4];
    const float* bq      = (const float*)d_in[5];
    const float* Wk      = (const float*)d_in[6];
    const float* bk      = (const float*)d_in[7];
    const float* Wv      = (const float*)d_in[8];
    const float* bv      = (const float*)d_in[9];
    const float* Wo      = (const float*)d_in[10];
    const float* bo      = (const float*)d_in[11];
    const float* ln1_g   = (const float*)d_in[12];
    const float* ln1_b   = (const float*)d_in[13];
    const float* W1      = (const float*)d_in[14];
    const float* b1      = (const float*)d_in[15];
    const float* W2      = (const float*)d_in[16];
    const float* b2      = (const float*)d_in[17];
    const float* ln2_g   = (const float*)d_in[18];
    const float* ln2_b   = (const float*)d_in[19];
    const float* w_dense = (const float*)d_in[20];
    const float* b_dense = (const float*)d_in[21];
    const float* w_out   = (const float*)d_in[22];
    const float* b_out   = (const float*)d_in[23];
    const int*   rb      = (const int*)d_in[24];
    float* out = (float*)d_out;

    // Workspace layout (total ~137 MiB):
    //  h fp32 (32M) | h_bf (16M) | big bf16 region 64M: qkv(48M)+o(16M) == ff1
    //  (embed phase reuses big: xr @ +0, wt_e @ +28M elems) | wt ~25M @ 112MiB
    const size_t PLANE = (size_t)B_ * H_ * S_ * DH_;  // 8,388,608
    float*  h    = (float*)d_ws;
    __bf16* h_bf = (__bf16*)(h + (size_t)MTOK * D_);
    __bf16* big  = (__bf16*)((char*)d_ws + (size_t)48 * 1024 * 1024);
    __bf16* qkv  = big;
    __bf16* o_bf = big + 3 * PLANE;
    __bf16* ff1  = big;                                // alias, lifetime-disjoint
    __bf16* xr   = big;                                // embed-phase only
    __bf16* wt_e = big + (size_t)28 * 1024 * 1024;     // embed-phase only (512*96)
    __bf16* wt   = (__bf16*)((char*)d_ws + (size_t)112 * 1024 * 1024);
    __bf16* wt_qkv = wt;                               // 3*L*D*D
    __bf16* wt_o   = wt_qkv + (size_t)3 * L_ * DD_;    // L*D*D
    __bf16* wt_1   = wt_o + (size_t)L_ * DD_;          // L*D*FF
    __bf16* wt_2   = wt_1 + (size_t)L_ * D_ * FF_;     // L*FF*D

    dim3 tb(32, 8);
    wconv_kernel<<<dim3(16, 16, L_), tb, 0, stream>>>(Wq, wt_qkv,                        D_, D_, D_);
    wconv_kernel<<<dim3(16, 16, L_), tb, 0, stream>>>(Wk, wt_qkv + (size_t)L_ * DD_,     D_, D_, D_);
    wconv_kernel<<<dim3(16, 16, L_), tb, 0, stream>>>(Wv, wt_qkv + (size_t)2 * L_ * DD_, D_, D_, D_);
    wconv_kernel<<<dim3(16, 16, L_), tb, 0, stream>>>(Wo, wt_o,                          D_, D_, D_);
    wconv_kernel<<<dim3(64, 16, L_), tb, 0, stream>>>(W1, wt_1,                          D_, FF_, D_);
    wconv_kernel<<<dim3(16, 64, L_), tb, 0, stream>>>(W2, wt_2,                          FF_, D_, FF_);
    wconv_kernel<<<dim3(16, 3, 1),  tb, 0, stream>>>(w_embed, wt_e,                      80, D_, KE_);

    // Embed = MFMA GEMM: h = xr @ wt_e^T + b_embed + pos_emb (cls row -> pe[0])
    xbuild_kernel<<<MTOK / 64, 256, 0, stream>>>(x, xr);
    mfma_gemm<<<dim3(D_ / 128, MTOK / 128, 1), 256, 0, stream>>>(
        xr, wt_e, b_embed, b_embed, b_embed,
        nullptr, pos_emb, h, h_bf, D_, KE_, 0, 0, 0, 0);

    for (int l = 0; l < L_; l++) {
        // QKV (fused, z selects q/k/v; v scattered transposed)
        mfma_gemm<<<dim3(D_ / 128, MTOK / 128, 3), 256, 0, stream>>>(
            h_bf, wt_qkv + (size_t)l * DD_, bq + l * D_, bk + l * D_, bv + l * D_,
            nullptr, nullptr, nullptr, qkv, D_, D_, (long)L_ * DD_, (long)PLANE, 0, 1);

        attn_kernel<<<B_ * H_ * NB_, 256, 0, stream>>>(qkv, qkv + PLANE, qkv + 2 * PLANE, rb, o_bf);

        // h = h + o @ Wo + bo
        mfma_gemm<<<dim3(D_ / 128, MTOK / 128, 1), 256, 0, stream>>>(
            o_bf, wt_o + (size_t)l * DD_, bo + l * D_, bo + l * D_, bo + l * D_,
            h, nullptr, h, nullptr, D_, D_, 0, 0, 0, 0);
        ln_kernel<<<MTOK / 4, 256, 0, stream>>>(h, h, h_bf, ln1_g + l * D_, ln1_b + l * D_);

        // ff1 = relu(h @ W1 + b1), bf16 out
        mfma_gemm<<<dim3(FF_ / 128, MTOK / 128, 1), 256, 0, stream>>>(
            h_bf, wt_1 + (size_t)l * D_ * FF_, b1 + l * FF_, b1 + l * FF_, b1 + l * FF_,
            nullptr, nullptr, nullptr, ff1, FF_, D_, 0, 0, 1, 0);

        // h = h + ff1 @ W2 + b2
        mfma_gemm<<<dim3(D_ / 128, MTOK / 128, 1), 256, 0, stream>>>(
            ff1, wt_2 + (size_t)l * FF_ * D_, b2 + l * D_, b2 + l * D_, b2 + l * D_,
            h, nullptr, h, nullptr, D_, FF_, 0, 0, 0, 0);
        ln_kernel<<<MTOK / 4, 256, 0, stream>>>(h, h, h_bf, ln2_g + l * D_, ln2_b + l * D_);
    }

    head_kernel<<<B_, 256, 0, stream>>>(h, w_dense, b_dense, w_out, b_out, out);
}

// Round 7
// 1361.488 us; speedup vs baseline: 6.5668x; 1.0382x over previous
//
#include <hip/hip_runtime.h>
#include <cstdint>
#include <cstddef>

// Problem constants
#define B_   8
#define NM_  10
#define T_   16376
#define D_   512
#define H_   8
#define DH_  64
#define L_   4
#define S_   2048
#define NB_  32
#define BS_  64
#define FF_  2048
#define MTOK (B_*S_)   // 16384 token rows
#define DD_  (D_*D_)
#define KE_  96        // embed K padded (80 -> 96)

typedef __attribute__((ext_vector_type(8))) __bf16 bf16x8;
typedef __attribute__((ext_vector_type(4))) __bf16 bf16x4;
typedef __attribute__((ext_vector_type(4))) float f32x4;

__device__ __forceinline__ void async16(void* lds, const void* g) {
    __builtin_amdgcn_global_load_lds(
        (const __attribute__((address_space(1))) void*)g,
        (__attribute__((address_space(3))) void*)lds, 16, 0, 0);
}

// ---------------------------------------------------------------------------
// Weight transpose+convert: in (K x N fp32, z-strided) -> out (N x Kp bf16),
// zero-padding k in [K, Kp). Grid: (N/32, Kp/32, Z).
// ---------------------------------------------------------------------------
__global__ __launch_bounds__(256) void wconv_kernel(
    const float* __restrict__ in, __bf16* __restrict__ outp, int K, int N, int Kp)
{
    __shared__ float t[32][33];
    const float* ip = in + (size_t)blockIdx.z * K * N;
    __bf16* op = outp + (size_t)blockIdx.z * N * Kp;
    int n0 = blockIdx.x * 32, k0 = blockIdx.y * 32;
    int tx = threadIdx.x, ty = threadIdx.y;   // 32 x 8
    #pragma unroll
    for (int j = 0; j < 4; j++) {
        int k = k0 + ty + 8 * j;
        t[ty + 8 * j][tx] = (k < K) ? ip[(size_t)k * N + n0 + tx] : 0.f;
    }
    __syncthreads();
    #pragma unroll
    for (int j = 0; j < 4; j++)
        op[(size_t)(n0 + ty + 8 * j) * Kp + k0 + tx] = (__bf16)t[tx][ty + 8 * j];
}

// ---------------------------------------------------------------------------
// Build xr (MTOK x KE_ bf16): xr[b*2048+t][m] = x[b, m/8, (m%8)*2047 + t-1]
// for t>=1, m<80; else 0. One block per 64 rows (same b).
// ---------------------------------------------------------------------------
__global__ __launch_bounds__(256) void xbuild_kernel(
    const float* __restrict__ x, __bf16* __restrict__ xr)
{
    __shared__ float xs[64][97];
    int row0 = blockIdx.x * 64;
    int b = row0 >> 11;
    int t0 = row0 & (S_ - 1);
    int tid = threadIdx.x;
    int lane = tid & 63;
    int mq = tid >> 6;          // 0..3
    // phase 1: coalesced loads over t for each m
    for (int mb = 0; mb < 24; mb++) {
        int m = mb * 4 + mq;    // 0..95
        int t = t0 + lane;
        float v = 0.f;
        if (m < 80 && t > 0)
            v = x[(size_t)b * NM_ * T_ + (size_t)(m >> 3) * T_ + (m & 7) * 2047 + (t - 1)];
        xs[lane][m] = v;
    }
    __syncthreads();
    // phase 2: row-major bf16 write, 8B chunks
    #pragma unroll
    for (int u = 0; u < 6; u++) {
        int ch = tid + u * 256;          // 0..1535
        int row = ch / 24, c4 = (ch % 24) * 4;
        bf16x4 pk;
        #pragma unroll
        for (int i = 0; i < 4; i++) pk[i] = (__bf16)xs[row][c4 + i];
        *(bf16x4*)&xr[(size_t)(row0 + row) * KE_ + c4] = pk;
    }
}

// ---------------------------------------------------------------------------
// MFMA bf16 GEMM: C = A(MxK bf16) @ Wt^T + bias [+res] [+posemb] [relu]
// Wt is N x K bf16 (pre-transposed). 128x128 tile, BK=32, 256 thr (4 waves).
// z (weight plane / bias select / scatter plane) folded into blockIdx.x:
//   z = bx % nz, bn = (bx / nz) * 128  -> same-A blocks adjacent for L2 reuse.
// Outputs: Cf (fp32 MxN, optional), Cb (bf16, optional).
// scatter==1: z in {0,1} -> (B,H,S,DH); z==2 -> V transposed (B,H,DH,S).
// pe != null: val += pe[(row&2047)*N + col]; row with t==0 -> val = pe[col].
// ---------------------------------------------------------------------------
__global__ __launch_bounds__(256, 2) void mfma_gemm(
    const __bf16* __restrict__ A, const __bf16* __restrict__ Wt,
    const float* __restrict__ bias0, const float* __restrict__ bias1,
    const float* __restrict__ bias2,
    const float* res, const float* __restrict__ pe, float* Cf, __bf16* Cb,
    int N, int K, long wtz, long cbz, int relu, int scatter, int nz)
{
    __shared__ __align__(16) __bf16 As[128 * 32];
    __shared__ __align__(16) __bf16 Bs[128 * 32];
    int tid = threadIdx.x;
    int wave = tid >> 6;
    int lane = tid & 63;
    int bx = blockIdx.x;
    int z = bx % nz;
    int bn = (bx / nz) * 128;
    int bm = blockIdx.y * 128;
    const __bf16* Wz = Wt + (size_t)z * wtz;
    const float* bias = (z == 0) ? bias0 : (z == 1 ? bias1 : bias2);

    f32x4 acc[4][4];
    #pragma unroll
    for (int r = 0; r < 4; r++)
        #pragma unroll
        for (int c = 0; c < 4; c++) acc[r][c] = (f32x4){0.f, 0.f, 0.f, 0.f};

    const int wr = (wave >> 1) * 64;
    const int wc = (wave & 1) * 64;
    const int fr = lane & 15;
    const int fk = (lane >> 4) * 8;

    const int c0 = tid, c1 = tid + 256;
    const __bf16* Ag0 = A  + (size_t)(bm + (c0 >> 2)) * K + (c0 & 3) * 8;
    const __bf16* Ag1 = A  + (size_t)(bm + (c1 >> 2)) * K + (c1 & 3) * 8;
    const __bf16* Bg0 = Wz + (size_t)(bn + (c0 >> 2)) * K + (c0 & 3) * 8;
    const __bf16* Bg1 = Wz + (size_t)(bn + (c1 >> 2)) * K + (c1 & 3) * 8;
    __bf16* AsW0 = As + (size_t)(wave * 64) * 8;
    __bf16* AsW1 = As + (size_t)(256 + wave * 64) * 8;
    __bf16* BsW0 = Bs + (size_t)(wave * 64) * 8;
    __bf16* BsW1 = Bs + (size_t)(256 + wave * 64) * 8;

    for (int kk = 0; kk < K; kk += 32) {
        __syncthreads();
        async16(AsW0, Ag0 + kk);
        async16(AsW1, Ag1 + kk);
        async16(BsW0, Bg0 + kk);
        async16(BsW1, Bg1 + kk);
        __syncthreads();
        bf16x8 af[4], bfr[4];
        #pragma unroll
        for (int r = 0; r < 4; r++)
            af[r] = *(const bf16x8*)&As[(size_t)(wr + r * 16 + fr) * 32 + fk];
        #pragma unroll
        for (int c = 0; c < 4; c++)
            bfr[c] = *(const bf16x8*)&Bs[(size_t)(wc + c * 16 + fr) * 32 + fk];
        #pragma unroll
        for (int r = 0; r < 4; r++)
            #pragma unroll
            for (int c = 0; c < 4; c++)
                acc[r][c] = __builtin_amdgcn_mfma_f32_16x16x32_bf16(af[r], bfr[c], acc[r][c], 0, 0, 0);
    }

    // epilogue: C/D layout col = lane&15, row = (lane>>4)*4 + reg
    int rbase = bm + wr + (lane >> 4) * 4;
    #pragma unroll
    for (int c = 0; c < 4; c++) {
        int cg = bn + wc + c * 16 + fr;
        float bv = bias[cg];
        #pragma unroll
        for (int r = 0; r < 4; r++) {
            int rg0 = rbase + r * 16;   // 4-aligned
            float vals[4];
            #pragma unroll
            for (int i = 0; i < 4; i++) {
                float val = acc[r][c][i] + bv;
                if (relu) val = fmaxf(val, 0.f);
                if (res) val += res[(size_t)(rg0 + i) * N + cg];
                if (pe) {
                    int t = (rg0 + i) & (S_ - 1);
                    val = (t == 0) ? pe[cg] : val + pe[(size_t)t * N + cg];
                }
                vals[i] = val;
            }
            if (Cf) {
                #pragma unroll
                for (int i = 0; i < 4; i++) Cf[(size_t)(rg0 + i) * N + cg] = vals[i];
            }
            if (Cb) {
                if (scatter) {
                    int bb = rg0 >> 11;
                    int s0 = rg0 & (S_ - 1);
                    int hh = cg >> 6, dh = cg & 63;
                    if (z == 2) {
                        // V transposed: (B,H,DH,S), pack 4 consecutive s
                        bf16x4 pk;
                        #pragma unroll
                        for (int i = 0; i < 4; i++) pk[i] = (__bf16)vals[i];
                        *(bf16x4*)(Cb + (size_t)z * cbz +
                                   ((((size_t)bb * H_ + hh) * DH_ + dh) * S_) + s0) = pk;
                    } else {
                        #pragma unroll
                        for (int i = 0; i < 4; i++)
                            (Cb + (size_t)z * cbz)[((((size_t)bb * H_ + hh) * S_ + s0 + i) * DH_) + dh] = (__bf16)vals[i];
                    }
                } else {
                    #pragma unroll
                    for (int i = 0; i < 4; i++) Cb[(size_t)(rg0 + i) * N + cg] = (__bf16)vals[i];
                }
            }
        }
    }
}

// ---------------------------------------------------------------------------
// MFMA block-sparse attention. One workgroup (4 waves) per (b,h,n); each wave
// owns 16 q-rows. K staged n-major, V^T staged d-major (from (B,H,DH,S)
// global layout). S^T = K·Q^T via MFMA (row stats at lane&15 -> 2 shuffles);
// P round-trips LDS m-major; PV via MFMA (A=P, B=V^T). Online softmax.
// ---------------------------------------------------------------------------
#define KSTR 72
__global__ __launch_bounds__(256, 4) void attn_kernel(
    const __bf16* __restrict__ q, const __bf16* __restrict__ k,
    const __bf16* __restrict__ vt, const int* __restrict__ rb,
    __bf16* __restrict__ o)
{
    __shared__ __align__(16) __bf16 Ks[64 * KSTR];
    __shared__ __align__(16) __bf16 Vs[64 * KSTR];
    __shared__ __align__(16) __bf16 Ps[64 * KSTR];
    int bid = blockIdx.x;
    int n = bid & (NB_ - 1);
    int hh = (bid >> 5) & (H_ - 1);
    int b = bid >> 8;
    int tid = threadIdx.x;
    int wave = tid >> 6;
    int lane = tid & 63;
    const int fr = lane & 15;
    const int fq = lane >> 4;

    int idx[6];
    idx[0] = 0;
    idx[1] = n > 0 ? n - 1 : 0;
    idx[2] = n;
    idx[3] = n < NB_ - 1 ? n + 1 : NB_ - 1;
    idx[4] = rb[n * 2 + 0];
    idx[5] = rb[n * 2 + 1];

    const size_t plane = ((size_t)b * H_ + hh) * S_;           // q,k row base
    const __bf16* vtb = vt + plane * DH_;                      // (B,H,DH,S) plane

    // Q fragments (B-operand): row m = wave*16 + fr, k = fq*8 (+32)
    const __bf16* qrow = q + (plane + (size_t)n * BS_ + wave * 16 + fr) * DH_ + fq * 8;
    bf16x8 qf0 = *(const bf16x8*)qrow;
    bf16x8 qf1 = *(const bf16x8*)(qrow + 32);

    f32x4 oacc[4];
    #pragma unroll
    for (int dt = 0; dt < 4; dt++) oacc[dt] = (f32x4){0.f, 0.f, 0.f, 0.f};
    float mrow = -1e30f, lrow = 0.f;

    for (int c = 0; c < 6; c++) {
        bool dup = false;
        #pragma unroll
        for (int j = 0; j < 6; j++) if (j < c && idx[j] == idx[c]) dup = true;
        if (dup) continue;   // uniform across workgroup

        __syncthreads();     // prior iteration's reads of Ks/Vs complete
        // ---- stage K (n-major) and V^T (d-major), 512 16B chunks each ----
        {
            const __bf16* kb = k + (plane + (size_t)idx[c] * BS_) * DH_;
            const __bf16* vb = vtb + (size_t)idx[c] * BS_;
            #pragma unroll
            for (int u = 0; u < 2; u++) {
                int ch = tid + u * 256;
                int row = ch >> 3, d0 = (ch & 7) * 8;
                *(bf16x8*)&Ks[row * KSTR + d0] = *(const bf16x8*)(kb + row * DH_ + d0);
                *(bf16x8*)&Vs[row * KSTR + d0] = *(const bf16x8*)(vb + (size_t)row * S_ + d0);
            }
        }
        __syncthreads();

        // ---- S^T = K·Q^T : rows = keys, cols = q ----
        f32x4 st[4];
        #pragma unroll
        for (int t = 0; t < 4; t++) {
            bf16x8 ka0 = *(const bf16x8*)&Ks[(t * 16 + fr) * KSTR + fq * 8];
            bf16x8 ka1 = *(const bf16x8*)&Ks[(t * 16 + fr) * KSTR + 32 + fq * 8];
            st[t] = __builtin_amdgcn_mfma_f32_16x16x32_bf16(ka0, qf0, (f32x4){0.f,0.f,0.f,0.f}, 0, 0, 0);
            st[t] = __builtin_amdgcn_mfma_f32_16x16x32_bf16(ka1, qf1, st[t], 0, 0, 0);
        }
        // element (n_loc = t*16 + fq*4 + i, m = fr); scale then row stats over n
        float rmax = -1e30f;
        #pragma unroll
        for (int t = 0; t < 4; t++)
            #pragma unroll
            for (int i = 0; i < 4; i++) {
                st[t][i] *= 0.125f;
                rmax = fmaxf(rmax, st[t][i]);
            }
        rmax = fmaxf(rmax, __shfl_xor(rmax, 16));
        rmax = fmaxf(rmax, __shfl_xor(rmax, 32));
        float newm = fmaxf(mrow, rmax);
        float corr = __expf(mrow - newm);
        mrow = newm;
        float psum = 0.f;
        #pragma unroll
        for (int t = 0; t < 4; t++) {
            bf16x4 pk;
            #pragma unroll
            for (int i = 0; i < 4; i++) {
                float p = __expf(st[t][i] - newm);
                psum += p;
                pk[i] = (__bf16)p;
            }
            // P m-major: row m = wave*16 + fr, cols n = t*16 + fq*4 .. +3
            *(bf16x4*)&Ps[(wave * 16 + fr) * KSTR + t * 16 + fq * 4] = pk;
        }
        psum += __shfl_xor(psum, 16);
        psum += __shfl_xor(psum, 32);
        lrow = lrow * corr + psum;

        // ---- rescale O (rows in C layout: m_loc = fq*4 + i) ----
        #pragma unroll
        for (int i = 0; i < 4; i++) {
            float ci = __shfl(corr, fq * 4 + i);
            #pragma unroll
            for (int dt = 0; dt < 4; dt++) oacc[dt][i] *= ci;
        }

        // ---- O += P·V : A = P (m-major), B = V^T (d-major) ----
        bf16x8 pa0 = *(const bf16x8*)&Ps[(wave * 16 + fr) * KSTR + fq * 8];
        bf16x8 pa1 = *(const bf16x8*)&Ps[(wave * 16 + fr) * KSTR + 32 + fq * 8];
        #pragma unroll
        for (int dt = 0; dt < 4; dt++) {
            bf16x8 vb0 = *(const bf16x8*)&Vs[(dt * 16 + fr) * KSTR + fq * 8];
            bf16x8 vb1 = *(const bf16x8*)&Vs[(dt * 16 + fr) * KSTR + 32 + fq * 8];
            oacc[dt] = __builtin_amdgcn_mfma_f32_16x16x32_bf16(pa0, vb0, oacc[dt], 0, 0, 0);
            oacc[dt] = __builtin_amdgcn_mfma_f32_16x16x32_bf16(pa1, vb1, oacc[dt], 0, 0, 0);
        }
    }

    // ---- epilogue: normalize rows, write (B,S,D) bf16 ----
    float linv = 1.f / lrow;
    #pragma unroll
    for (int i = 0; i < 4; i++) {
        float li = __shfl(linv, fq * 4 + i);
        int s = n * BS_ + wave * 16 + fq * 4 + i;
        __bf16* op = o + ((size_t)b * S_ + s) * D_ + hh * DH_ + fr;
        #pragma unroll
        for (int dt = 0; dt < 4; dt++)
            op[dt * 16] = (__bf16)(oacc[dt][i] * li);
    }
}

// ---------------------------------------------------------------------------
// Row LayerNorm: fp32 in -> fp32 out + bf16 out. 256 thr = 4 rows/block.
// ---------------------------------------------------------------------------
__global__ __launch_bounds__(256) void ln_kernel(
    const float* in, float* outp, __bf16* outb,
    const float* __restrict__ g, const float* __restrict__ bb)
{
    size_t r = (size_t)blockIdx.x * 4 + (threadIdx.x >> 6);
    int t = threadIdx.x & 63;
    const float4* ip = (const float4*)(in + r * D_);
    float4 x0 = ip[2 * t], x1 = ip[2 * t + 1];
    float s = x0.x + x0.y + x0.z + x0.w + x1.x + x1.y + x1.z + x1.w;
    #pragma unroll
    for (int off = 32; off; off >>= 1) s += __shfl_xor(s, off, 64);
    float mean = s * (1.0f / D_);
    float d0 = x0.x - mean, d1 = x0.y - mean, d2 = x0.z - mean, d3 = x0.w - mean;
    float d4 = x1.x - mean, d5 = x1.y - mean, d6 = x1.z - mean, d7 = x1.w - mean;
    float ss = d0*d0 + d1*d1 + d2*d2 + d3*d3 + d4*d4 + d5*d5 + d6*d6 + d7*d7;
    #pragma unroll
    for (int off = 32; off; off >>= 1) ss += __shfl_xor(ss, off, 64);
    float rs = rsqrtf(ss * (1.0f / D_) + 1e-5f);
    float4 g0 = ((const float4*)g)[2 * t], g1 = ((const float4*)g)[2 * t + 1];
    float4 b0 = ((const float4*)bb)[2 * t], b1 = ((const float4*)bb)[2 * t + 1];
    float y[8];
    y[0] = d0 * rs * g0.x + b0.x; y[1] = d1 * rs * g0.y + b0.y;
    y[2] = d2 * rs * g0.z + b0.z; y[3] = d3 * rs * g0.w + b0.w;
    y[4] = d4 * rs * g1.x + b1.x; y[5] = d5 * rs * g1.y + b1.y;
    y[6] = d6 * rs * g1.z + b1.z; y[7] = d7 * rs * g1.w + b1.w;
    float4* op = (float4*)(outp + r * D_);
    op[2 * t]     = (float4){y[0], y[1], y[2], y[3]};
    op[2 * t + 1] = (float4){y[4], y[5], y[6], y[7]};
    bf16x8 hb;
    #pragma unroll
    for (int j = 0; j < 8; j++) hb[j] = (__bf16)y[j];
    *(bf16x8*)(outb + r * D_ + t * 8) = hb;
}

// ---------------------------------------------------------------------------
// Head stage 1: grid (8,4). Block (b,jg): columns j = jg*256 + tid of
// dense = relu(h[b,0,:] @ w_dense + b_dense); partial sums of dense@w_out.
// ---------------------------------------------------------------------------
__global__ __launch_bounds__(256) void head1_kernel(
    const float* __restrict__ h, const float* __restrict__ wd,
    const float* __restrict__ bd, const float* __restrict__ wo,
    float* __restrict__ partial)
{
    __shared__ float hrow[D_];
    __shared__ float red[8];
    int b = blockIdx.x, jg = blockIdx.y;
    int tid = threadIdx.x;
    if (tid < 128) ((float4*)hrow)[tid] = ((const float4*)(h + (size_t)b * S_ * D_))[tid];
    __syncthreads();
    int j = jg * 256 + tid;
    float acc = bd[j];
    #pragma unroll 8
    for (int i = 0; i < D_; i++) acc = fmaf(hrow[i], wd[(size_t)i * 1024 + j], acc);
    float dns = fmaxf(acc, 0.f);
    float2 w2 = ((const float2*)wo)[j];
    float p0 = dns * w2.x, p1 = dns * w2.y;
    #pragma unroll
    for (int off = 32; off; off >>= 1) { p0 += __shfl_xor(p0, off, 64); p1 += __shfl_xor(p1, off, 64); }
    int wid = tid >> 6;
    if ((tid & 63) == 0) { red[wid * 2] = p0; red[wid * 2 + 1] = p1; }
    __syncthreads();
    if (tid == 0) {
        float t0 = red[0] + red[2] + red[4] + red[6];
        float t1 = red[1] + red[3] + red[5] + red[7];
        partial[((size_t)b * 4 + jg) * 2 + 0] = t0;
        partial[((size_t)b * 4 + jg) * 2 + 1] = t1;
    }
}

// Head stage 2: 16 threads, one block.
__global__ __launch_bounds__(64) void head2_kernel(
    const float* __restrict__ partial, const float* __restrict__ bo,
    float* __restrict__ out)
{
    int tid = threadIdx.x;
    if (tid < 16) {
        int b = tid >> 1, c = tid & 1;
        float s = bo[c];
        #pragma unroll
        for (int jg = 0; jg < 4; jg++) s += partial[((size_t)b * 4 + jg) * 2 + c];
        out[b * 2 + c] = tanhf(s);
    }
}

// ---------------------------------------------------------------------------
extern "C" void kernel_launch(void* const* d_in, const int* in_sizes, int n_in,
                              void* d_out, int out_size, void* d_ws, size_t ws_size,
                              hipStream_t stream) {
    (void)in_sizes; (void)n_in; (void)out_size; (void)ws_size;
    const float* x       = (const float*)d_in[0];
    const float* w_embed = (const float*)d_in[1];
    const float* b_embed = (const float*)d_in[2];
    const float* pos_emb = (const float*)d_in[3];
    const float* Wq      = (const float*)d_in[4];
    const float* bq      = (const float*)d_in[5];
    const float* Wk      = (const float*)d_in[6];
    const float* bk      = (const float*)d_in[7];
    const float* Wv      = (const float*)d_in[8];
    const float* bv      = (const float*)d_in[9];
    const float* Wo      = (const float*)d_in[10];
    const float* bo      = (const float*)d_in[11];
    const float* ln1_g   = (const float*)d_in[12];
    const float* ln1_b   = (const float*)d_in[13];
    const float* W1      = (const float*)d_in[14];
    const float* b1      = (const float*)d_in[15];
    const float* W2      = (const float*)d_in[16];
    const float* b2      = (const float*)d_in[17];
    const float* ln2_g   = (const float*)d_in[18];
    const float* ln2_b   = (const float*)d_in[19];
    const float* w_dense = (const float*)d_in[20];
    const float* b_dense = (const float*)d_in[21];
    const float* w_out   = (const float*)d_in[22];
    const float* b_out   = (const float*)d_in[23];
    const int*   rb      = (const int*)d_in[24];
    float* out = (float*)d_out;

    // Workspace layout (total ~141 MiB):
    //  h fp32 (32M) | h_bf (16M) | big bf16 region 64M: qkv(48M)+o(16M) == ff1
    //  (embed phase reuses big: xr @ +0, wt_e @ +28M elems) | wt ~25M @ 112MiB
    //  head partials @ 140 MiB
    const size_t PLANE = (size_t)B_ * H_ * S_ * DH_;  // 8,388,608
    float*  h    = (float*)d_ws;
    __bf16* h_bf = (__bf16*)(h + (size_t)MTOK * D_);
    __bf16* big  = (__bf16*)((char*)d_ws + (size_t)48 * 1024 * 1024);
    __bf16* qkv  = big;
    __bf16* o_bf = big + 3 * PLANE;
    __bf16* ff1  = big;                                // alias, lifetime-disjoint
    __bf16* xr   = big;                                // embed-phase only
    __bf16* wt_e = big + (size_t)28 * 1024 * 1024;     // embed-phase only (512*96)
    __bf16* wt   = (__bf16*)((char*)d_ws + (size_t)112 * 1024 * 1024);
    __bf16* wt_qkv = wt;                               // 3*L*D*D
    __bf16* wt_o   = wt_qkv + (size_t)3 * L_ * DD_;    // L*D*D
    __bf16* wt_1   = wt_o + (size_t)L_ * DD_;          // L*D*FF
    __bf16* wt_2   = wt_1 + (size_t)L_ * D_ * FF_;     // L*FF*D
    float*  hpart  = (float*)((char*)d_ws + (size_t)140 * 1024 * 1024);  // 64 floats

    dim3 tb(32, 8);
    wconv_kernel<<<dim3(16, 16, L_), tb, 0, stream>>>(Wq, wt_qkv,                        D_, D_, D_);
    wconv_kernel<<<dim3(16, 16, L_), tb, 0, stream>>>(Wk, wt_qkv + (size_t)L_ * DD_,     D_, D_, D_);
    wconv_kernel<<<dim3(16, 16, L_), tb, 0, stream>>>(Wv, wt_qkv + (size_t)2 * L_ * DD_, D_, D_, D_);
    wconv_kernel<<<dim3(16, 16, L_), tb, 0, stream>>>(Wo, wt_o,                          D_, D_, D_);
    wconv_kernel<<<dim3(64, 16, L_), tb, 0, stream>>>(W1, wt_1,                          D_, FF_, D_);
    wconv_kernel<<<dim3(16, 64, L_), tb, 0, stream>>>(W2, wt_2,                          FF_, D_, FF_);
    wconv_kernel<<<dim3(16, 3, 1),  tb, 0, stream>>>(w_embed, wt_e,                      80, D_, KE_);

    // Embed = MFMA GEMM: h = xr @ wt_e^T + b_embed + pos_emb (cls row -> pe[0])
    xbuild_kernel<<<MTOK / 64, 256, 0, stream>>>(x, xr);
    mfma_gemm<<<dim3(D_ / 128, MTOK / 128, 1), 256, 0, stream>>>(
        xr, wt_e, b_embed, b_embed, b_embed,
        nullptr, pos_emb, h, h_bf, D_, KE_, 0, 0, 0, 0, 1);

    for (int l = 0; l < L_; l++) {
        // QKV (z folded into blockIdx.x for A-slice L2 reuse; v scattered transposed)
        mfma_gemm<<<dim3((D_ / 128) * 3, MTOK / 128, 1), 256, 0, stream>>>(
            h_bf, wt_qkv + (size_t)l * DD_, bq + l * D_, bk + l * D_, bv + l * D_,
            nullptr, nullptr, nullptr, qkv, D_, D_, (long)L_ * DD_, (long)PLANE, 0, 1, 3);

        attn_kernel<<<B_ * H_ * NB_, 256, 0, stream>>>(qkv, qkv + PLANE, qkv + 2 * PLANE, rb, o_bf);

        // h = h + o @ Wo + bo
        mfma_gemm<<<dim3(D_ / 128, MTOK / 128, 1), 256, 0, stream>>>(
            o_bf, wt_o + (size_t)l * DD_, bo + l * D_, bo + l * D_, bo + l * D_,
            h, nullptr, h, nullptr, D_, D_, 0, 0, 0, 0, 1);
        ln_kernel<<<MTOK / 4, 256, 0, stream>>>(h, h, h_bf, ln1_g + l * D_, ln1_b + l * D_);

        // ff1 = relu(h @ W1 + b1), bf16 out
        mfma_gemm<<<dim3(FF_ / 128, MTOK / 128, 1), 256, 0, stream>>>(
            h_bf, wt_1 + (size_t)l * D_ * FF_, b1 + l * FF_, b1 + l * FF_, b1 + l * FF_,
            nullptr, nullptr, nullptr, ff1, FF_, D_, 0, 0, 1, 0, 1);

        // h = h + ff1 @ W2 + b2
        mfma_gemm<<<dim3(D_ / 128, MTOK / 128, 1), 256, 0, stream>>>(
            ff1, wt_2 + (size_t)l * FF_ * D_, b2 + l * D_, b2 + l * D_, b2 + l * D_,
            h, nullptr, h, nullptr, D_, FF_, 0, 0, 0, 0, 1);
        ln_kernel<<<MTOK / 4, 256, 0, stream>>>(h, h, h_bf, ln2_g + l * D_, ln2_b + l * D_);
    }

    head1_kernel<<<dim3(B_, 4), 256, 0, stream>>>(h, w_dense, b_dense, w_out, hpart);
    head2_kernel<<<1, 64, 0, stream>>>(hpart, b_out, out);
}

// Round 8
// 1356.407 us; speedup vs baseline: 6.5914x; 1.0037x over previous
//
#include <hip/hip_runtime.h>
#include <cstdint>
#include <cstddef>

// Problem constants
#define B_   8
#define NM_  10
#define T_   16376
#define D_   512
#define H_   8
#define DH_  64
#define L_   4
#define S_   2048
#define NB_  32
#define BS_  64
#define FF_  2048
#define MTOK (B_*S_)   // 16384 token rows
#define DD_  (D_*D_)
#define KE_  96        // embed K padded (80 -> 96)

typedef __attribute__((ext_vector_type(8))) __bf16 bf16x8;
typedef __attribute__((ext_vector_type(4))) __bf16 bf16x4;
typedef __attribute__((ext_vector_type(4))) float f32x4;

__device__ __forceinline__ void async16(void* lds, const void* g) {
    __builtin_amdgcn_global_load_lds(
        (const __attribute__((address_space(1))) void*)g,
        (__attribute__((address_space(3))) void*)lds, 16, 0, 0);
}

// ---------------------------------------------------------------------------
// Weight transpose+convert: in (K x N fp32, z-strided) -> out (N x Kp bf16),
// zero-padding k in [K, Kp). Grid: (N/32, Kp/32, Z).
// ---------------------------------------------------------------------------
__global__ __launch_bounds__(256) void wconv_kernel(
    const float* __restrict__ in, __bf16* __restrict__ outp, int K, int N, int Kp)
{
    __shared__ float t[32][33];
    const float* ip = in + (size_t)blockIdx.z * K * N;
    __bf16* op = outp + (size_t)blockIdx.z * N * Kp;
    int n0 = blockIdx.x * 32, k0 = blockIdx.y * 32;
    int tx = threadIdx.x, ty = threadIdx.y;   // 32 x 8
    #pragma unroll
    for (int j = 0; j < 4; j++) {
        int k = k0 + ty + 8 * j;
        t[ty + 8 * j][tx] = (k < K) ? ip[(size_t)k * N + n0 + tx] : 0.f;
    }
    __syncthreads();
    #pragma unroll
    for (int j = 0; j < 4; j++)
        op[(size_t)(n0 + ty + 8 * j) * Kp + k0 + tx] = (__bf16)t[tx][ty + 8 * j];
}

// ---------------------------------------------------------------------------
// Build xr (MTOK x KE_ bf16): xr[b*2048+t][m] = x[b, m/8, (m%8)*2047 + t-1]
// for t>=1, m<80; else 0. One block per 64 rows (same b).
// ---------------------------------------------------------------------------
__global__ __launch_bounds__(256) void xbuild_kernel(
    const float* __restrict__ x, __bf16* __restrict__ xr)
{
    __shared__ float xs[64][97];
    int row0 = blockIdx.x * 64;
    int b = row0 >> 11;
    int t0 = row0 & (S_ - 1);
    int tid = threadIdx.x;
    int lane = tid & 63;
    int mq = tid >> 6;          // 0..3
    // phase 1: coalesced loads over t for each m
    for (int mb = 0; mb < 24; mb++) {
        int m = mb * 4 + mq;    // 0..95
        int t = t0 + lane;
        float v = 0.f;
        if (m < 80 && t > 0)
            v = x[(size_t)b * NM_ * T_ + (size_t)(m >> 3) * T_ + (m & 7) * 2047 + (t - 1)];
        xs[lane][m] = v;
    }
    __syncthreads();
    // phase 2: row-major bf16 write, 8B chunks
    #pragma unroll
    for (int u = 0; u < 6; u++) {
        int ch = tid + u * 256;          // 0..1535
        int row = ch / 24, c4 = (ch % 24) * 4;
        bf16x4 pk;
        #pragma unroll
        for (int i = 0; i < 4; i++) pk[i] = (__bf16)xs[row][c4 + i];
        *(bf16x4*)&xr[(size_t)(row0 + row) * KE_ + c4] = pk;
    }
}

// ---------------------------------------------------------------------------
// MFMA bf16 GEMM: C = A(MxK bf16) @ Wt^T + bias [+res] [+posemb] [relu]
// Wt is N x K bf16 (pre-transposed). 128x128 tile, BK=32, 256 thr (4 waves).
// z (weight plane / bias select / scatter plane) folded into x index.
// XCD-aware swizzle: consecutive workgroups go round-robin to the 8 XCDs
// (private L2s). We remap so each XCD owns a contiguous band of bm rows and
// all (z,bn) tiles for it -> A-slice fetched by ONE XCD's L2, not all 8.
// Outputs: Cf (fp32 MxN, optional), Cb (bf16, optional).
// scatter==1: z in {0,1} -> (B,H,S,DH); z==2 -> V transposed (B,H,DH,S).
// pe != null: val += pe[(row&2047)*N + col]; row with t==0 -> val = pe[col].
// ---------------------------------------------------------------------------
__global__ __launch_bounds__(256, 2) void mfma_gemm(
    const __bf16* __restrict__ A, const __bf16* __restrict__ Wt,
    const float* __restrict__ bias0, const float* __restrict__ bias1,
    const float* __restrict__ bias2,
    const float* res, const float* __restrict__ pe, float* Cf, __bf16* Cb,
    int N, int K, long wtz, long cbz, int relu, int scatter, int nz)
{
    __shared__ __align__(16) __bf16 As[128 * 32];
    __shared__ __align__(16) __bf16 Bs[128 * 32];
    int tid = threadIdx.x;
    int wave = tid >> 6;
    int lane = tid & 63;

    int nbx = gridDim.x, nby = gridDim.y;
    int bxIdx, bmIdx;
    if ((nby & 7) == 0) {
        int id = blockIdx.y * nbx + blockIdx.x;   // dispatch-linear order
        int chunk = nby >> 3;
        int xcd = id & 7;
        int local = id >> 3;
        int row = local / nbx;
        bmIdx = xcd * chunk + row;
        bxIdx = local - row * nbx;
    } else {
        bxIdx = blockIdx.x; bmIdx = blockIdx.y;
    }
    int z = bxIdx % nz;
    int bn = (bxIdx / nz) * 128;
    int bm = bmIdx * 128;
    const __bf16* Wz = Wt + (size_t)z * wtz;
    const float* bias = (z == 0) ? bias0 : (z == 1 ? bias1 : bias2);

    f32x4 acc[4][4];
    #pragma unroll
    for (int r = 0; r < 4; r++)
        #pragma unroll
        for (int c = 0; c < 4; c++) acc[r][c] = (f32x4){0.f, 0.f, 0.f, 0.f};

    const int wr = (wave >> 1) * 64;
    const int wc = (wave & 1) * 64;
    const int fr = lane & 15;
    const int fk = (lane >> 4) * 8;

    const int c0 = tid, c1 = tid + 256;
    const __bf16* Ag0 = A  + (size_t)(bm + (c0 >> 2)) * K + (c0 & 3) * 8;
    const __bf16* Ag1 = A  + (size_t)(bm + (c1 >> 2)) * K + (c1 & 3) * 8;
    const __bf16* Bg0 = Wz + (size_t)(bn + (c0 >> 2)) * K + (c0 & 3) * 8;
    const __bf16* Bg1 = Wz + (size_t)(bn + (c1 >> 2)) * K + (c1 & 3) * 8;
    __bf16* AsW0 = As + (size_t)(wave * 64) * 8;
    __bf16* AsW1 = As + (size_t)(256 + wave * 64) * 8;
    __bf16* BsW0 = Bs + (size_t)(wave * 64) * 8;
    __bf16* BsW1 = Bs + (size_t)(256 + wave * 64) * 8;

    for (int kk = 0; kk < K; kk += 32) {
        __syncthreads();
        async16(AsW0, Ag0 + kk);
        async16(AsW1, Ag1 + kk);
        async16(BsW0, Bg0 + kk);
        async16(BsW1, Bg1 + kk);
        __syncthreads();
        bf16x8 af[4], bfr[4];
        #pragma unroll
        for (int r = 0; r < 4; r++)
            af[r] = *(const bf16x8*)&As[(size_t)(wr + r * 16 + fr) * 32 + fk];
        #pragma unroll
        for (int c = 0; c < 4; c++)
            bfr[c] = *(const bf16x8*)&Bs[(size_t)(wc + c * 16 + fr) * 32 + fk];
        #pragma unroll
        for (int r = 0; r < 4; r++)
            #pragma unroll
            for (int c = 0; c < 4; c++)
                acc[r][c] = __builtin_amdgcn_mfma_f32_16x16x32_bf16(af[r], bfr[c], acc[r][c], 0, 0, 0);
    }

    // epilogue: C/D layout col = lane&15, row = (lane>>4)*4 + reg
    int rbase = bm + wr + (lane >> 4) * 4;
    #pragma unroll
    for (int c = 0; c < 4; c++) {
        int cg = bn + wc + c * 16 + fr;
        float bv = bias[cg];
        #pragma unroll
        for (int r = 0; r < 4; r++) {
            int rg0 = rbase + r * 16;   // 4-aligned
            float vals[4];
            #pragma unroll
            for (int i = 0; i < 4; i++) {
                float val = acc[r][c][i] + bv;
                if (relu) val = fmaxf(val, 0.f);
                if (res) val += res[(size_t)(rg0 + i) * N + cg];
                if (pe) {
                    int t = (rg0 + i) & (S_ - 1);
                    val = (t == 0) ? pe[cg] : val + pe[(size_t)t * N + cg];
                }
                vals[i] = val;
            }
            if (Cf) {
                #pragma unroll
                for (int i = 0; i < 4; i++) Cf[(size_t)(rg0 + i) * N + cg] = vals[i];
            }
            if (Cb) {
                if (scatter) {
                    int bb = rg0 >> 11;
                    int s0 = rg0 & (S_ - 1);
                    int hh = cg >> 6, dh = cg & 63;
                    if (z == 2) {
                        // V transposed: (B,H,DH,S), pack 4 consecutive s
                        bf16x4 pk;
                        #pragma unroll
                        for (int i = 0; i < 4; i++) pk[i] = (__bf16)vals[i];
                        *(bf16x4*)(Cb + (size_t)z * cbz +
                                   ((((size_t)bb * H_ + hh) * DH_ + dh) * S_) + s0) = pk;
                    } else {
                        #pragma unroll
                        for (int i = 0; i < 4; i++)
                            (Cb + (size_t)z * cbz)[((((size_t)bb * H_ + hh) * S_ + s0 + i) * DH_) + dh] = (__bf16)vals[i];
                    }
                } else {
                    #pragma unroll
                    for (int i = 0; i < 4; i++) Cb[(size_t)(rg0 + i) * N + cg] = (__bf16)vals[i];
                }
            }
        }
    }
}

// ---------------------------------------------------------------------------
// MFMA block-sparse attention. One workgroup (4 waves) per (b,h,n); each wave
// owns 16 q-rows. K staged n-major, V^T staged d-major (from (B,H,DH,S)
// global layout). S^T = K·Q^T via MFMA (row stats at lane&15 -> 2 shuffles);
// P round-trips LDS m-major; PV via MFMA (A=P, B=V^T). Online softmax.
// ---------------------------------------------------------------------------
#define KSTR 72
__global__ __launch_bounds__(256, 4) void attn_kernel(
    const __bf16* __restrict__ q, const __bf16* __restrict__ k,
    const __bf16* __restrict__ vt, const int* __restrict__ rb,
    __bf16* __restrict__ o)
{
    __shared__ __align__(16) __bf16 Ks[64 * KSTR];
    __shared__ __align__(16) __bf16 Vs[64 * KSTR];
    __shared__ __align__(16) __bf16 Ps[64 * KSTR];
    int bid = blockIdx.x;
    int n = bid & (NB_ - 1);
    int hh = (bid >> 5) & (H_ - 1);
    int b = bid >> 8;
    int tid = threadIdx.x;
    int wave = tid >> 6;
    int lane = tid & 63;
    const int fr = lane & 15;
    const int fq = lane >> 4;

    int idx[6];
    idx[0] = 0;
    idx[1] = n > 0 ? n - 1 : 0;
    idx[2] = n;
    idx[3] = n < NB_ - 1 ? n + 1 : NB_ - 1;
    idx[4] = rb[n * 2 + 0];
    idx[5] = rb[n * 2 + 1];

    const size_t plane = ((size_t)b * H_ + hh) * S_;           // q,k row base
    const __bf16* vtb = vt + plane * DH_;                      // (B,H,DH,S) plane

    // Q fragments (B-operand): row m = wave*16 + fr, k = fq*8 (+32)
    const __bf16* qrow = q + (plane + (size_t)n * BS_ + wave * 16 + fr) * DH_ + fq * 8;
    bf16x8 qf0 = *(const bf16x8*)qrow;
    bf16x8 qf1 = *(const bf16x8*)(qrow + 32);

    f32x4 oacc[4];
    #pragma unroll
    for (int dt = 0; dt < 4; dt++) oacc[dt] = (f32x4){0.f, 0.f, 0.f, 0.f};
    float mrow = -1e30f, lrow = 0.f;

    for (int c = 0; c < 6; c++) {
        bool dup = false;
        #pragma unroll
        for (int j = 0; j < 6; j++) if (j < c && idx[j] == idx[c]) dup = true;
        if (dup) continue;   // uniform across workgroup

        __syncthreads();     // prior iteration's reads of Ks/Vs complete
        // ---- stage K (n-major) and V^T (d-major), 512 16B chunks each ----
        {
            const __bf16* kb = k + (plane + (size_t)idx[c] * BS_) * DH_;
            const __bf16* vb = vtb + (size_t)idx[c] * BS_;
            #pragma unroll
            for (int u = 0; u < 2; u++) {
                int ch = tid + u * 256;
                int row = ch >> 3, d0 = (ch & 7) * 8;
                *(bf16x8*)&Ks[row * KSTR + d0] = *(const bf16x8*)(kb + row * DH_ + d0);
                *(bf16x8*)&Vs[row * KSTR + d0] = *(const bf16x8*)(vb + (size_t)row * S_ + d0);
            }
        }
        __syncthreads();

        // ---- S^T = K·Q^T : rows = keys, cols = q ----
        f32x4 st[4];
        #pragma unroll
        for (int t = 0; t < 4; t++) {
            bf16x8 ka0 = *(const bf16x8*)&Ks[(t * 16 + fr) * KSTR + fq * 8];
            bf16x8 ka1 = *(const bf16x8*)&Ks[(t * 16 + fr) * KSTR + 32 + fq * 8];
            st[t] = __builtin_amdgcn_mfma_f32_16x16x32_bf16(ka0, qf0, (f32x4){0.f,0.f,0.f,0.f}, 0, 0, 0);
            st[t] = __builtin_amdgcn_mfma_f32_16x16x32_bf16(ka1, qf1, st[t], 0, 0, 0);
        }
        // element (n_loc = t*16 + fq*4 + i, m = fr); scale then row stats over n
        float rmax = -1e30f;
        #pragma unroll
        for (int t = 0; t < 4; t++)
            #pragma unroll
            for (int i = 0; i < 4; i++) {
                st[t][i] *= 0.125f;
                rmax = fmaxf(rmax, st[t][i]);
            }
        rmax = fmaxf(rmax, __shfl_xor(rmax, 16));
        rmax = fmaxf(rmax, __shfl_xor(rmax, 32));
        float newm = fmaxf(mrow, rmax);
        float corr = __expf(mrow - newm);
        mrow = newm;
        float psum = 0.f;
        #pragma unroll
        for (int t = 0; t < 4; t++) {
            bf16x4 pk;
            #pragma unroll
            for (int i = 0; i < 4; i++) {
                float p = __expf(st[t][i] - newm);
                psum += p;
                pk[i] = (__bf16)p;
            }
            // P m-major: row m = wave*16 + fr, cols n = t*16 + fq*4 .. +3
            *(bf16x4*)&Ps[(wave * 16 + fr) * KSTR + t * 16 + fq * 4] = pk;
        }
        psum += __shfl_xor(psum, 16);
        psum += __shfl_xor(psum, 32);
        lrow = lrow * corr + psum;

        // ---- rescale O (rows in C layout: m_loc = fq*4 + i) ----
        #pragma unroll
        for (int i = 0; i < 4; i++) {
            float ci = __shfl(corr, fq * 4 + i);
            #pragma unroll
            for (int dt = 0; dt < 4; dt++) oacc[dt][i] *= ci;
        }

        // ---- O += P·V : A = P (m-major), B = V^T (d-major) ----
        bf16x8 pa0 = *(const bf16x8*)&Ps[(wave * 16 + fr) * KSTR + fq * 8];
        bf16x8 pa1 = *(const bf16x8*)&Ps[(wave * 16 + fr) * KSTR + 32 + fq * 8];
        #pragma unroll
        for (int dt = 0; dt < 4; dt++) {
            bf16x8 vb0 = *(const bf16x8*)&Vs[(dt * 16 + fr) * KSTR + fq * 8];
            bf16x8 vb1 = *(const bf16x8*)&Vs[(dt * 16 + fr) * KSTR + 32 + fq * 8];
            oacc[dt] = __builtin_amdgcn_mfma_f32_16x16x32_bf16(pa0, vb0, oacc[dt], 0, 0, 0);
            oacc[dt] = __builtin_amdgcn_mfma_f32_16x16x32_bf16(pa1, vb1, oacc[dt], 0, 0, 0);
        }
    }

    // ---- epilogue: normalize rows, write (B,S,D) bf16 ----
    float linv = 1.f / lrow;
    #pragma unroll
    for (int i = 0; i < 4; i++) {
        float li = __shfl(linv, fq * 4 + i);
        int s = n * BS_ + wave * 16 + fq * 4 + i;
        __bf16* op = o + ((size_t)b * S_ + s) * D_ + hh * DH_ + fr;
        #pragma unroll
        for (int dt = 0; dt < 4; dt++)
            op[dt * 16] = (__bf16)(oacc[dt][i] * li);
    }
}

// ---------------------------------------------------------------------------
// Row LayerNorm: fp32 in -> fp32 out + bf16 out. 256 thr = 4 rows/block.
// ---------------------------------------------------------------------------
__global__ __launch_bounds__(256) void ln_kernel(
    const float* in, float* outp, __bf16* outb,
    const float* __restrict__ g, const float* __restrict__ bb)
{
    size_t r = (size_t)blockIdx.x * 4 + (threadIdx.x >> 6);
    int t = threadIdx.x & 63;
    const float4* ip = (const float4*)(in + r * D_);
    float4 x0 = ip[2 * t], x1 = ip[2 * t + 1];
    float s = x0.x + x0.y + x0.z + x0.w + x1.x + x1.y + x1.z + x1.w;
    #pragma unroll
    for (int off = 32; off; off >>= 1) s += __shfl_xor(s, off, 64);
    float mean = s * (1.0f / D_);
    float d0 = x0.x - mean, d1 = x0.y - mean, d2 = x0.z - mean, d3 = x0.w - mean;
    float d4 = x1.x - mean, d5 = x1.y - mean, d6 = x1.z - mean, d7 = x1.w - mean;
    float ss = d0*d0 + d1*d1 + d2*d2 + d3*d3 + d4*d4 + d5*d5 + d6*d6 + d7*d7;
    #pragma unroll
    for (int off = 32; off; off >>= 1) ss += __shfl_xor(ss, off, 64);
    float rs = rsqrtf(ss * (1.0f / D_) + 1e-5f);
    float4 g0 = ((const float4*)g)[2 * t], g1 = ((const float4*)g)[2 * t + 1];
    float4 b0 = ((const float4*)bb)[2 * t], b1 = ((const float4*)bb)[2 * t + 1];
    float y[8];
    y[0] = d0 * rs * g0.x + b0.x; y[1] = d1 * rs * g0.y + b0.y;
    y[2] = d2 * rs * g0.z + b0.z; y[3] = d3 * rs * g0.w + b0.w;
    y[4] = d4 * rs * g1.x + b1.x; y[5] = d5 * rs * g1.y + b1.y;
    y[6] = d6 * rs * g1.z + b1.z; y[7] = d7 * rs * g1.w + b1.w;
    float4* op = (float4*)(outp + r * D_);
    op[2 * t]     = (float4){y[0], y[1], y[2], y[3]};
    op[2 * t + 1] = (float4){y[4], y[5], y[6], y[7]};
    bf16x8 hb;
    #pragma unroll
    for (int j = 0; j < 8; j++) hb[j] = (__bf16)y[j];
    *(bf16x8*)(outb + r * D_ + t * 8) = hb;
}

// ---------------------------------------------------------------------------
// Head stage 1: grid (8,4). Block (b,jg): columns j = jg*256 + tid of
// dense = relu(h[b,0,:] @ w_dense + b_dense); partial sums of dense@w_out.
// ---------------------------------------------------------------------------
__global__ __launch_bounds__(256) void head1_kernel(
    const float* __restrict__ h, const float* __restrict__ wd,
    const float* __restrict__ bd, const float* __restrict__ wo,
    float* __restrict__ partial)
{
    __shared__ float hrow[D_];
    __shared__ float red[8];
    int b = blockIdx.x, jg = blockIdx.y;
    int tid = threadIdx.x;
    if (tid < 128) ((float4*)hrow)[tid] = ((const float4*)(h + (size_t)b * S_ * D_))[tid];
    __syncthreads();
    int j = jg * 256 + tid;
    float acc = bd[j];
    #pragma unroll 8
    for (int i = 0; i < D_; i++) acc = fmaf(hrow[i], wd[(size_t)i * 1024 + j], acc);
    float dns = fmaxf(acc, 0.f);
    float2 w2 = ((const float2*)wo)[j];
    float p0 = dns * w2.x, p1 = dns * w2.y;
    #pragma unroll
    for (int off = 32; off; off >>= 1) { p0 += __shfl_xor(p0, off, 64); p1 += __shfl_xor(p1, off, 64); }
    int wid = tid >> 6;
    if ((tid & 63) == 0) { red[wid * 2] = p0; red[wid * 2 + 1] = p1; }
    __syncthreads();
    if (tid == 0) {
        float t0 = red[0] + red[2] + red[4] + red[6];
        float t1 = red[1] + red[3] + red[5] + red[7];
        partial[((size_t)b * 4 + jg) * 2 + 0] = t0;
        partial[((size_t)b * 4 + jg) * 2 + 1] = t1;
    }
}

// Head stage 2: 16 threads, one block.
__global__ __launch_bounds__(64) void head2_kernel(
    const float* __restrict__ partial, const float* __restrict__ bo,
    float* __restrict__ out)
{
    int tid = threadIdx.x;
    if (tid < 16) {
        int b = tid >> 1, c = tid & 1;
        float s = bo[c];
        #pragma unroll
        for (int jg = 0; jg < 4; jg++) s += partial[((size_t)b * 4 + jg) * 2 + c];
        out[b * 2 + c] = tanhf(s);
    }
}

// ---------------------------------------------------------------------------
extern "C" void kernel_launch(void* const* d_in, const int* in_sizes, int n_in,
                              void* d_out, int out_size, void* d_ws, size_t ws_size,
                              hipStream_t stream) {
    (void)in_sizes; (void)n_in; (void)out_size; (void)ws_size;
    const float* x       = (const float*)d_in[0];
    const float* w_embed = (const float*)d_in[1];
    const float* b_embed = (const float*)d_in[2];
    const float* pos_emb = (const float*)d_in[3];
    const float* Wq      = (const float*)d_in[4];
    const float* bq      = (const float*)d_in[5];
    const float* Wk      = (const float*)d_in[6];
    const float* bk      = (const float*)d_in[7];
    const float* Wv      = (const float*)d_in[8];
    const float* bv      = (const float*)d_in[9];
    const float* Wo      = (const float*)d_in[10];
    const float* bo      = (const float*)d_in[11];
    const float* ln1_g   = (const float*)d_in[12];
    const float* ln1_b   = (const float*)d_in[13];
    const float* W1      = (const float*)d_in[14];
    const float* b1      = (const float*)d_in[15];
    const float* W2      = (const float*)d_in[16];
    const float* b2      = (const float*)d_in[17];
    const float* ln2_g   = (const float*)d_in[18];
    const float* ln2_b   = (const float*)d_in[19];
    const float* w_dense = (const float*)d_in[20];
    const float* b_dense = (const float*)d_in[21];
    const float* w_out   = (const float*)d_in[22];
    const float* b_out   = (const float*)d_in[23];
    const int*   rb      = (const int*)d_in[24];
    float* out = (float*)d_out;

    // Workspace layout (total ~141 MiB):
    //  h fp32 (32M) | h_bf (16M) | big bf16 region 64M: qkv(48M)+o(16M) == ff1
    //  (embed phase reuses big: xr @ +0, wt_e @ +28M elems) | wt ~25M @ 112MiB
    //  head partials @ 140 MiB
    const size_t PLANE = (size_t)B_ * H_ * S_ * DH_;  // 8,388,608
    float*  h    = (float*)d_ws;
    __bf16* h_bf = (__bf16*)(h + (size_t)MTOK * D_);
    __bf16* big  = (__bf16*)((char*)d_ws + (size_t)48 * 1024 * 1024);
    __bf16* qkv  = big;
    __bf16* o_bf = big + 3 * PLANE;
    __bf16* ff1  = big;                                // alias, lifetime-disjoint
    __bf16* xr   = big;                                // embed-phase only
    __bf16* wt_e = big + (size_t)28 * 1024 * 1024;     // embed-phase only (512*96)
    __bf16* wt   = (__bf16*)((char*)d_ws + (size_t)112 * 1024 * 1024);
    __bf16* wt_qkv = wt;                               // 3*L*D*D
    __bf16* wt_o   = wt_qkv + (size_t)3 * L_ * DD_;    // L*D*D
    __bf16* wt_1   = wt_o + (size_t)L_ * DD_;          // L*D*FF
    __bf16* wt_2   = wt_1 + (size_t)L_ * D_ * FF_;     // L*FF*D
    float*  hpart  = (float*)((char*)d_ws + (size_t)140 * 1024 * 1024);  // 64 floats

    dim3 tb(32, 8);
    wconv_kernel<<<dim3(16, 16, L_), tb, 0, stream>>>(Wq, wt_qkv,                        D_, D_, D_);
    wconv_kernel<<<dim3(16, 16, L_), tb, 0, stream>>>(Wk, wt_qkv + (size_t)L_ * DD_,     D_, D_, D_);
    wconv_kernel<<<dim3(16, 16, L_), tb, 0, stream>>>(Wv, wt_qkv + (size_t)2 * L_ * DD_, D_, D_, D_);
    wconv_kernel<<<dim3(16, 16, L_), tb, 0, stream>>>(Wo, wt_o,                          D_, D_, D_);
    wconv_kernel<<<dim3(64, 16, L_), tb, 0, stream>>>(W1, wt_1,                          D_, FF_, D_);
    wconv_kernel<<<dim3(16, 64, L_), tb, 0, stream>>>(W2, wt_2,                          FF_, D_, FF_);
    wconv_kernel<<<dim3(16, 3, 1),  tb, 0, stream>>>(w_embed, wt_e,                      80, D_, KE_);

    // Embed = MFMA GEMM: h = xr @ wt_e^T + b_embed + pos_emb (cls row -> pe[0])
    xbuild_kernel<<<MTOK / 64, 256, 0, stream>>>(x, xr);
    mfma_gemm<<<dim3(D_ / 128, MTOK / 128, 1), 256, 0, stream>>>(
        xr, wt_e, b_embed, b_embed, b_embed,
        nullptr, pos_emb, h, h_bf, D_, KE_, 0, 0, 0, 0, 1);

    for (int l = 0; l < L_; l++) {
        // QKV (z folded into x for A-slice reuse; XCD swizzle in-kernel)
        mfma_gemm<<<dim3((D_ / 128) * 3, MTOK / 128, 1), 256, 0, stream>>>(
            h_bf, wt_qkv + (size_t)l * DD_, bq + l * D_, bk + l * D_, bv + l * D_,
            nullptr, nullptr, nullptr, qkv, D_, D_, (long)L_ * DD_, (long)PLANE, 0, 1, 3);

        attn_kernel<<<B_ * H_ * NB_, 256, 0, stream>>>(qkv, qkv + PLANE, qkv + 2 * PLANE, rb, o_bf);

        // h = h + o @ Wo + bo
        mfma_gemm<<<dim3(D_ / 128, MTOK / 128, 1), 256, 0, stream>>>(
            o_bf, wt_o + (size_t)l * DD_, bo + l * D_, bo + l * D_, bo + l * D_,
            h, nullptr, h, nullptr, D_, D_, 0, 0, 0, 0, 1);
        ln_kernel<<<MTOK / 4, 256, 0, stream>>>(h, h, h_bf, ln1_g + l * D_, ln1_b + l * D_);

        // ff1 = relu(h @ W1 + b1), bf16 out
        mfma_gemm<<<dim3(FF_ / 128, MTOK / 128, 1), 256, 0, stream>>>(
            h_bf, wt_1 + (size_t)l * D_ * FF_, b1 + l * FF_, b1 + l * FF_, b1 + l * FF_,
            nullptr, nullptr, nullptr, ff1, FF_, D_, 0, 0, 1, 0, 1);

        // h = h + ff1 @ W2 + b2
        mfma_gemm<<<dim3(D_ / 128, MTOK / 128, 1), 256, 0, stream>>>(
            ff1, wt_2 + (size_t)l * FF_ * D_, b2 + l * D_, b2 + l * D_, b2 + l * D_,
            h, nullptr, h, nullptr, D_, FF_, 0, 0, 0, 0, 1);
        ln_kernel<<<MTOK / 4, 256, 0, stream>>>(h, h, h_bf, ln2_g + l * D_, ln2_b + l * D_);
    }

    head1_kernel<<<dim3(B_, 4), 256, 0, stream>>>(h, w_dense, b_dense, w_out, hpart);
    head2_kernel<<<1, 64, 0, stream>>>(hpart, b_out, out);
}

// Round 9
// 1306.897 us; speedup vs baseline: 6.8411x; 1.0379x over previous
//
#include <hip/hip_runtime.h>
#include <cstdint>
#include <cstddef>

// Problem constants
#define B_   8
#define NM_  10
#define T_   16376
#define D_   512
#define H_   8
#define DH_  64
#define L_   4
#define S_   2048
#define NB_  32
#define BS_  64
#define FF_  2048
#define MTOK (B_*S_)   // 16384 token rows
#define DD_  (D_*D_)
#define KE_  96        // embed K padded (80 -> 96)

typedef __attribute__((ext_vector_type(8))) __bf16 bf16x8;
typedef __attribute__((ext_vector_type(4))) __bf16 bf16x4;
typedef __attribute__((ext_vector_type(4))) float f32x4;

__device__ __forceinline__ void async16(void* lds, const void* g) {
    __builtin_amdgcn_global_load_lds(
        (const __attribute__((address_space(1))) void*)g,
        (__attribute__((address_space(3))) void*)lds, 16, 0, 0);
}

// XOR-swizzled 16B-chunk index for a 128row x 32el bf16 tile.
// (row,kq) -> chunk row*4 + (kq ^ ((row>>1)&3)).  For a 16-lane fragment-read
// group this spreads lanes 2-per-bank-group (2-way = free) vs 8-way unswizzled.
#define SWZC(row, kq) (((row) << 2) + ((kq) ^ (((row) >> 1) & 3)))

// ---------------------------------------------------------------------------
// Weight transpose+convert: in (K x N fp32, z-strided) -> out (N x Kp bf16),
// zero-padding k in [K, Kp). Grid: (N/32, Kp/32, Z).
// ---------------------------------------------------------------------------
__global__ __launch_bounds__(256) void wconv_kernel(
    const float* __restrict__ in, __bf16* __restrict__ outp, int K, int N, int Kp)
{
    __shared__ float t[32][33];
    const float* ip = in + (size_t)blockIdx.z * K * N;
    __bf16* op = outp + (size_t)blockIdx.z * N * Kp;
    int n0 = blockIdx.x * 32, k0 = blockIdx.y * 32;
    int tx = threadIdx.x, ty = threadIdx.y;   // 32 x 8
    #pragma unroll
    for (int j = 0; j < 4; j++) {
        int k = k0 + ty + 8 * j;
        t[ty + 8 * j][tx] = (k < K) ? ip[(size_t)k * N + n0 + tx] : 0.f;
    }
    __syncthreads();
    #pragma unroll
    for (int j = 0; j < 4; j++)
        op[(size_t)(n0 + ty + 8 * j) * Kp + k0 + tx] = (__bf16)t[tx][ty + 8 * j];
}

// ---------------------------------------------------------------------------
// Build xr (MTOK x KE_ bf16): xr[b*2048+t][m] = x[b, m/8, (m%8)*2047 + t-1]
// for t>=1, m<80; else 0. One block per 64 rows (same b).
// ---------------------------------------------------------------------------
__global__ __launch_bounds__(256) void xbuild_kernel(
    const float* __restrict__ x, __bf16* __restrict__ xr)
{
    __shared__ float xs[64][97];
    int row0 = blockIdx.x * 64;
    int b = row0 >> 11;
    int t0 = row0 & (S_ - 1);
    int tid = threadIdx.x;
    int lane = tid & 63;
    int mq = tid >> 6;          // 0..3
    // phase 1: coalesced loads over t for each m
    for (int mb = 0; mb < 24; mb++) {
        int m = mb * 4 + mq;    // 0..95
        int t = t0 + lane;
        float v = 0.f;
        if (m < 80 && t > 0)
            v = x[(size_t)b * NM_ * T_ + (size_t)(m >> 3) * T_ + (m & 7) * 2047 + (t - 1)];
        xs[lane][m] = v;
    }
    __syncthreads();
    // phase 2: row-major bf16 write, 8B chunks
    #pragma unroll
    for (int u = 0; u < 6; u++) {
        int ch = tid + u * 256;          // 0..1535
        int row = ch / 24, c4 = (ch % 24) * 4;
        bf16x4 pk;
        #pragma unroll
        for (int i = 0; i < 4; i++) pk[i] = (__bf16)xs[row][c4 + i];
        *(bf16x4*)&xr[(size_t)(row0 + row) * KE_ + c4] = pk;
    }
}

// ---------------------------------------------------------------------------
// MFMA bf16 GEMM: C = A(MxK bf16) @ Wt^T + bias [+res] [+posemb] [relu]
// Wt is N x K bf16 (pre-transposed). 128x128 tile, BK=32, 256 thr (4 waves).
// Double-buffered LDS (prefetch tile k+1 after the barrier, compute tile k)
// + XOR-swizzled tile layout (see SWZC) -> conflict-free ds_read_b128.
// z folded into x index; XCD-aware swizzle maps each XCD to a contiguous
// band of bm rows so A-slices live in ONE XCD's private L2.
// Outputs: Cf (fp32 MxN, optional), Cb (bf16, optional).
// scatter==1: z in {0,1} -> (B,H,S,DH); z==2 -> V transposed (B,H,DH,S).
// pe != null: val += pe[(row&2047)*N + col]; row with t==0 -> val = pe[col].
// ---------------------------------------------------------------------------
__global__ __launch_bounds__(256, 2) void mfma_gemm(
    const __bf16* __restrict__ A, const __bf16* __restrict__ Wt,
    const float* __restrict__ bias0, const float* __restrict__ bias1,
    const float* __restrict__ bias2,
    const float* res, const float* __restrict__ pe, float* Cf, __bf16* Cb,
    int N, int K, long wtz, long cbz, int relu, int scatter, int nz)
{
    __shared__ __align__(16) __bf16 As[2][128 * 32];
    __shared__ __align__(16) __bf16 Bs[2][128 * 32];
    int tid = threadIdx.x;
    int wave = tid >> 6;
    int lane = tid & 63;

    int nbx = gridDim.x, nby = gridDim.y;
    int bxIdx, bmIdx;
    if ((nby & 7) == 0) {
        int id = blockIdx.y * nbx + blockIdx.x;   // dispatch-linear order
        int chunk = nby >> 3;
        int xcd = id & 7;
        int local = id >> 3;
        int row = local / nbx;
        bmIdx = xcd * chunk + row;
        bxIdx = local - row * nbx;
    } else {
        bxIdx = blockIdx.x; bmIdx = blockIdx.y;
    }
    int z = bxIdx % nz;
    int bn = (bxIdx / nz) * 128;
    int bm = bmIdx * 128;
    const __bf16* Wz = Wt + (size_t)z * wtz;
    const float* bias = (z == 0) ? bias0 : (z == 1 ? bias1 : bias2);

    f32x4 acc[4][4];
    #pragma unroll
    for (int r = 0; r < 4; r++)
        #pragma unroll
        for (int c = 0; c < 4; c++) acc[r][c] = (f32x4){0.f, 0.f, 0.f, 0.f};

    const int wr = (wave >> 1) * 64;
    const int wc = (wave & 1) * 64;
    const int fr = lane & 15;
    const int kqi = lane >> 4;

    // staging: physical chunk ch holds (row = ch>>2, kq = (ch&3) ^ ((ch>>3)&3))
    const int c0 = tid, c1 = tid + 256;
    const int r0 = c0 >> 2, q0 = (c0 & 3) ^ ((c0 >> 3) & 3);
    const int r1 = c1 >> 2, q1 = (c1 & 3) ^ ((c1 >> 3) & 3);
    const __bf16* Ag0 = A  + (size_t)(bm + r0) * K + q0 * 8;
    const __bf16* Ag1 = A  + (size_t)(bm + r1) * K + q1 * 8;
    const __bf16* Bg0 = Wz + (size_t)(bn + r0) * K + q0 * 8;
    const __bf16* Bg1 = Wz + (size_t)(bn + r1) * K + q1 * 8;
    const int wb0 = wave * 512;          // element offset of this wave's chunk run
    const int wb1 = 2048 + wave * 512;

    __bf16 *a_cur = As[0], *a_nxt = As[1];
    __bf16 *b_cur = Bs[0], *b_nxt = Bs[1];

    // prefetch tile 0
    async16(a_cur + wb0, Ag0);
    async16(a_cur + wb1, Ag1);
    async16(b_cur + wb0, Bg0);
    async16(b_cur + wb1, Bg1);

    for (int kk = 0; kk < K; kk += 32) {
        __syncthreads();                 // drains vmcnt: tile kk resident; prior readers of nxt done
        if (kk + 32 < K) {               // prefetch tile kk+32 (overlaps compute below)
            async16(a_nxt + wb0, Ag0 + kk + 32);
            async16(a_nxt + wb1, Ag1 + kk + 32);
            async16(b_nxt + wb0, Bg0 + kk + 32);
            async16(b_nxt + wb1, Bg1 + kk + 32);
        }
        bf16x8 af[4], bfr[4];
        #pragma unroll
        for (int r = 0; r < 4; r++)
            af[r] = *(const bf16x8*)&a_cur[SWZC(wr + r * 16 + fr, kqi) * 8];
        #pragma unroll
        for (int c = 0; c < 4; c++)
            bfr[c] = *(const bf16x8*)&b_cur[SWZC(wc + c * 16 + fr, kqi) * 8];
        #pragma unroll
        for (int r = 0; r < 4; r++)
            #pragma unroll
            for (int c = 0; c < 4; c++)
                acc[r][c] = __builtin_amdgcn_mfma_f32_16x16x32_bf16(af[r], bfr[c], acc[r][c], 0, 0, 0);
        __bf16* t;
        t = a_cur; a_cur = a_nxt; a_nxt = t;
        t = b_cur; b_cur = b_nxt; b_nxt = t;
    }

    // epilogue: C/D layout col = lane&15, row = (lane>>4)*4 + reg
    int rbase = bm + wr + (lane >> 4) * 4;
    #pragma unroll
    for (int c = 0; c < 4; c++) {
        int cg = bn + wc + c * 16 + fr;
        float bv = bias[cg];
        #pragma unroll
        for (int r = 0; r < 4; r++) {
            int rg0 = rbase + r * 16;   // 4-aligned
            float vals[4];
            #pragma unroll
            for (int i = 0; i < 4; i++) {
                float val = acc[r][c][i] + bv;
                if (relu) val = fmaxf(val, 0.f);
                if (res) val += res[(size_t)(rg0 + i) * N + cg];
                if (pe) {
                    int t = (rg0 + i) & (S_ - 1);
                    val = (t == 0) ? pe[cg] : val + pe[(size_t)t * N + cg];
                }
                vals[i] = val;
            }
            if (Cf) {
                #pragma unroll
                for (int i = 0; i < 4; i++) Cf[(size_t)(rg0 + i) * N + cg] = vals[i];
            }
            if (Cb) {
                if (scatter) {
                    int bb = rg0 >> 11;
                    int s0 = rg0 & (S_ - 1);
                    int hh = cg >> 6, dh = cg & 63;
                    if (z == 2) {
                        // V transposed: (B,H,DH,S), pack 4 consecutive s
                        bf16x4 pk;
                        #pragma unroll
                        for (int i = 0; i < 4; i++) pk[i] = (__bf16)vals[i];
                        *(bf16x4*)(Cb + (size_t)z * cbz +
                                   ((((size_t)bb * H_ + hh) * DH_ + dh) * S_) + s0) = pk;
                    } else {
                        #pragma unroll
                        for (int i = 0; i < 4; i++)
                            (Cb + (size_t)z * cbz)[((((size_t)bb * H_ + hh) * S_ + s0 + i) * DH_) + dh] = (__bf16)vals[i];
                    }
                } else {
                    #pragma unroll
                    for (int i = 0; i < 4; i++) Cb[(size_t)(rg0 + i) * N + cg] = (__bf16)vals[i];
                }
            }
        }
    }
}

// ---------------------------------------------------------------------------
// MFMA block-sparse attention. One workgroup (4 waves) per (b,h,n); each wave
// owns 16 q-rows. K staged n-major, V^T staged d-major (from (B,H,DH,S)
// global layout). S^T = K·Q^T via MFMA (row stats at lane&15 -> 2 shuffles);
// P round-trips LDS m-major; PV via MFMA (A=P, B=V^T). Online softmax.
// ---------------------------------------------------------------------------
#define KSTR 72
__global__ __launch_bounds__(256, 4) void attn_kernel(
    const __bf16* __restrict__ q, const __bf16* __restrict__ k,
    const __bf16* __restrict__ vt, const int* __restrict__ rb,
    __bf16* __restrict__ o)
{
    __shared__ __align__(16) __bf16 Ks[64 * KSTR];
    __shared__ __align__(16) __bf16 Vs[64 * KSTR];
    __shared__ __align__(16) __bf16 Ps[64 * KSTR];
    int bid = blockIdx.x;
    int n = bid & (NB_ - 1);
    int hh = (bid >> 5) & (H_ - 1);
    int b = bid >> 8;
    int tid = threadIdx.x;
    int wave = tid >> 6;
    int lane = tid & 63;
    const int fr = lane & 15;
    const int fq = lane >> 4;

    int idx[6];
    idx[0] = 0;
    idx[1] = n > 0 ? n - 1 : 0;
    idx[2] = n;
    idx[3] = n < NB_ - 1 ? n + 1 : NB_ - 1;
    idx[4] = rb[n * 2 + 0];
    idx[5] = rb[n * 2 + 1];

    const size_t plane = ((size_t)b * H_ + hh) * S_;           // q,k row base
    const __bf16* vtb = vt + plane * DH_;                      // (B,H,DH,S) plane

    // Q fragments (B-operand): row m = wave*16 + fr, k = fq*8 (+32)
    const __bf16* qrow = q + (plane + (size_t)n * BS_ + wave * 16 + fr) * DH_ + fq * 8;
    bf16x8 qf0 = *(const bf16x8*)qrow;
    bf16x8 qf1 = *(const bf16x8*)(qrow + 32);

    f32x4 oacc[4];
    #pragma unroll
    for (int dt = 0; dt < 4; dt++) oacc[dt] = (f32x4){0.f, 0.f, 0.f, 0.f};
    float mrow = -1e30f, lrow = 0.f;

    for (int c = 0; c < 6; c++) {
        bool dup = false;
        #pragma unroll
        for (int j = 0; j < 6; j++) if (j < c && idx[j] == idx[c]) dup = true;
        if (dup) continue;   // uniform across workgroup

        __syncthreads();     // prior iteration's reads of Ks/Vs complete
        // ---- stage K (n-major) and V^T (d-major), 512 16B chunks each ----
        {
            const __bf16* kb = k + (plane + (size_t)idx[c] * BS_) * DH_;
            const __bf16* vb = vtb + (size_t)idx[c] * BS_;
            #pragma unroll
            for (int u = 0; u < 2; u++) {
                int ch = tid + u * 256;
                int row = ch >> 3, d0 = (ch & 7) * 8;
                *(bf16x8*)&Ks[row * KSTR + d0] = *(const bf16x8*)(kb + row * DH_ + d0);
                *(bf16x8*)&Vs[row * KSTR + d0] = *(const bf16x8*)(vb + (size_t)row * S_ + d0);
            }
        }
        __syncthreads();

        // ---- S^T = K·Q^T : rows = keys, cols = q ----
        f32x4 st[4];
        #pragma unroll
        for (int t = 0; t < 4; t++) {
            bf16x8 ka0 = *(const bf16x8*)&Ks[(t * 16 + fr) * KSTR + fq * 8];
            bf16x8 ka1 = *(const bf16x8*)&Ks[(t * 16 + fr) * KSTR + 32 + fq * 8];
            st[t] = __builtin_amdgcn_mfma_f32_16x16x32_bf16(ka0, qf0, (f32x4){0.f,0.f,0.f,0.f}, 0, 0, 0);
            st[t] = __builtin_amdgcn_mfma_f32_16x16x32_bf16(ka1, qf1, st[t], 0, 0, 0);
        }
        // element (n_loc = t*16 + fq*4 + i, m = fr); scale then row stats over n
        float rmax = -1e30f;
        #pragma unroll
        for (int t = 0; t < 4; t++)
            #pragma unroll
            for (int i = 0; i < 4; i++) {
                st[t][i] *= 0.125f;
                rmax = fmaxf(rmax, st[t][i]);
            }
        rmax = fmaxf(rmax, __shfl_xor(rmax, 16));
        rmax = fmaxf(rmax, __shfl_xor(rmax, 32));
        float newm = fmaxf(mrow, rmax);
        float corr = __expf(mrow - newm);
        mrow = newm;
        float psum = 0.f;
        #pragma unroll
        for (int t = 0; t < 4; t++) {
            bf16x4 pk;
            #pragma unroll
            for (int i = 0; i < 4; i++) {
                float p = __expf(st[t][i] - newm);
                psum += p;
                pk[i] = (__bf16)p;
            }
            // P m-major: row m = wave*16 + fr, cols n = t*16 + fq*4 .. +3
            *(bf16x4*)&Ps[(wave * 16 + fr) * KSTR + t * 16 + fq * 4] = pk;
        }
        psum += __shfl_xor(psum, 16);
        psum += __shfl_xor(psum, 32);
        lrow = lrow * corr + psum;

        // ---- rescale O (rows in C layout: m_loc = fq*4 + i) ----
        #pragma unroll
        for (int i = 0; i < 4; i++) {
            float ci = __shfl(corr, fq * 4 + i);
            #pragma unroll
            for (int dt = 0; dt < 4; dt++) oacc[dt][i] *= ci;
        }

        // ---- O += P·V : A = P (m-major), B = V^T (d-major) ----
        bf16x8 pa0 = *(const bf16x8*)&Ps[(wave * 16 + fr) * KSTR + fq * 8];
        bf16x8 pa1 = *(const bf16x8*)&Ps[(wave * 16 + fr) * KSTR + 32 + fq * 8];
        #pragma unroll
        for (int dt = 0; dt < 4; dt++) {
            bf16x8 vb0 = *(const bf16x8*)&Vs[(dt * 16 + fr) * KSTR + fq * 8];
            bf16x8 vb1 = *(const bf16x8*)&Vs[(dt * 16 + fr) * KSTR + 32 + fq * 8];
            oacc[dt] = __builtin_amdgcn_mfma_f32_16x16x32_bf16(pa0, vb0, oacc[dt], 0, 0, 0);
            oacc[dt] = __builtin_amdgcn_mfma_f32_16x16x32_bf16(pa1, vb1, oacc[dt], 0, 0, 0);
        }
    }

    // ---- epilogue: normalize rows, write (B,S,D) bf16 ----
    float linv = 1.f / lrow;
    #pragma unroll
    for (int i = 0; i < 4; i++) {
        float li = __shfl(linv, fq * 4 + i);
        int s = n * BS_ + wave * 16 + fq * 4 + i;
        __bf16* op = o + ((size_t)b * S_ + s) * D_ + hh * DH_ + fr;
        #pragma unroll
        for (int dt = 0; dt < 4; dt++)
            op[dt * 16] = (__bf16)(oacc[dt][i] * li);
    }
}

// ---------------------------------------------------------------------------
// Row LayerNorm: fp32 in -> fp32 out + bf16 out. 256 thr = 4 rows/block.
// ---------------------------------------------------------------------------
__global__ __launch_bounds__(256) void ln_kernel(
    const float* in, float* outp, __bf16* outb,
    const float* __restrict__ g, const float* __restrict__ bb)
{
    size_t r = (size_t)blockIdx.x * 4 + (threadIdx.x >> 6);
    int t = threadIdx.x & 63;
    const float4* ip = (const float4*)(in + r * D_);
    float4 x0 = ip[2 * t], x1 = ip[2 * t + 1];
    float s = x0.x + x0.y + x0.z + x0.w + x1.x + x1.y + x1.z + x1.w;
    #pragma unroll
    for (int off = 32; off; off >>= 1) s += __shfl_xor(s, off, 64);
    float mean = s * (1.0f / D_);
    float d0 = x0.x - mean, d1 = x0.y - mean, d2 = x0.z - mean, d3 = x0.w - mean;
    float d4 = x1.x - mean, d5 = x1.y - mean, d6 = x1.z - mean, d7 = x1.w - mean;
    float ss = d0*d0 + d1*d1 + d2*d2 + d3*d3 + d4*d4 + d5*d5 + d6*d6 + d7*d7;
    #pragma unroll
    for (int off = 32; off; off >>= 1) ss += __shfl_xor(ss, off, 64);
    float rs = rsqrtf(ss * (1.0f / D_) + 1e-5f);
    float4 g0 = ((const float4*)g)[2 * t], g1 = ((const float4*)g)[2 * t + 1];
    float4 b0 = ((const float4*)bb)[2 * t], b1 = ((const float4*)bb)[2 * t + 1];
    float y[8];
    y[0] = d0 * rs * g0.x + b0.x; y[1] = d1 * rs * g0.y + b0.y;
    y[2] = d2 * rs * g0.z + b0.z; y[3] = d3 * rs * g0.w + b0.w;
    y[4] = d4 * rs * g1.x + b1.x; y[5] = d5 * rs * g1.y + b1.y;
    y[6] = d6 * rs * g1.z + b1.z; y[7] = d7 * rs * g1.w + b1.w;
    float4* op = (float4*)(outp + r * D_);
    op[2 * t]     = (float4){y[0], y[1], y[2], y[3]};
    op[2 * t + 1] = (float4){y[4], y[5], y[6], y[7]};
    bf16x8 hb;
    #pragma unroll
    for (int j = 0; j < 8; j++) hb[j] = (__bf16)y[j];
    *(bf16x8*)(outb + r * D_ + t * 8) = hb;
}

// ---------------------------------------------------------------------------
// Head stage 1: grid (8,4). Block (b,jg): columns j = jg*256 + tid of
// dense = relu(h[b,0,:] @ w_dense + b_dense); partial sums of dense@w_out.
// ---------------------------------------------------------------------------
__global__ __launch_bounds__(256) void head1_kernel(
    const float* __restrict__ h, const float* __restrict__ wd,
    const float* __restrict__ bd, const float* __restrict__ wo,
    float* __restrict__ partial)
{
    __shared__ float hrow[D_];
    __shared__ float red[8];
    int b = blockIdx.x, jg = blockIdx.y;
    int tid = threadIdx.x;
    if (tid < 128) ((float4*)hrow)[tid] = ((const float4*)(h + (size_t)b * S_ * D_))[tid];
    __syncthreads();
    int j = jg * 256 + tid;
    float acc = bd[j];
    #pragma unroll 8
    for (int i = 0; i < D_; i++) acc = fmaf(hrow[i], wd[(size_t)i * 1024 + j], acc);
    float dns = fmaxf(acc, 0.f);
    float2 w2 = ((const float2*)wo)[j];
    float p0 = dns * w2.x, p1 = dns * w2.y;
    #pragma unroll
    for (int off = 32; off; off >>= 1) { p0 += __shfl_xor(p0, off, 64); p1 += __shfl_xor(p1, off, 64); }
    int wid = tid >> 6;
    if ((tid & 63) == 0) { red[wid * 2] = p0; red[wid * 2 + 1] = p1; }
    __syncthreads();
    if (tid == 0) {
        float t0 = red[0] + red[2] + red[4] + red[6];
        float t1 = red[1] + red[3] + red[5] + red[7];
        partial[((size_t)b * 4 + jg) * 2 + 0] = t0;
        partial[((size_t)b * 4 + jg) * 2 + 1] = t1;
    }
}

// Head stage 2: 16 threads, one block.
__global__ __launch_bounds__(64) void head2_kernel(
    const float* __restrict__ partial, const float* __restrict__ bo,
    float* __restrict__ out)
{
    int tid = threadIdx.x;
    if (tid < 16) {
        int b = tid >> 1, c = tid & 1;
        float s = bo[c];
        #pragma unroll
        for (int jg = 0; jg < 4; jg++) s += partial[((size_t)b * 4 + jg) * 2 + c];
        out[b * 2 + c] = tanhf(s);
    }
}

// ---------------------------------------------------------------------------
extern "C" void kernel_launch(void* const* d_in, const int* in_sizes, int n_in,
                              void* d_out, int out_size, void* d_ws, size_t ws_size,
                              hipStream_t stream) {
    (void)in_sizes; (void)n_in; (void)out_size; (void)ws_size;
    const float* x       = (const float*)d_in[0];
    const float* w_embed = (const float*)d_in[1];
    const float* b_embed = (const float*)d_in[2];
    const float* pos_emb = (const float*)d_in[3];
    const float* Wq      = (const float*)d_in[4];
    const float* bq      = (const float*)d_in[5];
    const float* Wk      = (const float*)d_in[6];
    const float* bk      = (const float*)d_in[7];
    const float* Wv      = (const float*)d_in[8];
    const float* bv      = (const float*)d_in[9];
    const float* Wo      = (const float*)d_in[10];
    const float* bo      = (const float*)d_in[11];
    const float* ln1_g   = (const float*)d_in[12];
    const float* ln1_b   = (const float*)d_in[13];
    const float* W1      = (const float*)d_in[14];
    const float* b1      = (const float*)d_in[15];
    const float* W2      = (const float*)d_in[16];
    const float* b2      = (const float*)d_in[17];
    const float* ln2_g   = (const float*)d_in[18];
    const float* ln2_b   = (const float*)d_in[19];
    const float* w_dense = (const float*)d_in[20];
    const float* b_dense = (const float*)d_in[21];
    const float* w_out   = (const float*)d_in[22];
    const float* b_out   = (const float*)d_in[23];
    const int*   rb      = (const int*)d_in[24];
    float* out = (float*)d_out;

    // Workspace layout (total ~141 MiB):
    //  h fp32 (32M) | h_bf (16M) | big bf16 region 64M: qkv(48M)+o(16M) == ff1
    //  (embed phase reuses big: xr @ +0, wt_e @ +28M elems) | wt ~25M @ 112MiB
    //  head partials @ 140 MiB
    const size_t PLANE = (size_t)B_ * H_ * S_ * DH_;  // 8,388,608
    float*  h    = (float*)d_ws;
    __bf16* h_bf = (__bf16*)(h + (size_t)MTOK * D_);
    __bf16* big  = (__bf16*)((char*)d_ws + (size_t)48 * 1024 * 1024);
    __bf16* qkv  = big;
    __bf16* o_bf = big + 3 * PLANE;
    __bf16* ff1  = big;                                // alias, lifetime-disjoint
    __bf16* xr   = big;                                // embed-phase only
    __bf16* wt_e = big + (size_t)28 * 1024 * 1024;     // embed-phase only (512*96)
    __bf16* wt   = (__bf16*)((char*)d_ws + (size_t)112 * 1024 * 1024);
    __bf16* wt_qkv = wt;                               // 3*L*D*D
    __bf16* wt_o   = wt_qkv + (size_t)3 * L_ * DD_;    // L*D*D
    __bf16* wt_1   = wt_o + (size_t)L_ * DD_;          // L*D*FF
    __bf16* wt_2   = wt_1 + (size_t)L_ * D_ * FF_;     // L*FF*D
    float*  hpart  = (float*)((char*)d_ws + (size_t)140 * 1024 * 1024);  // 64 floats

    dim3 tb(32, 8);
    wconv_kernel<<<dim3(16, 16, L_), tb, 0, stream>>>(Wq, wt_qkv,                        D_, D_, D_);
    wconv_kernel<<<dim3(16, 16, L_), tb, 0, stream>>>(Wk, wt_qkv + (size_t)L_ * DD_,     D_, D_, D_);
    wconv_kernel<<<dim3(16, 16, L_), tb, 0, stream>>>(Wv, wt_qkv + (size_t)2 * L_ * DD_, D_, D_, D_);
    wconv_kernel<<<dim3(16, 16, L_), tb, 0, stream>>>(Wo, wt_o,                          D_, D_, D_);
    wconv_kernel<<<dim3(64, 16, L_), tb, 0, stream>>>(W1, wt_1,                          D_, FF_, D_);
    wconv_kernel<<<dim3(16, 64, L_), tb, 0, stream>>>(W2, wt_2,                          FF_, D_, FF_);
    wconv_kernel<<<dim3(16, 3, 1),  tb, 0, stream>>>(w_embed, wt_e,                      80, D_, KE_);

    // Embed = MFMA GEMM: h = xr @ wt_e^T + b_embed + pos_emb (cls row -> pe[0])
    xbuild_kernel<<<MTOK / 64, 256, 0, stream>>>(x, xr);
    mfma_gemm<<<dim3(D_ / 128, MTOK / 128, 1), 256, 0, stream>>>(
        xr, wt_e, b_embed, b_embed, b_embed,
        nullptr, pos_emb, h, h_bf, D_, KE_, 0, 0, 0, 0, 1);

    for (int l = 0; l < L_; l++) {
        // QKV (z folded into x for A-slice reuse; XCD swizzle in-kernel)
        mfma_gemm<<<dim3((D_ / 128) * 3, MTOK / 128, 1), 256, 0, stream>>>(
            h_bf, wt_qkv + (size_t)l * DD_, bq + l * D_, bk + l * D_, bv + l * D_,
            nullptr, nullptr, nullptr, qkv, D_, D_, (long)L_ * DD_, (long)PLANE, 0, 1, 3);

        attn_kernel<<<B_ * H_ * NB_, 256, 0, stream>>>(qkv, qkv + PLANE, qkv + 2 * PLANE, rb, o_bf);

        // h = h + o @ Wo + bo
        mfma_gemm<<<dim3(D_ / 128, MTOK / 128, 1), 256, 0, stream>>>(
            o_bf, wt_o + (size_t)l * DD_, bo + l * D_, bo + l * D_, bo + l * D_,
            h, nullptr, h, nullptr, D_, D_, 0, 0, 0, 0, 1);
        ln_kernel<<<MTOK / 4, 256, 0, stream>>>(h, h, h_bf, ln1_g + l * D_, ln1_b + l * D_);

        // ff1 = relu(h @ W1 + b1), bf16 out
        mfma_gemm<<<dim3(FF_ / 128, MTOK / 128, 1), 256, 0, stream>>>(
            h_bf, wt_1 + (size_t)l * D_ * FF_, b1 + l * FF_, b1 + l * FF_, b1 + l * FF_,
            nullptr, nullptr, nullptr, ff1, FF_, D_, 0, 0, 1, 0, 1);

        // h = h + ff1 @ W2 + b2
        mfma_gemm<<<dim3(D_ / 128, MTOK / 128, 1), 256, 0, stream>>>(
            ff1, wt_2 + (size_t)l * FF_ * D_, b2 + l * D_, b2 + l * D_, b2 + l * D_,
            h, nullptr, h, nullptr, D_, FF_, 0, 0, 0, 0, 1);
        ln_kernel<<<MTOK / 4, 256, 0, stream>>>(h, h, h_bf, ln2_g + l * D_, ln2_b + l * D_);
    }

    head1_kernel<<<dim3(B_, 4), 256, 0, stream>>>(h, w_dense, b_dense, w_out, hpart);
    head2_kernel<<<1, 64, 0, stream>>>(hpart, b_out, out);
}

// Round 10
// 1184.240 us; speedup vs baseline: 7.5496x; 1.1036x over previous
//
#include <hip/hip_runtime.h>
#include <cstdint>
#include <cstddef>

// Problem constants
#define B_   8
#define NM_  10
#define T_   16376
#define D_   512
#define H_   8
#define DH_  64
#define L_   4
#define S_   2048
#define NB_  32
#define BS_  64
#define FF_  2048
#define MTOK (B_*S_)   // 16384 token rows
#define DD_  (D_*D_)
#define KE_  128       // embed K padded (80 -> 128, divisible by BK=64)

typedef __attribute__((ext_vector_type(8))) __bf16 bf16x8;
typedef __attribute__((ext_vector_type(4))) __bf16 bf16x4;
typedef __attribute__((ext_vector_type(4))) float f32x4;

__device__ __forceinline__ void async16(void* lds, const void* g) {
    __builtin_amdgcn_global_load_lds(
        (const __attribute__((address_space(1))) void*)g,
        (__attribute__((address_space(3))) void*)lds, 16, 0, 0);
}

// XOR-swizzled 16B-chunk index for a 128row x 64el bf16 tile (8 chunks/row).
// (row,kq) -> row*8 + (kq ^ (row&7)). A 16-lane fragment-read group (rows
// consecutive, kq fixed) hits all 8 chunk residues 2x -> balanced 8/bank.
#define SWZ64(row, kq) (((row) << 3) + ((kq) ^ ((row) & 7)))

// ---------------------------------------------------------------------------
// Weight transpose+convert: in (K x N fp32) -> out (N x Kp bf16), zero-pad
// k in [K, Kp). Grid: (N/32, Kp/32, Z) with z-strided in/out.
// ---------------------------------------------------------------------------
__global__ __launch_bounds__(256) void wconv_kernel(
    const float* __restrict__ in, __bf16* __restrict__ outp, int K, int N, int Kp)
{
    __shared__ float t[32][33];
    const float* ip = in + (size_t)blockIdx.z * K * N;
    __bf16* op = outp + (size_t)blockIdx.z * N * Kp;
    int n0 = blockIdx.x * 32, k0 = blockIdx.y * 32;
    int tx = threadIdx.x, ty = threadIdx.y;   // 32 x 8
    #pragma unroll
    for (int j = 0; j < 4; j++) {
        int k = k0 + ty + 8 * j;
        t[ty + 8 * j][tx] = (k < K) ? ip[(size_t)k * N + n0 + tx] : 0.f;
    }
    __syncthreads();
    #pragma unroll
    for (int j = 0; j < 4; j++)
        op[(size_t)(n0 + ty + 8 * j) * Kp + k0 + tx] = (__bf16)t[tx][ty + 8 * j];
}

// Merged Wq/Wk/Wv/Wo transpose (all D_ x D_). Grid (16,16,16): z = mat*4+layer.
__global__ __launch_bounds__(256) void wconv_qkvo(
    const float* __restrict__ wq, const float* __restrict__ wk,
    const float* __restrict__ wv, const float* __restrict__ wo,
    __bf16* __restrict__ wtqkv, __bf16* __restrict__ wto)
{
    __shared__ float t[32][33];
    int zz = blockIdx.z;
    int mat = zz >> 2, layer = zz & 3;
    const float* src = (mat == 0 ? wq : mat == 1 ? wk : mat == 2 ? wv : wo)
                       + (size_t)layer * DD_;
    __bf16* dst = (mat < 3) ? wtqkv + ((size_t)mat * L_ + layer) * DD_
                            : wto + (size_t)layer * DD_;
    int n0 = blockIdx.x * 32, k0 = blockIdx.y * 32;
    int tx = threadIdx.x, ty = threadIdx.y;   // 32 x 8
    #pragma unroll
    for (int j = 0; j < 4; j++)
        t[ty + 8 * j][tx] = src[(size_t)(k0 + ty + 8 * j) * D_ + n0 + tx];
    __syncthreads();
    #pragma unroll
    for (int j = 0; j < 4; j++)
        dst[(size_t)(n0 + ty + 8 * j) * D_ + k0 + tx] = (__bf16)t[tx][ty + 8 * j];
}

// ---------------------------------------------------------------------------
// Build xr (MTOK x KE_ bf16): xr[b*2048+t][m] = x[b, m/8, (m%8)*2047 + t-1]
// for t>=1, m<80; else 0. One block per 64 rows (same b).
// ---------------------------------------------------------------------------
__global__ __launch_bounds__(256) void xbuild_kernel(
    const float* __restrict__ x, __bf16* __restrict__ xr)
{
    __shared__ float xs[64][KE_ + 1];
    int row0 = blockIdx.x * 64;
    int b = row0 >> 11;
    int t0 = row0 & (S_ - 1);
    int tid = threadIdx.x;
    int lane = tid & 63;
    int mq = tid >> 6;          // 0..3
    // phase 1: coalesced loads over t for each m
    for (int mb = 0; mb < 32; mb++) {
        int m = mb * 4 + mq;    // 0..127
        int t = t0 + lane;
        float v = 0.f;
        if (m < 80 && t > 0)
            v = x[(size_t)b * NM_ * T_ + (size_t)(m >> 3) * T_ + (m & 7) * 2047 + (t - 1)];
        xs[lane][m] = v;
    }
    __syncthreads();
    // phase 2: row-major bf16 write, 8B chunks (64 rows x 32 chunks)
    #pragma unroll
    for (int u = 0; u < 8; u++) {
        int ch = tid + u * 256;          // 0..2047
        int row = ch >> 5, c4 = (ch & 31) * 4;
        bf16x4 pk;
        #pragma unroll
        for (int i = 0; i < 4; i++) pk[i] = (__bf16)xs[row][c4 + i];
        *(bf16x4*)&xr[(size_t)(row0 + row) * KE_ + c4] = pk;
    }
}

// ---------------------------------------------------------------------------
// MFMA bf16 GEMM: C = A(MxK bf16) @ Wt^T + bias [+res] [+posemb] [relu]
// Wt is N x K bf16 (pre-transposed). 128x128 tile, BK=64, 256 thr (4 waves).
// Double-buffered LDS + XOR swizzle (SWZ64) -> conflict-free ds_read_b128;
// 8 barriers for K=512 (BK=64 halves exposed-latency events vs BK=32).
// z folded into x index; XCD-aware swizzle gives each XCD a contiguous bm
// band so A-slices live in ONE XCD's private L2.
// scatter==1: z in {0,1} -> (B,H,S,DH); z==2 -> V transposed (B,H,DH,S).
// pe != null: val += pe[(row&2047)*N + col]; row with t==0 -> val = pe[col].
// ---------------------------------------------------------------------------
__global__ __launch_bounds__(256, 2) void mfma_gemm(
    const __bf16* __restrict__ A, const __bf16* __restrict__ Wt,
    const float* __restrict__ bias0, const float* __restrict__ bias1,
    const float* __restrict__ bias2,
    const float* res, const float* __restrict__ pe, float* Cf, __bf16* Cb,
    int N, int K, long wtz, long cbz, int relu, int scatter, int nz)
{
    __shared__ __align__(16) __bf16 As[2][128 * 64];
    __shared__ __align__(16) __bf16 Bs[2][128 * 64];
    int tid = threadIdx.x;
    int wave = tid >> 6;
    int lane = tid & 63;

    int nbx = gridDim.x, nby = gridDim.y;
    int bxIdx, bmIdx;
    if ((nby & 7) == 0) {
        int id = blockIdx.y * nbx + blockIdx.x;   // dispatch-linear order
        int chunk = nby >> 3;
        int xcd = id & 7;
        int local = id >> 3;
        int row = local / nbx;
        bmIdx = xcd * chunk + row;
        bxIdx = local - row * nbx;
    } else {
        bxIdx = blockIdx.x; bmIdx = blockIdx.y;
    }
    int z = bxIdx % nz;
    int bn = (bxIdx / nz) * 128;
    int bm = bmIdx * 128;
    const __bf16* Wz = Wt + (size_t)z * wtz;
    const float* bias = (z == 0) ? bias0 : (z == 1 ? bias1 : bias2);

    f32x4 acc[4][4];
    #pragma unroll
    for (int r = 0; r < 4; r++)
        #pragma unroll
        for (int c = 0; c < 4; c++) acc[r][c] = (f32x4){0.f, 0.f, 0.f, 0.f};

    const int wr = (wave >> 1) * 64;
    const int wc = (wave & 1) * 64;
    const int fr = lane & 15;
    const int kqi = lane >> 4;   // 0..3

    // staging: 1024 chunks (16B) per matrix per tile; 4 per thread.
    // physical chunk p holds (row = p>>3, kq = (p&7) ^ (row&7)).
    const __bf16* pA[4];
    const __bf16* pB[4];
    int ldsoff[4];
    #pragma unroll
    for (int u = 0; u < 4; u++) {
        int p = tid + 256 * u;
        int row = p >> 3;
        int kq = (p & 7) ^ (row & 7);
        pA[u] = A  + (size_t)(bm + row) * K + kq * 8;
        pB[u] = Wz + (size_t)(bn + row) * K + kq * 8;
        ldsoff[u] = (u * 256 + wave * 64) * 8;   // wave-contiguous chunk run
    }

    __bf16 *a_cur = As[0], *a_nxt = As[1];
    __bf16 *b_cur = Bs[0], *b_nxt = Bs[1];

    // prefetch tile 0
    #pragma unroll
    for (int u = 0; u < 4; u++) {
        async16(a_cur + ldsoff[u], pA[u]);
        async16(b_cur + ldsoff[u], pB[u]);
    }

    for (int kk = 0; kk < K; kk += 64) {
        __syncthreads();                 // tile kk resident; prior readers of nxt done
        if (kk + 64 < K) {
            #pragma unroll
            for (int u = 0; u < 4; u++) {
                async16(a_nxt + ldsoff[u], pA[u] + kk + 64);
                async16(b_nxt + ldsoff[u], pB[u] + kk + 64);
            }
        }
        #pragma unroll
        for (int ks = 0; ks < 2; ks++) {
            int kq0 = ks * 4 + kqi;
            bf16x8 af[4], bfr[4];
            #pragma unroll
            for (int r = 0; r < 4; r++)
                af[r] = *(const bf16x8*)&a_cur[SWZ64(wr + r * 16 + fr, kq0) * 8];
            #pragma unroll
            for (int c = 0; c < 4; c++)
                bfr[c] = *(const bf16x8*)&b_cur[SWZ64(wc + c * 16 + fr, kq0) * 8];
            #pragma unroll
            for (int r = 0; r < 4; r++)
                #pragma unroll
                for (int c = 0; c < 4; c++)
                    acc[r][c] = __builtin_amdgcn_mfma_f32_16x16x32_bf16(af[r], bfr[c], acc[r][c], 0, 0, 0);
        }
        __bf16* t;
        t = a_cur; a_cur = a_nxt; a_nxt = t;
        t = b_cur; b_cur = b_nxt; b_nxt = t;
    }

    // epilogue: C/D layout col = lane&15, row = (lane>>4)*4 + reg
    int rbase = bm + wr + (lane >> 4) * 4;
    #pragma unroll
    for (int c = 0; c < 4; c++) {
        int cg = bn + wc + c * 16 + fr;
        float bv = bias[cg];
        #pragma unroll
        for (int r = 0; r < 4; r++) {
            int rg0 = rbase + r * 16;   // 4-aligned
            float vals[4];
            #pragma unroll
            for (int i = 0; i < 4; i++) {
                float val = acc[r][c][i] + bv;
                if (relu) val = fmaxf(val, 0.f);
                if (res) val += res[(size_t)(rg0 + i) * N + cg];
                if (pe) {
                    int t = (rg0 + i) & (S_ - 1);
                    val = (t == 0) ? pe[cg] : val + pe[(size_t)t * N + cg];
                }
                vals[i] = val;
            }
            if (Cf) {
                #pragma unroll
                for (int i = 0; i < 4; i++) Cf[(size_t)(rg0 + i) * N + cg] = vals[i];
            }
            if (Cb) {
                if (scatter) {
                    int bb = rg0 >> 11;
                    int s0 = rg0 & (S_ - 1);
                    int hh = cg >> 6, dh = cg & 63;
                    if (z == 2) {
                        bf16x4 pk;
                        #pragma unroll
                        for (int i = 0; i < 4; i++) pk[i] = (__bf16)vals[i];
                        *(bf16x4*)(Cb + (size_t)z * cbz +
                                   ((((size_t)bb * H_ + hh) * DH_ + dh) * S_) + s0) = pk;
                    } else {
                        #pragma unroll
                        for (int i = 0; i < 4; i++)
                            (Cb + (size_t)z * cbz)[((((size_t)bb * H_ + hh) * S_ + s0 + i) * DH_) + dh] = (__bf16)vals[i];
                    }
                } else {
                    #pragma unroll
                    for (int i = 0; i < 4; i++) Cb[(size_t)(rg0 + i) * N + cg] = (__bf16)vals[i];
                }
            }
        }
    }
}

// ---------------------------------------------------------------------------
// MFMA block-sparse attention. One workgroup (4 waves) per (b,h,n); each wave
// owns 16 q-rows. XCD affinity: all 32 n-blocks of one (b,h) map to the same
// XCD (bid&7) so the (b,h) K/V planes (512 KB) stay in one private L2.
// ---------------------------------------------------------------------------
#define KSTR 72
__global__ __launch_bounds__(256, 4) void attn_kernel(
    const __bf16* __restrict__ q, const __bf16* __restrict__ k,
    const __bf16* __restrict__ vt, const int* __restrict__ rb,
    __bf16* __restrict__ o)
{
    __shared__ __align__(16) __bf16 Ks[64 * KSTR];
    __shared__ __align__(16) __bf16 Vs[64 * KSTR];
    __shared__ __align__(16) __bf16 Ps[64 * KSTR];
    int bid = blockIdx.x;                 // 2048
    int xcd = bid & 7;
    int local = bid >> 3;                 // 0..255
    int bh = (local >> 5) * 8 + xcd;      // 0..63, fixed per XCD
    int n = local & 31;
    int b = bh >> 3;
    int hh = bh & 7;
    int tid = threadIdx.x;
    int wave = tid >> 6;
    int lane = tid & 63;
    const int fr = lane & 15;
    const int fq = lane >> 4;

    int idx[6];
    idx[0] = 0;
    idx[1] = n > 0 ? n - 1 : 0;
    idx[2] = n;
    idx[3] = n < NB_ - 1 ? n + 1 : NB_ - 1;
    idx[4] = rb[n * 2 + 0];
    idx[5] = rb[n * 2 + 1];

    const size_t plane = ((size_t)b * H_ + hh) * S_;           // q,k row base
    const __bf16* vtb = vt + plane * DH_;                      // (B,H,DH,S) plane

    // Q fragments (B-operand): row m = wave*16 + fr, k = fq*8 (+32)
    const __bf16* qrow = q + (plane + (size_t)n * BS_ + wave * 16 + fr) * DH_ + fq * 8;
    bf16x8 qf0 = *(const bf16x8*)qrow;
    bf16x8 qf1 = *(const bf16x8*)(qrow + 32);

    f32x4 oacc[4];
    #pragma unroll
    for (int dt = 0; dt < 4; dt++) oacc[dt] = (f32x4){0.f, 0.f, 0.f, 0.f};
    float mrow = -1e30f, lrow = 0.f;

    for (int c = 0; c < 6; c++) {
        bool dup = false;
        #pragma unroll
        for (int j = 0; j < 6; j++) if (j < c && idx[j] == idx[c]) dup = true;
        if (dup) continue;   // uniform across workgroup

        __syncthreads();     // prior iteration's reads of Ks/Vs complete
        // ---- stage K (n-major) and V^T (d-major), 512 16B chunks each ----
        {
            const __bf16* kb = k + (plane + (size_t)idx[c] * BS_) * DH_;
            const __bf16* vb = vtb + (size_t)idx[c] * BS_;
            #pragma unroll
            for (int u = 0; u < 2; u++) {
                int ch = tid + u * 256;
                int row = ch >> 3, d0 = (ch & 7) * 8;
                *(bf16x8*)&Ks[row * KSTR + d0] = *(const bf16x8*)(kb + row * DH_ + d0);
                *(bf16x8*)&Vs[row * KSTR + d0] = *(const bf16x8*)(vb + (size_t)row * S_ + d0);
            }
        }
        __syncthreads();

        // ---- S^T = K·Q^T : rows = keys, cols = q ----
        f32x4 st[4];
        #pragma unroll
        for (int t = 0; t < 4; t++) {
            bf16x8 ka0 = *(const bf16x8*)&Ks[(t * 16 + fr) * KSTR + fq * 8];
            bf16x8 ka1 = *(const bf16x8*)&Ks[(t * 16 + fr) * KSTR + 32 + fq * 8];
            st[t] = __builtin_amdgcn_mfma_f32_16x16x32_bf16(ka0, qf0, (f32x4){0.f,0.f,0.f,0.f}, 0, 0, 0);
            st[t] = __builtin_amdgcn_mfma_f32_16x16x32_bf16(ka1, qf1, st[t], 0, 0, 0);
        }
        // element (n_loc = t*16 + fq*4 + i, m = fr); scale then row stats over n
        float rmax = -1e30f;
        #pragma unroll
        for (int t = 0; t < 4; t++)
            #pragma unroll
            for (int i = 0; i < 4; i++) {
                st[t][i] *= 0.125f;
                rmax = fmaxf(rmax, st[t][i]);
            }
        rmax = fmaxf(rmax, __shfl_xor(rmax, 16));
        rmax = fmaxf(rmax, __shfl_xor(rmax, 32));
        float newm = fmaxf(mrow, rmax);
        float corr = __expf(mrow - newm);
        mrow = newm;
        float psum = 0.f;
        #pragma unroll
        for (int t = 0; t < 4; t++) {
            bf16x4 pk;
            #pragma unroll
            for (int i = 0; i < 4; i++) {
                float p = __expf(st[t][i] - newm);
                psum += p;
                pk[i] = (__bf16)p;
            }
            *(bf16x4*)&Ps[(wave * 16 + fr) * KSTR + t * 16 + fq * 4] = pk;
        }
        psum += __shfl_xor(psum, 16);
        psum += __shfl_xor(psum, 32);
        lrow = lrow * corr + psum;

        // ---- rescale O (rows in C layout: m_loc = fq*4 + i) ----
        #pragma unroll
        for (int i = 0; i < 4; i++) {
            float ci = __shfl(corr, fq * 4 + i);
            #pragma unroll
            for (int dt = 0; dt < 4; dt++) oacc[dt][i] *= ci;
        }

        // ---- O += P·V : A = P (m-major), B = V^T (d-major) ----
        bf16x8 pa0 = *(const bf16x8*)&Ps[(wave * 16 + fr) * KSTR + fq * 8];
        bf16x8 pa1 = *(const bf16x8*)&Ps[(wave * 16 + fr) * KSTR + 32 + fq * 8];
        #pragma unroll
        for (int dt = 0; dt < 4; dt++) {
            bf16x8 vb0 = *(const bf16x8*)&Vs[(dt * 16 + fr) * KSTR + fq * 8];
            bf16x8 vb1 = *(const bf16x8*)&Vs[(dt * 16 + fr) * KSTR + 32 + fq * 8];
            oacc[dt] = __builtin_amdgcn_mfma_f32_16x16x32_bf16(pa0, vb0, oacc[dt], 0, 0, 0);
            oacc[dt] = __builtin_amdgcn_mfma_f32_16x16x32_bf16(pa1, vb1, oacc[dt], 0, 0, 0);
        }
    }

    // ---- epilogue: normalize rows, write (B,S,D) bf16 ----
    float linv = 1.f / lrow;
    #pragma unroll
    for (int i = 0; i < 4; i++) {
        float li = __shfl(linv, fq * 4 + i);
        int s = n * BS_ + wave * 16 + fq * 4 + i;
        __bf16* op = o + ((size_t)b * S_ + s) * D_ + hh * DH_ + fr;
        #pragma unroll
        for (int dt = 0; dt < 4; dt++)
            op[dt * 16] = (__bf16)(oacc[dt][i] * li);
    }
}

// ---------------------------------------------------------------------------
// Row LayerNorm: fp32 in -> fp32 out + bf16 out. 256 thr = 4 rows/block.
// ---------------------------------------------------------------------------
__global__ __launch_bounds__(256) void ln_kernel(
    const float* in, float* outp, __bf16* outb,
    const float* __restrict__ g, const float* __restrict__ bb)
{
    size_t r = (size_t)blockIdx.x * 4 + (threadIdx.x >> 6);
    int t = threadIdx.x & 63;
    const float4* ip = (const float4*)(in + r * D_);
    float4 x0 = ip[2 * t], x1 = ip[2 * t + 1];
    float s = x0.x + x0.y + x0.z + x0.w + x1.x + x1.y + x1.z + x1.w;
    #pragma unroll
    for (int off = 32; off; off >>= 1) s += __shfl_xor(s, off, 64);
    float mean = s * (1.0f / D_);
    float d0 = x0.x - mean, d1 = x0.y - mean, d2 = x0.z - mean, d3 = x0.w - mean;
    float d4 = x1.x - mean, d5 = x1.y - mean, d6 = x1.z - mean, d7 = x1.w - mean;
    float ss = d0*d0 + d1*d1 + d2*d2 + d3*d3 + d4*d4 + d5*d5 + d6*d6 + d7*d7;
    #pragma unroll
    for (int off = 32; off; off >>= 1) ss += __shfl_xor(ss, off, 64);
    float rs = rsqrtf(ss * (1.0f / D_) + 1e-5f);
    float4 g0 = ((const float4*)g)[2 * t], g1 = ((const float4*)g)[2 * t + 1];
    float4 b0 = ((const float4*)bb)[2 * t], b1 = ((const float4*)bb)[2 * t + 1];
    float y[8];
    y[0] = d0 * rs * g0.x + b0.x; y[1] = d1 * rs * g0.y + b0.y;
    y[2] = d2 * rs * g0.z + b0.z; y[3] = d3 * rs * g0.w + b0.w;
    y[4] = d4 * rs * g1.x + b1.x; y[5] = d5 * rs * g1.y + b1.y;
    y[6] = d6 * rs * g1.z + b1.z; y[7] = d7 * rs * g1.w + b1.w;
    float4* op = (float4*)(outp + r * D_);
    op[2 * t]     = (float4){y[0], y[1], y[2], y[3]};
    op[2 * t + 1] = (float4){y[4], y[5], y[6], y[7]};
    bf16x8 hb;
    #pragma unroll
    for (int j = 0; j < 8; j++) hb[j] = (__bf16)y[j];
    *(bf16x8*)(outb + r * D_ + t * 8) = hb;
}

// ---------------------------------------------------------------------------
// Head stage 1: grid (8,4). Block (b,jg): columns j = jg*256 + tid of
// dense = relu(h[b,0,:] @ w_dense + b_dense); partial sums of dense@w_out.
// ---------------------------------------------------------------------------
__global__ __launch_bounds__(256) void head1_kernel(
    const float* __restrict__ h, const float* __restrict__ wd,
    const float* __restrict__ bd, const float* __restrict__ wo,
    float* __restrict__ partial)
{
    __shared__ float hrow[D_];
    __shared__ float red[8];
    int b = blockIdx.x, jg = blockIdx.y;
    int tid = threadIdx.x;
    if (tid < 128) ((float4*)hrow)[tid] = ((const float4*)(h + (size_t)b * S_ * D_))[tid];
    __syncthreads();
    int j = jg * 256 + tid;
    float acc = bd[j];
    #pragma unroll 8
    for (int i = 0; i < D_; i++) acc = fmaf(hrow[i], wd[(size_t)i * 1024 + j], acc);
    float dns = fmaxf(acc, 0.f);
    float2 w2 = ((const float2*)wo)[j];
    float p0 = dns * w2.x, p1 = dns * w2.y;
    #pragma unroll
    for (int off = 32; off; off >>= 1) { p0 += __shfl_xor(p0, off, 64); p1 += __shfl_xor(p1, off, 64); }
    int wid = tid >> 6;
    if ((tid & 63) == 0) { red[wid * 2] = p0; red[wid * 2 + 1] = p1; }
    __syncthreads();
    if (tid == 0) {
        float t0 = red[0] + red[2] + red[4] + red[6];
        float t1 = red[1] + red[3] + red[5] + red[7];
        partial[((size_t)b * 4 + jg) * 2 + 0] = t0;
        partial[((size_t)b * 4 + jg) * 2 + 1] = t1;
    }
}

// Head stage 2: 16 threads, one block.
__global__ __launch_bounds__(64) void head2_kernel(
    const float* __restrict__ partial, const float* __restrict__ bo,
    float* __restrict__ out)
{
    int tid = threadIdx.x;
    if (tid < 16) {
        int b = tid >> 1, c = tid & 1;
        float s = bo[c];
        #pragma unroll
        for (int jg = 0; jg < 4; jg++) s += partial[((size_t)b * 4 + jg) * 2 + c];
        out[b * 2 + c] = tanhf(s);
    }
}

// ---------------------------------------------------------------------------
extern "C" void kernel_launch(void* const* d_in, const int* in_sizes, int n_in,
                              void* d_out, int out_size, void* d_ws, size_t ws_size,
                              hipStream_t stream) {
    (void)in_sizes; (void)n_in; (void)out_size; (void)ws_size;
    const float* x       = (const float*)d_in[0];
    const float* w_embed = (const float*)d_in[1];
    const float* b_embed = (const float*)d_in[2];
    const float* pos_emb = (const float*)d_in[3];
    const float* Wq      = (const float*)d_in[4];
    const float* bq      = (const float*)d_in[5];
    const float* Wk      = (const float*)d_in[6];
    const float* bk      = (const float*)d_in[7];
    const float* Wv      = (const float*)d_in[8];
    const float* bv      = (const float*)d_in[9];
    const float* Wo      = (const float*)d_in[10];
    const float* bo      = (const float*)d_in[11];
    const float* ln1_g   = (const float*)d_in[12];
    const float* ln1_b   = (const float*)d_in[13];
    const float* W1      = (const float*)d_in[14];
    const float* b1      = (const float*)d_in[15];
    const float* W2      = (const float*)d_in[16];
    const float* b2      = (const float*)d_in[17];
    const float* ln2_g   = (const float*)d_in[18];
    const float* ln2_b   = (const float*)d_in[19];
    const float* w_dense = (const float*)d_in[20];
    const float* b_dense = (const float*)d_in[21];
    const float* w_out   = (const float*)d_in[22];
    const float* b_out   = (const float*)d_in[23];
    const int*   rb      = (const int*)d_in[24];
    float* out = (float*)d_out;

    // Workspace layout (total ~141 MiB):
    //  h fp32 (32M) | h_bf (16M) | big bf16 region 64M: qkv(48M)+o(16M) == ff1
    //  (embed phase reuses big: xr @ +0 (4MB), wt_e @ +28M elems) | wt @ 112MiB
    //  head partials @ 140 MiB
    const size_t PLANE = (size_t)B_ * H_ * S_ * DH_;  // 8,388,608
    float*  h    = (float*)d_ws;
    __bf16* h_bf = (__bf16*)(h + (size_t)MTOK * D_);
    __bf16* big  = (__bf16*)((char*)d_ws + (size_t)48 * 1024 * 1024);
    __bf16* qkv  = big;
    __bf16* o_bf = big + 3 * PLANE;
    __bf16* ff1  = big;                                // alias, lifetime-disjoint
    __bf16* xr   = big;                                // embed-phase only
    __bf16* wt_e = big + (size_t)28 * 1024 * 1024;     // embed-phase only (512*128)
    __bf16* wt   = (__bf16*)((char*)d_ws + (size_t)112 * 1024 * 1024);
    __bf16* wt_qkv = wt;                               // 3*L*D*D
    __bf16* wt_o   = wt_qkv + (size_t)3 * L_ * DD_;    // L*D*D
    __bf16* wt_1   = wt_o + (size_t)L_ * DD_;          // L*D*FF
    __bf16* wt_2   = wt_1 + (size_t)L_ * D_ * FF_;     // L*FF*D
    float*  hpart  = (float*)((char*)d_ws + (size_t)140 * 1024 * 1024);  // 64 floats

    dim3 tb(32, 8);
    wconv_qkvo<<<dim3(16, 16, 16), tb, 0, stream>>>(Wq, Wk, Wv, Wo, wt_qkv, wt_o);
    wconv_kernel<<<dim3(64, 16, L_), tb, 0, stream>>>(W1, wt_1, D_, FF_, D_);
    wconv_kernel<<<dim3(16, 64, L_), tb, 0, stream>>>(W2, wt_2, FF_, D_, FF_);
    wconv_kernel<<<dim3(16, 4, 1),  tb, 0, stream>>>(w_embed, wt_e, 80, D_, KE_);

    // Embed = MFMA GEMM: h = xr @ wt_e^T + b_embed + pos_emb (cls row -> pe[0])
    xbuild_kernel<<<MTOK / 64, 256, 0, stream>>>(x, xr);
    mfma_gemm<<<dim3(D_ / 128, MTOK / 128, 1), 256, 0, stream>>>(
        xr, wt_e, b_embed, b_embed, b_embed,
        nullptr, pos_emb, h, h_bf, D_, KE_, 0, 0, 0, 0, 1);

    for (int l = 0; l < L_; l++) {
        // QKV (z folded into x for A-slice reuse; XCD swizzle in-kernel)
        mfma_gemm<<<dim3((D_ / 128) * 3, MTOK / 128, 1), 256, 0, stream>>>(
            h_bf, wt_qkv + (size_t)l * DD_, bq + l * D_, bk + l * D_, bv + l * D_,
            nullptr, nullptr, nullptr, qkv, D_, D_, (long)L_ * DD_, (long)PLANE, 0, 1, 3);

        attn_kernel<<<B_ * H_ * NB_, 256, 0, stream>>>(qkv, qkv + PLANE, qkv + 2 * PLANE, rb, o_bf);

        // h = h + o @ Wo + bo
        mfma_gemm<<<dim3(D_ / 128, MTOK / 128, 1), 256, 0, stream>>>(
            o_bf, wt_o + (size_t)l * DD_, bo + l * D_, bo + l * D_, bo + l * D_,
            h, nullptr, h, nullptr, D_, D_, 0, 0, 0, 0, 1);
        ln_kernel<<<MTOK / 4, 256, 0, stream>>>(h, h, h_bf, ln1_g + l * D_, ln1_b + l * D_);

        // ff1 = relu(h @ W1 + b1), bf16 out
        mfma_gemm<<<dim3(FF_ / 128, MTOK / 128, 1), 256, 0, stream>>>(
            h_bf, wt_1 + (size_t)l * D_ * FF_, b1 + l * FF_, b1 + l * FF_, b1 + l * FF_,
            nullptr, nullptr, nullptr, ff1, FF_, D_, 0, 0, 1, 0, 1);

        // h = h + ff1 @ W2 + b2
        mfma_gemm<<<dim3(D_ / 128, MTOK / 128, 1), 256, 0, stream>>>(
            ff1, wt_2 + (size_t)l * FF_ * D_, b2 + l * D_, b2 + l * D_, b2 + l * D_,
            h, nullptr, h, nullptr, D_, FF_, 0, 0, 0, 0, 1);
        ln_kernel<<<MTOK / 4, 256, 0, stream>>>(h, h, h_bf, ln2_g + l * D_, ln2_b + l * D_);
    }

    head1_kernel<<<dim3(B_, 4), 256, 0, stream>>>(h, w_dense, b_dense, w_out, hpart);
    head2_kernel<<<1, 64, 0, stream>>>(hpart, b_out, out);
}

// Round 12
// 1149.450 us; speedup vs baseline: 7.7781x; 1.0303x over previous
//
#include <hip/hip_runtime.h>
#include <cstdint>
#include <cstddef>

// Problem constants
#define B_   8
#define NM_  10
#define T_   16376
#define D_   512
#define H_   8
#define DH_  64
#define L_   4
#define S_   2048
#define NB_  32
#define BS_  64
#define FF_  2048
#define MTOK (B_*S_)   // 16384 token rows
#define DD_  (D_*D_)
#define KE_  128       // embed K padded (80 -> 128, divisible by BK=64)

typedef __attribute__((ext_vector_type(8))) __bf16 bf16x8;
typedef __attribute__((ext_vector_type(4))) __bf16 bf16x4;
typedef __attribute__((ext_vector_type(4))) float f32x4;

__device__ __forceinline__ void async16(void* lds, const void* g) {
    __builtin_amdgcn_global_load_lds(
        (const __attribute__((address_space(1))) void*)g,
        (__attribute__((address_space(3))) void*)lds, 16, 0, 0);
}

// XOR-swizzled 16B-chunk index for a 128row x 64el bf16 tile (8 chunks/row).
#define SWZ64(row, kq) (((row) << 3) + ((kq) ^ ((row) & 7)))

// ---------------------------------------------------------------------------
// Weight transpose+convert: in (K x N fp32) -> out (N x Kp bf16), zero-pad
// k in [K, Kp). Grid: (N/32, Kp/32, Z) with z-strided in/out.
// ---------------------------------------------------------------------------
__global__ __launch_bounds__(256) void wconv_kernel(
    const float* __restrict__ in, __bf16* __restrict__ outp, int K, int N, int Kp)
{
    __shared__ float t[32][33];
    const float* ip = in + (size_t)blockIdx.z * K * N;
    __bf16* op = outp + (size_t)blockIdx.z * N * Kp;
    int n0 = blockIdx.x * 32, k0 = blockIdx.y * 32;
    int tx = threadIdx.x, ty = threadIdx.y;   // 32 x 8
    #pragma unroll
    for (int j = 0; j < 4; j++) {
        int k = k0 + ty + 8 * j;
        t[ty + 8 * j][tx] = (k < K) ? ip[(size_t)k * N + n0 + tx] : 0.f;
    }
    __syncthreads();
    #pragma unroll
    for (int j = 0; j < 4; j++)
        op[(size_t)(n0 + ty + 8 * j) * Kp + k0 + tx] = (__bf16)t[tx][ty + 8 * j];
}

// Merged Wq/Wk/Wv/Wo transpose (all D_ x D_). Grid (16,16,16): z = mat*4+layer.
__global__ __launch_bounds__(256) void wconv_qkvo(
    const float* __restrict__ wq, const float* __restrict__ wk,
    const float* __restrict__ wv, const float* __restrict__ wo,
    __bf16* __restrict__ wtqkv, __bf16* __restrict__ wto)
{
    __shared__ float t[32][33];
    int zz = blockIdx.z;
    int mat = zz >> 2, layer = zz & 3;
    const float* src = (mat == 0 ? wq : mat == 1 ? wk : mat == 2 ? wv : wo)
                       + (size_t)layer * DD_;
    __bf16* dst = (mat < 3) ? wtqkv + ((size_t)mat * L_ + layer) * DD_
                            : wto + (size_t)layer * DD_;
    int n0 = blockIdx.x * 32, k0 = blockIdx.y * 32;
    int tx = threadIdx.x, ty = threadIdx.y;   // 32 x 8
    #pragma unroll
    for (int j = 0; j < 4; j++)
        t[ty + 8 * j][tx] = src[(size_t)(k0 + ty + 8 * j) * D_ + n0 + tx];
    __syncthreads();
    #pragma unroll
    for (int j = 0; j < 4; j++)
        dst[(size_t)(n0 + ty + 8 * j) * D_ + k0 + tx] = (__bf16)t[tx][ty + 8 * j];
}

// ---------------------------------------------------------------------------
// Build xr (MTOK x KE_ bf16): xr[b*2048+t][m] = x[b, m/8, (m%8)*2047 + t-1]
// for t>=1, m<80; else 0. One block per 64 rows (same b).
// ---------------------------------------------------------------------------
__global__ __launch_bounds__(256) void xbuild_kernel(
    const float* __restrict__ x, __bf16* __restrict__ xr)
{
    __shared__ float xs[64][KE_ + 1];
    int row0 = blockIdx.x * 64;
    int b = row0 >> 11;
    int t0 = row0 & (S_ - 1);
    int tid = threadIdx.x;
    int lane = tid & 63;
    int mq = tid >> 6;          // 0..3
    for (int mb = 0; mb < 32; mb++) {
        int m = mb * 4 + mq;    // 0..127
        int t = t0 + lane;
        float v = 0.f;
        if (m < 80 && t > 0)
            v = x[(size_t)b * NM_ * T_ + (size_t)(m >> 3) * T_ + (m & 7) * 2047 + (t - 1)];
        xs[lane][m] = v;
    }
    __syncthreads();
    #pragma unroll
    for (int u = 0; u < 8; u++) {
        int ch = tid + u * 256;          // 0..2047
        int row = ch >> 5, c4 = (ch & 31) * 4;
        bf16x4 pk;
        #pragma unroll
        for (int i = 0; i < 4; i++) pk[i] = (__bf16)xs[row][c4 + i];
        *(bf16x4*)&xr[(size_t)(row0 + row) * KE_ + c4] = pk;
    }
}

// ---------------------------------------------------------------------------
// MFMA bf16 GEMM: C = A(MxK bf16) @ Wt^T + bias [+pe] [relu]
// Wt is N x K bf16 (pre-transposed). 128x128 tile, BK=64, 256 thr (4 waves).
// Double-buffered LDS + XOR swizzle (conflict-free ds_read_b128).
// z folded into x; XCD-aware swizzle: each XCD owns a contiguous bm band.
// Outputs: Cf fp32 (optional) and/or Cb bf16 (optional). No residual read —
// residual adds live in ln_add_kernel (fp32 accumulator).
// scatter==1: z in {0,1} -> (B,H,S,DH); z==2 -> V transposed (B,H,DH,S).
// pe != null: val += pe[(row&2047)*N + col]; row with t==0 -> val = pe[col].
// ---------------------------------------------------------------------------
__global__ __launch_bounds__(256, 2) void mfma_gemm(
    const __bf16* __restrict__ A, const __bf16* __restrict__ Wt,
    const float* __restrict__ bias0, const float* __restrict__ bias1,
    const float* __restrict__ bias2,
    const float* __restrict__ pe, float* __restrict__ Cf, __bf16* __restrict__ Cb,
    int N, int K, long wtz, long cbz, int relu, int scatter, int nz)
{
    __shared__ __align__(16) __bf16 As[2][128 * 64];
    __shared__ __align__(16) __bf16 Bs[2][128 * 64];
    int tid = threadIdx.x;
    int wave = tid >> 6;
    int lane = tid & 63;

    int nbx = gridDim.x, nby = gridDim.y;
    int bxIdx, bmIdx;
    if ((nby & 7) == 0) {
        int id = blockIdx.y * nbx + blockIdx.x;   // dispatch-linear order
        int chunk = nby >> 3;
        int xcd = id & 7;
        int local = id >> 3;
        int row = local / nbx;
        bmIdx = xcd * chunk + row;
        bxIdx = local - row * nbx;
    } else {
        bxIdx = blockIdx.x; bmIdx = blockIdx.y;
    }
    int z = bxIdx % nz;
    int bn = (bxIdx / nz) * 128;
    int bm = bmIdx * 128;
    const __bf16* Wz = Wt + (size_t)z * wtz;
    const float* bias = (z == 0) ? bias0 : (z == 1 ? bias1 : bias2);

    f32x4 acc[4][4];
    #pragma unroll
    for (int r = 0; r < 4; r++)
        #pragma unroll
        for (int c = 0; c < 4; c++) acc[r][c] = (f32x4){0.f, 0.f, 0.f, 0.f};

    const int wr = (wave >> 1) * 64;
    const int wc = (wave & 1) * 64;
    const int fr = lane & 15;
    const int kqi = lane >> 4;   // 0..3

    const __bf16* pA[4];
    const __bf16* pB[4];
    int ldsoff[4];
    #pragma unroll
    for (int u = 0; u < 4; u++) {
        int p = tid + 256 * u;
        int row = p >> 3;
        int kq = (p & 7) ^ (row & 7);
        pA[u] = A  + (size_t)(bm + row) * K + kq * 8;
        pB[u] = Wz + (size_t)(bn + row) * K + kq * 8;
        ldsoff[u] = (u * 256 + wave * 64) * 8;
    }

    __bf16 *a_cur = As[0], *a_nxt = As[1];
    __bf16 *b_cur = Bs[0], *b_nxt = Bs[1];

    #pragma unroll
    for (int u = 0; u < 4; u++) {
        async16(a_cur + ldsoff[u], pA[u]);
        async16(b_cur + ldsoff[u], pB[u]);
    }

    for (int kk = 0; kk < K; kk += 64) {
        __syncthreads();
        if (kk + 64 < K) {
            #pragma unroll
            for (int u = 0; u < 4; u++) {
                async16(a_nxt + ldsoff[u], pA[u] + kk + 64);
                async16(b_nxt + ldsoff[u], pB[u] + kk + 64);
            }
        }
        #pragma unroll
        for (int ks = 0; ks < 2; ks++) {
            int kq0 = ks * 4 + kqi;
            bf16x8 af[4], bfr[4];
            #pragma unroll
            for (int r = 0; r < 4; r++)
                af[r] = *(const bf16x8*)&a_cur[SWZ64(wr + r * 16 + fr, kq0) * 8];
            #pragma unroll
            for (int c = 0; c < 4; c++)
                bfr[c] = *(const bf16x8*)&b_cur[SWZ64(wc + c * 16 + fr, kq0) * 8];
            #pragma unroll
            for (int r = 0; r < 4; r++)
                #pragma unroll
                for (int c = 0; c < 4; c++)
                    acc[r][c] = __builtin_amdgcn_mfma_f32_16x16x32_bf16(af[r], bfr[c], acc[r][c], 0, 0, 0);
        }
        __bf16* t;
        t = a_cur; a_cur = a_nxt; a_nxt = t;
        t = b_cur; b_cur = b_nxt; b_nxt = t;
    }

    // epilogue: C/D layout col = lane&15, row = (lane>>4)*4 + reg
    int rbase = bm + wr + (lane >> 4) * 4;
    #pragma unroll
    for (int c = 0; c < 4; c++) {
        int cg = bn + wc + c * 16 + fr;
        float bv = bias[cg];
        #pragma unroll
        for (int r = 0; r < 4; r++) {
            int rg0 = rbase + r * 16;   // 4-aligned
            float vals[4];
            #pragma unroll
            for (int i = 0; i < 4; i++) {
                float val = acc[r][c][i] + bv;
                if (relu) val = fmaxf(val, 0.f);
                if (pe) {
                    int t = (rg0 + i) & (S_ - 1);
                    val = (t == 0) ? pe[cg] : val + pe[(size_t)t * N + cg];
                }
                vals[i] = val;
            }
            if (Cf) {
                #pragma unroll
                for (int i = 0; i < 4; i++) Cf[(size_t)(rg0 + i) * N + cg] = vals[i];
            }
            if (Cb) {
                if (scatter) {
                    int bb = rg0 >> 11;
                    int s0 = rg0 & (S_ - 1);
                    int hh = cg >> 6, dh = cg & 63;
                    if (z == 2) {
                        bf16x4 pk;
                        #pragma unroll
                        for (int i = 0; i < 4; i++) pk[i] = (__bf16)vals[i];
                        *(bf16x4*)(Cb + (size_t)z * cbz +
                                   ((((size_t)bb * H_ + hh) * DH_ + dh) * S_) + s0) = pk;
                    } else {
                        #pragma unroll
                        for (int i = 0; i < 4; i++)
                            (Cb + (size_t)z * cbz)[((((size_t)bb * H_ + hh) * S_ + s0 + i) * DH_) + dh] = (__bf16)vals[i];
                    }
                } else {
                    #pragma unroll
                    for (int i = 0; i < 4; i++) Cb[(size_t)(rg0 + i) * N + cg] = (__bf16)vals[i];
                }
            }
        }
    }
}

// ---------------------------------------------------------------------------
// MFMA block-sparse attention. One workgroup (4 waves) per (b,h,n); each wave
// owns 16 q-rows. XCD affinity: all 32 n-blocks of one (b,h) on one XCD.
// ---------------------------------------------------------------------------
#define KSTR 72
__global__ __launch_bounds__(256, 4) void attn_kernel(
    const __bf16* __restrict__ q, const __bf16* __restrict__ k,
    const __bf16* __restrict__ vt, const int* __restrict__ rb,
    __bf16* __restrict__ o)
{
    __shared__ __align__(16) __bf16 Ks[64 * KSTR];
    __shared__ __align__(16) __bf16 Vs[64 * KSTR];
    __shared__ __align__(16) __bf16 Ps[64 * KSTR];
    int bid = blockIdx.x;                 // 2048
    int xcd = bid & 7;
    int local = bid >> 3;                 // 0..255
    int bh = (local >> 5) * 8 + xcd;      // 0..63, fixed per XCD
    int n = local & 31;
    int b = bh >> 3;
    int hh = bh & 7;
    int tid = threadIdx.x;
    int wave = tid >> 6;
    int lane = tid & 63;
    const int fr = lane & 15;
    const int fq = lane >> 4;

    int idx[6];
    idx[0] = 0;
    idx[1] = n > 0 ? n - 1 : 0;
    idx[2] = n;
    idx[3] = n < NB_ - 1 ? n + 1 : NB_ - 1;
    idx[4] = rb[n * 2 + 0];
    idx[5] = rb[n * 2 + 1];

    const size_t plane = ((size_t)b * H_ + hh) * S_;
    const __bf16* vtb = vt + plane * DH_;

    const __bf16* qrow = q + (plane + (size_t)n * BS_ + wave * 16 + fr) * DH_ + fq * 8;
    bf16x8 qf0 = *(const bf16x8*)qrow;
    bf16x8 qf1 = *(const bf16x8*)(qrow + 32);

    f32x4 oacc[4];
    #pragma unroll
    for (int dt = 0; dt < 4; dt++) oacc[dt] = (f32x4){0.f, 0.f, 0.f, 0.f};
    float mrow = -1e30f, lrow = 0.f;

    for (int c = 0; c < 6; c++) {
        bool dup = false;
        #pragma unroll
        for (int j = 0; j < 6; j++) if (j < c && idx[j] == idx[c]) dup = true;
        if (dup) continue;   // uniform across workgroup

        __syncthreads();
        {
            const __bf16* kb = k + (plane + (size_t)idx[c] * BS_) * DH_;
            const __bf16* vb = vtb + (size_t)idx[c] * BS_;
            #pragma unroll
            for (int u = 0; u < 2; u++) {
                int ch = tid + u * 256;
                int row = ch >> 3, d0 = (ch & 7) * 8;
                *(bf16x8*)&Ks[row * KSTR + d0] = *(const bf16x8*)(kb + row * DH_ + d0);
                *(bf16x8*)&Vs[row * KSTR + d0] = *(const bf16x8*)(vb + (size_t)row * S_ + d0);
            }
        }
        __syncthreads();

        // ---- S^T = K·Q^T ----
        f32x4 st[4];
        #pragma unroll
        for (int t = 0; t < 4; t++) {
            bf16x8 ka0 = *(const bf16x8*)&Ks[(t * 16 + fr) * KSTR + fq * 8];
            bf16x8 ka1 = *(const bf16x8*)&Ks[(t * 16 + fr) * KSTR + 32 + fq * 8];
            st[t] = __builtin_amdgcn_mfma_f32_16x16x32_bf16(ka0, qf0, (f32x4){0.f,0.f,0.f,0.f}, 0, 0, 0);
            st[t] = __builtin_amdgcn_mfma_f32_16x16x32_bf16(ka1, qf1, st[t], 0, 0, 0);
        }
        float rmax = -1e30f;
        #pragma unroll
        for (int t = 0; t < 4; t++)
            #pragma unroll
            for (int i = 0; i < 4; i++) {
                st[t][i] *= 0.125f;
                rmax = fmaxf(rmax, st[t][i]);
            }
        rmax = fmaxf(rmax, __shfl_xor(rmax, 16));
        rmax = fmaxf(rmax, __shfl_xor(rmax, 32));
        float newm = fmaxf(mrow, rmax);
        float corr = __expf(mrow - newm);
        mrow = newm;
        float psum = 0.f;
        #pragma unroll
        for (int t = 0; t < 4; t++) {
            bf16x4 pk;
            #pragma unroll
            for (int i = 0; i < 4; i++) {
                float p = __expf(st[t][i] - newm);
                psum += p;
                pk[i] = (__bf16)p;
            }
            *(bf16x4*)&Ps[(wave * 16 + fr) * KSTR + t * 16 + fq * 4] = pk;
        }
        psum += __shfl_xor(psum, 16);
        psum += __shfl_xor(psum, 32);
        lrow = lrow * corr + psum;

        #pragma unroll
        for (int i = 0; i < 4; i++) {
            float ci = __shfl(corr, fq * 4 + i);
            #pragma unroll
            for (int dt = 0; dt < 4; dt++) oacc[dt][i] *= ci;
        }

        bf16x8 pa0 = *(const bf16x8*)&Ps[(wave * 16 + fr) * KSTR + fq * 8];
        bf16x8 pa1 = *(const bf16x8*)&Ps[(wave * 16 + fr) * KSTR + 32 + fq * 8];
        #pragma unroll
        for (int dt = 0; dt < 4; dt++) {
            bf16x8 vb0 = *(const bf16x8*)&Vs[(dt * 16 + fr) * KSTR + fq * 8];
            bf16x8 vb1 = *(const bf16x8*)&Vs[(dt * 16 + fr) * KSTR + 32 + fq * 8];
            oacc[dt] = __builtin_amdgcn_mfma_f32_16x16x32_bf16(pa0, vb0, oacc[dt], 0, 0, 0);
            oacc[dt] = __builtin_amdgcn_mfma_f32_16x16x32_bf16(pa1, vb1, oacc[dt], 0, 0, 0);
        }
    }

    float linv = 1.f / lrow;
    #pragma unroll
    for (int i = 0; i < 4; i++) {
        float li = __shfl(linv, fq * 4 + i);
        int s = n * BS_ + wave * 16 + fq * 4 + i;
        __bf16* op = o + ((size_t)b * S_ + s) * D_ + hh * DH_ + fr;
        #pragma unroll
        for (int dt = 0; dt < 4; dt++)
            op[dt * 16] = (__bf16)(oacc[dt][i] * li);
    }
}

// ---------------------------------------------------------------------------
// Fused residual-add + LayerNorm: h(fp32) += delta(bf16); LN; write h fp32
// and h_bf bf16. Stats in fp32. 256 thr = 4 rows/block.
// ---------------------------------------------------------------------------
__global__ __launch_bounds__(256) void ln_add_kernel(
    float* h, const __bf16* __restrict__ delta, __bf16* __restrict__ hb,
    const float* __restrict__ g, const float* __restrict__ bb)
{
    size_t r = (size_t)blockIdx.x * 4 + (threadIdx.x >> 6);
    int t = threadIdx.x & 63;
    float4* hp = (float4*)(h + r * D_) + 2 * t;
    float4 x0 = hp[0], x1 = hp[1];
    bf16x8 dv = *(const bf16x8*)&delta[r * D_ + t * 8];
    float x[8] = {x0.x, x0.y, x0.z, x0.w, x1.x, x1.y, x1.z, x1.w};
    #pragma unroll
    for (int j = 0; j < 8; j++) x[j] += (float)dv[j];
    float s = 0.f;
    #pragma unroll
    for (int j = 0; j < 8; j++) s += x[j];
    #pragma unroll
    for (int off = 32; off; off >>= 1) s += __shfl_xor(s, off, 64);
    float mean = s * (1.0f / D_);
    float ss = 0.f;
    #pragma unroll
    for (int j = 0; j < 8; j++) { x[j] -= mean; ss += x[j] * x[j]; }
    #pragma unroll
    for (int off = 32; off; off >>= 1) ss += __shfl_xor(ss, off, 64);
    float rs = rsqrtf(ss * (1.0f / D_) + 1e-5f);
    float4 g0 = ((const float4*)g)[2 * t], g1 = ((const float4*)g)[2 * t + 1];
    float4 b0 = ((const float4*)bb)[2 * t], b1 = ((const float4*)bb)[2 * t + 1];
    float gg[8] = {g0.x, g0.y, g0.z, g0.w, g1.x, g1.y, g1.z, g1.w};
    float bbv[8] = {b0.x, b0.y, b0.z, b0.w, b1.x, b1.y, b1.z, b1.w};
    float y[8];
    bf16x8 outv;
    #pragma unroll
    for (int j = 0; j < 8; j++) {
        y[j] = x[j] * rs * gg[j] + bbv[j];
        outv[j] = (__bf16)y[j];
    }
    hp[0] = (float4){y[0], y[1], y[2], y[3]};
    hp[1] = (float4){y[4], y[5], y[6], y[7]};
    *(bf16x8*)&hb[r * D_ + t * 8] = outv;
}

// ---------------------------------------------------------------------------
// Head stage 1: grid (8,4). Block (b,jg): columns j = jg*256 + tid of
// dense = relu(h[b,0,:] @ w_dense + b_dense); partial sums of dense@w_out.
// ---------------------------------------------------------------------------
__global__ __launch_bounds__(256) void head1_kernel(
    const float* __restrict__ h, const float* __restrict__ wd,
    const float* __restrict__ bd, const float* __restrict__ wo,
    float* __restrict__ partial)
{
    __shared__ float hrow[D_];
    __shared__ float red[8];
    int b = blockIdx.x, jg = blockIdx.y;
    int tid = threadIdx.x;
    if (tid < 128) ((float4*)hrow)[tid] = ((const float4*)(h + (size_t)b * S_ * D_))[tid];
    __syncthreads();
    int j = jg * 256 + tid;
    float acc = bd[j];
    #pragma unroll 8
    for (int i = 0; i < D_; i++) acc = fmaf(hrow[i], wd[(size_t)i * 1024 + j], acc);
    float dns = fmaxf(acc, 0.f);
    float2 w2 = ((const float2*)wo)[j];
    float p0 = dns * w2.x, p1 = dns * w2.y;
    #pragma unroll
    for (int off = 32; off; off >>= 1) { p0 += __shfl_xor(p0, off, 64); p1 += __shfl_xor(p1, off, 64); }
    int wid = tid >> 6;
    if ((tid & 63) == 0) { red[wid * 2] = p0; red[wid * 2 + 1] = p1; }
    __syncthreads();
    if (tid == 0) {
        float t0 = red[0] + red[2] + red[4] + red[6];
        float t1 = red[1] + red[3] + red[5] + red[7];
        partial[((size_t)b * 4 + jg) * 2 + 0] = t0;
        partial[((size_t)b * 4 + jg) * 2 + 1] = t1;
    }
}

// Head stage 2: 16 threads, one block.
__global__ __launch_bounds__(64) void head2_kernel(
    const float* __restrict__ partial, const float* __restrict__ bo,
    float* __restrict__ out)
{
    int tid = threadIdx.x;
    if (tid < 16) {
        int b = tid >> 1, c = tid & 1;
        float s = bo[c];
        #pragma unroll
        for (int jg = 0; jg < 4; jg++) s += partial[((size_t)b * 4 + jg) * 2 + c];
        out[b * 2 + c] = tanhf(s);
    }
}

// ---------------------------------------------------------------------------
extern "C" void kernel_launch(void* const* d_in, const int* in_sizes, int n_in,
                              void* d_out, int out_size, void* d_ws, size_t ws_size,
                              hipStream_t stream) {
    (void)in_sizes; (void)n_in; (void)out_size; (void)ws_size;
    const float* x       = (const float*)d_in[0];
    const float* w_embed = (const float*)d_in[1];
    const float* b_embed = (const float*)d_in[2];
    const float* pos_emb = (const float*)d_in[3];
    const float* Wq      = (const float*)d_in[4];
    const float* bq      = (const float*)d_in[5];
    const float* Wk      = (const float*)d_in[6];
    const float* bk      = (const float*)d_in[7];
    const float* Wv      = (const float*)d_in[8];
    const float* bv      = (const float*)d_in[9];
    const float* Wo      = (const float*)d_in[10];
    const float* bo      = (const float*)d_in[11];
    const float* ln1_g   = (const float*)d_in[12];
    const float* ln1_b   = (const float*)d_in[13];
    const float* W1      = (const float*)d_in[14];
    const float* b1      = (const float*)d_in[15];
    const float* W2      = (const float*)d_in[16];
    const float* b2      = (const float*)d_in[17];
    const float* ln2_g   = (const float*)d_in[18];
    const float* ln2_b   = (const float*)d_in[19];
    const float* w_dense = (const float*)d_in[20];
    const float* b_dense = (const float*)d_in[21];
    const float* w_out   = (const float*)d_in[22];
    const float* b_out   = (const float*)d_in[23];
    const int*   rb      = (const int*)d_in[24];
    float* out = (float*)d_out;

    // Workspace layout (~155 MiB):
    //  h fp32 32M @0 | h_bf 16M @32MiB | big 64M @48MiB: qkv(48M)+o(16M)==ff1
    //  (embed phase reuses big: xr, wt_e) | wt ~25M @112MiB | dbuf 16M @138MiB
    //  head partials @ 154 MiB
    const size_t PLANE = (size_t)B_ * H_ * S_ * DH_;  // 8,388,608
    float*  h    = (float*)d_ws;
    __bf16* h_bf = (__bf16*)((char*)d_ws + (size_t)32 * 1024 * 1024);
    __bf16* big  = (__bf16*)((char*)d_ws + (size_t)48 * 1024 * 1024);
    __bf16* qkv  = big;
    __bf16* o_bf = big + 3 * PLANE;
    __bf16* ff1  = big;                                // alias, lifetime-disjoint
    __bf16* xr   = big;                                // embed-phase only
    __bf16* wt_e = big + (size_t)28 * 1024 * 1024;     // embed-phase only (512*128)
    __bf16* wt   = (__bf16*)((char*)d_ws + (size_t)112 * 1024 * 1024);
    __bf16* wt_qkv = wt;                               // 3*L*D*D
    __bf16* wt_o   = wt_qkv + (size_t)3 * L_ * DD_;    // L*D*D
    __bf16* wt_1   = wt_o + (size_t)L_ * DD_;          // L*D*FF
    __bf16* wt_2   = wt_1 + (size_t)L_ * D_ * FF_;     // L*FF*D
    __bf16* dbuf   = (__bf16*)((char*)d_ws + (size_t)138 * 1024 * 1024); // 16M
    float*  hpart  = (float*)((char*)d_ws + (size_t)154 * 1024 * 1024);  // 64 floats

    dim3 tb(32, 8);
    wconv_qkvo<<<dim3(16, 16, 16), tb, 0, stream>>>(Wq, Wk, Wv, Wo, wt_qkv, wt_o);
    wconv_kernel<<<dim3(64, 16, L_), tb, 0, stream>>>(W1, wt_1, D_, FF_, D_);
    wconv_kernel<<<dim3(16, 64, L_), tb, 0, stream>>>(W2, wt_2, FF_, D_, FF_);
    wconv_kernel<<<dim3(16, 4, 1),  tb, 0, stream>>>(w_embed, wt_e, 80, D_, KE_);

    // Embed = MFMA GEMM: h/h_bf = xr @ wt_e^T + b_embed + pos_emb (cls -> pe[0])
    xbuild_kernel<<<MTOK / 64, 256, 0, stream>>>(x, xr);
    mfma_gemm<<<dim3(D_ / 128, MTOK / 128, 1), 256, 0, stream>>>(
        xr, wt_e, b_embed, b_embed, b_embed,
        pos_emb, h, h_bf, D_, KE_, 0, 0, 0, 0, 1);

    for (int l = 0; l < L_; l++) {
        // QKV (z folded into x for A-slice reuse; XCD swizzle in-kernel)
        mfma_gemm<<<dim3((D_ / 128) * 3, MTOK / 128, 1), 256, 0, stream>>>(
            h_bf, wt_qkv + (size_t)l * DD_, bq + l * D_, bk + l * D_, bv + l * D_,
            nullptr, nullptr, qkv, D_, D_, (long)L_ * DD_, (long)PLANE, 0, 1, 3);

        attn_kernel<<<B_ * H_ * NB_, 256, 0, stream>>>(qkv, qkv + PLANE, qkv + 2 * PLANE, rb, o_bf);

        // dbuf = o @ Wo + bo  (delta only, bf16)
        mfma_gemm<<<dim3(D_ / 128, MTOK / 128, 1), 256, 0, stream>>>(
            o_bf, wt_o + (size_t)l * DD_, bo + l * D_, bo + l * D_, bo + l * D_,
            nullptr, nullptr, dbuf, D_, D_, 0, 0, 0, 0, 1);
        // h += dbuf; LN -> h (fp32) + h_bf (bf16)
        ln_add_kernel<<<MTOK / 4, 256, 0, stream>>>(h, dbuf, h_bf, ln1_g + l * D_, ln1_b + l * D_);

        // ff1 = relu(h @ W1 + b1)
        mfma_gemm<<<dim3(FF_ / 128, MTOK / 128, 1), 256, 0, stream>>>(
            h_bf, wt_1 + (size_t)l * D_ * FF_, b1 + l * FF_, b1 + l * FF_, b1 + l * FF_,
            nullptr, nullptr, ff1, FF_, D_, 0, 0, 1, 0, 1);

        // dbuf = ff1 @ W2 + b2  (delta only, bf16)
        mfma_gemm<<<dim3(D_ / 128, MTOK / 128, 1), 256, 0, stream>>>(
            ff1, wt_2 + (size_t)l * FF_ * D_, b2 + l * D_, b2 + l * D_, b2 + l * D_,
            nullptr, nullptr, dbuf, D_, FF_, 0, 0, 0, 0, 1);
        ln_add_kernel<<<MTOK / 4, 256, 0, stream>>>(h, dbuf, h_bf, ln2_g + l * D_, ln2_b + l * D_);
    }

    head1_kernel<<<dim3(B_, 4), 256, 0, stream>>>(h, w_dense, b_dense, w_out, hpart);
    head2_kernel<<<1, 64, 0, stream>>>(hpart, b_out, out);
}